// Round 1
// baseline (3416.792 us; speedup 1.0000x reference)
//
#include <hip/hip_runtime.h>
#include <float.h>

#define N_NODES 100000
#define N_EDGES 3200000
#define N_GRAPHS 1024
#define F_IN 78
#define H 128
#define BN_EPS 1e-5f

#define CHUNK 1024
#define NCHUNK ((N_NODES + CHUNK - 1) / CHUNK)  // 98

// ---------------- CSR build ----------------

__global__ void k_deg(const int* __restrict__ dst, int* __restrict__ deg) {
    int e = blockIdx.x * blockDim.x + threadIdx.x;
    if (e < N_EDGES) atomicAdd(&deg[dst[e]], 1);
}

__global__ void k_chunk_sum(const int* __restrict__ deg, int* __restrict__ csum) {
    __shared__ int sd[256];
    int b = blockIdx.x;
    int s = 0;
    for (int j = threadIdx.x; j < CHUNK; j += 256) {
        int i = b * CHUNK + j;
        s += (i < N_NODES) ? deg[i] : 0;
    }
    sd[threadIdx.x] = s;
    __syncthreads();
    for (int off = 128; off > 0; off >>= 1) {
        if (threadIdx.x < off) sd[threadIdx.x] += sd[threadIdx.x + off];
        __syncthreads();
    }
    if (threadIdx.x == 0) csum[b] = sd[0];
}

__global__ void k_scan_chunks(const int* __restrict__ csum, int* __restrict__ coff,
                              int* __restrict__ row_start) {
    if (threadIdx.x == 0) {
        int acc = 0;
        for (int b = 0; b < NCHUNK; ++b) { coff[b] = acc; acc += csum[b]; }
        row_start[N_NODES] = acc;  // == N_EDGES
    }
}

__global__ void k_scan_within(const int* __restrict__ deg, const int* __restrict__ coff,
                              int* __restrict__ row_start) {
    __shared__ int sd[256];
    int b = blockIdx.x, t = threadIdx.x;
    int base = b * CHUNK + t * 4;
    int loc[4];
    int s = 0;
#pragma unroll
    for (int j = 0; j < 4; ++j) {
        loc[j] = s;
        int i = base + j;
        s += (i < N_NODES) ? deg[i] : 0;
    }
    sd[t] = s;
    __syncthreads();
    if (t == 0) {
        int run = 0;
        for (int u = 0; u < 256; ++u) { int tmp = sd[u]; sd[u] = run; run += tmp; }
    }
    __syncthreads();
    int off = coff[b] + sd[t];
#pragma unroll
    for (int j = 0; j < 4; ++j) {
        int i = base + j;
        if (i < N_NODES) row_start[i] = off + loc[j];
    }
}

__global__ void k_scatter(const int* __restrict__ src, const int* __restrict__ dst,
                          int* __restrict__ cursor, int* __restrict__ esrc) {
    int e = blockIdx.x * blockDim.x + threadIdx.x;
    if (e < N_EDGES) {
        int d = dst[e];
        int p = atomicAdd(&cursor[d], 1);
        esrc[p] = src[e];
    }
}

// ---------------- per-layer kernels ----------------

// out[i] = x[i] + sum_{j in in-edges(i)} x[j]; one wave per node
template <int NC>
__global__ void k_gather(const float* __restrict__ x, const int* __restrict__ row_start,
                         const int* __restrict__ esrc, float* __restrict__ out) {
    int wave = threadIdx.x >> 6;
    int lane = threadIdx.x & 63;
    int node = blockIdx.x * 4 + wave;
    if (node >= N_NODES) return;
    int s = row_start[node], e = row_start[node + 1];
    const int NJ = (NC + 63) / 64;
    float acc[NJ];
#pragma unroll
    for (int j = 0; j < NJ; ++j) {
        int c = lane + j * 64;
        acc[j] = (c < NC) ? x[node * NC + c] : 0.f;
    }
    for (int p = s; p < e; ++p) {
        int sn = esrc[p];
        int base = sn * NC;
#pragma unroll
        for (int j = 0; j < NJ; ++j) {
            int c = lane + j * 64;
            if (c < NC) acc[j] += x[base + c];
        }
    }
#pragma unroll
    for (int j = 0; j < NJ; ++j) {
        int c = lane + j * 64;
        if (c < NC) out[node * NC + c] = acc[j];
    }
}

// out = relu(in @ W + bias); in: [N_NODES, K], W: [K, H], out: [N_NODES, H]
// 16 rows per block; each thread: 2 rows x 4 cols
template <int K>
__global__ __launch_bounds__(256) void k_gemm(const float* __restrict__ in,
                                              const float* __restrict__ W,
                                              const float* __restrict__ bias,
                                              float* __restrict__ out) {
    __shared__ float xs[16][K];
    int c0 = (threadIdx.x & 31) * 4;
    int rp = threadIdx.x >> 5;  // 0..7 -> rows 2rp, 2rp+1
    int rowBase = blockIdx.x * 16;
    for (int idx = threadIdx.x; idx < 16 * K; idx += 256) {
        int r = idx / K, k = idx - r * K;
        xs[r][k] = in[(rowBase + r) * K + k];
    }
    __syncthreads();
    float4 b4 = *reinterpret_cast<const float4*>(&bias[c0]);
    float acc[2][4];
    acc[0][0] = b4.x; acc[0][1] = b4.y; acc[0][2] = b4.z; acc[0][3] = b4.w;
    acc[1][0] = b4.x; acc[1][1] = b4.y; acc[1][2] = b4.z; acc[1][3] = b4.w;
#pragma unroll 4
    for (int k = 0; k < K; ++k) {
        float4 w = *reinterpret_cast<const float4*>(&W[k * H + c0]);
        float a0 = xs[2 * rp][k];
        float a1 = xs[2 * rp + 1][k];
        acc[0][0] += a0 * w.x; acc[0][1] += a0 * w.y; acc[0][2] += a0 * w.z; acc[0][3] += a0 * w.w;
        acc[1][0] += a1 * w.x; acc[1][1] += a1 * w.y; acc[1][2] += a1 * w.z; acc[1][3] += a1 * w.w;
    }
#pragma unroll
    for (int i = 0; i < 2; ++i) {
        int r = rowBase + 2 * rp + i;
        float4 o;
        o.x = fmaxf(acc[i][0], 0.f);
        o.y = fmaxf(acc[i][1], 0.f);
        o.z = fmaxf(acc[i][2], 0.f);
        o.w = fmaxf(acc[i][3], 0.f);
        *reinterpret_cast<float4*>(&out[r * H + c0]) = o;
    }
}

__global__ void k_bnstats(const float* __restrict__ v, float* __restrict__ gsum,
                          float* __restrict__ gss) {
    __shared__ float sd[512];
    int c = threadIdx.x & 127;
    int half = threadIdx.x >> 7;
    float s = 0.f, ss = 0.f;
    for (int i = blockIdx.x * 2 + half; i < N_NODES; i += gridDim.x * 2) {
        float val = v[i * H + c];
        s += val;
        ss += val * val;
    }
    sd[threadIdx.x] = s;
    sd[256 + threadIdx.x] = ss;
    __syncthreads();
    if (threadIdx.x < 128) {
        atomicAdd(&gsum[c], sd[c] + sd[128 + c]);
        atomicAdd(&gss[c], sd[256 + c] + sd[384 + c]);
    }
}

__global__ void k_bnfinal(const float* __restrict__ gsum, const float* __restrict__ gss,
                          const float* __restrict__ gamma, const float* __restrict__ beta,
                          float* __restrict__ scale, float* __restrict__ shift) {
    int c = threadIdx.x;
    const float inv_n = 1.f / (float)N_NODES;
    float mu = gsum[c] * inv_n;
    float var = fmaxf(gss[c] * inv_n - mu * mu, 0.f);
    float sc = gamma[c] * rsqrtf(var + BN_EPS);
    scale[c] = sc;
    shift[c] = beta[c] - mu * sc;
}

template <bool RES>
__global__ void k_bnapply(const float* __restrict__ v, const float* __restrict__ scale,
                          const float* __restrict__ shift, float* __restrict__ h) {
    int idx = blockIdx.x * blockDim.x + threadIdx.x;  // float4 index
    if (idx >= N_NODES * H / 4) return;
    int c4 = idx & 31;
    float4 val = reinterpret_cast<const float4*>(v)[idx];
    float4 sc = reinterpret_cast<const float4*>(scale)[c4];
    float4 sh = reinterpret_cast<const float4*>(shift)[c4];
    float4 r;
    r.x = val.x * sc.x + sh.x;
    r.y = val.y * sc.y + sh.y;
    r.z = val.z * sc.z + sh.z;
    r.w = val.w * sc.w + sh.w;
    if (RES) {
        float4 hv = reinterpret_cast<float4*>(h)[idx];
        r.x += hv.x; r.y += hv.y; r.z += hv.z; r.w += hv.w;
    }
    reinterpret_cast<float4*>(h)[idx] = r;
}

// ---------------- pooling + head ----------------

__global__ void k_bounds(const int* __restrict__ batch, int* __restrict__ row_begin) {
    int i = blockIdx.x * blockDim.x + threadIdx.x;
    if (i >= N_NODES) return;
    int bi = batch[i];
    int bp = (i == 0) ? -1 : batch[i - 1];
    for (int g = bp + 1; g <= bi; ++g) row_begin[g] = i;
    if (i == N_NODES - 1) {
        for (int g = bi + 1; g <= N_GRAPHS; ++g) row_begin[g] = N_NODES;
    }
}

__global__ void k_pool(const float* __restrict__ h, const int* __restrict__ row_begin,
                       float* __restrict__ pooled) {
    int g = blockIdx.x;
    int c = threadIdx.x;  // 128
    int s = row_begin[g], e = row_begin[g + 1];
    float sum = 0.f, mx = -FLT_MAX;
    for (int i = s; i < e; ++i) {
        float v = h[i * H + c];
        sum += v;
        mx = fmaxf(mx, v);
    }
    int cnt = e - s;
    pooled[g * 256 + c]       = (cnt > 0) ? sum / (float)cnt : 0.f;
    pooled[g * 256 + 128 + c] = (cnt > 0) ? mx : 0.f;
}

__global__ void k_final(const float* __restrict__ pooled, const float* __restrict__ Wf,
                        const float* __restrict__ bf, float* __restrict__ out) {
    __shared__ float ps[256];
    int g = blockIdx.x, c = threadIdx.x;  // 128 threads
    ps[c] = pooled[g * 256 + c];
    ps[128 + c] = pooled[g * 256 + 128 + c];
    __syncthreads();
    float acc = bf[c];
#pragma unroll 8
    for (int k = 0; k < 256; ++k) acc += ps[k] * Wf[k * H + c];
    out[g * H + c] = acc;
}

// ---------------- launcher ----------------

extern "C" void kernel_launch(void* const* d_in, const int* in_sizes, int n_in,
                              void* d_out, int out_size, void* d_ws, size_t ws_size,
                              hipStream_t stream) {
    const float* x     = (const float*)d_in[0];
    const int*   ei    = (const int*)d_in[1];
    const int*   src   = ei;
    const int*   dst   = ei + N_EDGES;
    const int*   batch = (const int*)d_in[2];
    const float* W1_0  = (const float*)d_in[3];
    const float* b1_0  = (const float*)d_in[4];
    const float* W2_0  = (const float*)d_in[5];
    const float* b2_0  = (const float*)d_in[6];
    const float* W1    = (const float*)d_in[7];
    const float* b1    = (const float*)d_in[8];
    const float* W2    = (const float*)d_in[9];
    const float* b2    = (const float*)d_in[10];
    const float* gamma = (const float*)d_in[11];
    const float* beta  = (const float*)d_in[12];
    const float* Wf    = (const float*)d_in[13];
    const float* bf    = (const float*)d_in[14];
    float* out = (float*)d_out;

    char* ws = (char*)d_ws;
    size_t off = 0;
    auto alloc = [&](size_t bytes) -> void* {
        void* p = ws + off;
        off = (off + bytes + 255) & ~(size_t)255;
        return p;
    };

    float* h    = (float*)alloc((size_t)N_NODES * H * 4);
    float* bufA = (float*)alloc((size_t)N_NODES * H * 4);
    float* bufB = (float*)alloc((size_t)N_NODES * H * 4);
    int* deg       = (int*)alloc((size_t)N_NODES * 4);
    int* row_start = (int*)alloc((size_t)(N_NODES + 1) * 4);
    int* cursor    = (int*)alloc((size_t)N_NODES * 4);
    int* esrc      = (int*)alloc((size_t)N_EDGES * 4);
    int* csum      = (int*)alloc((size_t)NCHUNK * 4);
    int* coff      = (int*)alloc((size_t)NCHUNK * 4);
    float* gsum  = (float*)alloc(H * 4);
    float* gss   = (float*)alloc(H * 4);
    float* scale = (float*)alloc(H * 4);
    float* shift = (float*)alloc(H * 4);
    int* row_begin = (int*)alloc((size_t)(N_GRAPHS + 1) * 4);
    float* pooled  = (float*)alloc((size_t)N_GRAPHS * 256 * 4);

    // ---- CSR build (counting sort by dst) ----
    hipMemsetAsync(deg, 0, (size_t)N_NODES * 4, stream);
    k_deg<<<N_EDGES / 256, 256, 0, stream>>>(dst, deg);
    k_chunk_sum<<<NCHUNK, 256, 0, stream>>>(deg, csum);
    k_scan_chunks<<<1, 64, 0, stream>>>(csum, coff, row_start);
    k_scan_within<<<NCHUNK, 256, 0, stream>>>(deg, coff, row_start);
    hipMemcpyAsync(cursor, row_start, (size_t)N_NODES * 4, hipMemcpyDeviceToDevice, stream);
    k_scatter<<<N_EDGES / 256, 256, 0, stream>>>(src, dst, cursor, esrc);

    // ---- layer 0 (78 -> 128, no residual) ----
    k_gather<F_IN><<<N_NODES / 4, 256, 0, stream>>>(x, row_start, esrc, bufA);
    k_gemm<F_IN><<<N_NODES / 16, 256, 0, stream>>>(bufA, W1_0, b1_0, bufB);
    k_gemm<H><<<N_NODES / 16, 256, 0, stream>>>(bufB, W2_0, b2_0, bufA);
    hipMemsetAsync(gsum, 0, H * 4, stream);
    hipMemsetAsync(gss, 0, H * 4, stream);
    k_bnstats<<<256, 256, 0, stream>>>(bufA, gsum, gss);
    k_bnfinal<<<1, 128, 0, stream>>>(gsum, gss, gamma, beta, scale, shift);
    k_bnapply<false><<<N_NODES * H / 4 / 256, 256, 0, stream>>>(bufA, scale, shift, h);

    // ---- layers 1..4 (residual) ----
    for (int l = 0; l < 4; ++l) {
        k_gather<H><<<N_NODES / 4, 256, 0, stream>>>(h, row_start, esrc, bufA);
        k_gemm<H><<<N_NODES / 16, 256, 0, stream>>>(bufA, W1 + l * H * H, b1 + l * H, bufB);
        k_gemm<H><<<N_NODES / 16, 256, 0, stream>>>(bufB, W2 + l * H * H, b2 + l * H, bufA);
        hipMemsetAsync(gsum, 0, H * 4, stream);
        hipMemsetAsync(gss, 0, H * 4, stream);
        k_bnstats<<<256, 256, 0, stream>>>(bufA, gsum, gss);
        k_bnfinal<<<1, 128, 0, stream>>>(gsum, gss, gamma + (l + 1) * H, beta + (l + 1) * H,
                                         scale, shift);
        k_bnapply<true><<<N_NODES * H / 4 / 256, 256, 0, stream>>>(bufA, scale, shift, h);
    }

    // ---- pooling + head ----
    k_bounds<<<(N_NODES + 255) / 256, 256, 0, stream>>>(batch, row_begin);
    k_pool<<<N_GRAPHS, 128, 0, stream>>>(h, row_begin, pooled);
    k_final<<<N_GRAPHS, 128, 0, stream>>>(pooled, Wf, bf, out);
}

// Round 2
// 2550.017 us; speedup vs baseline: 1.3399x; 1.3399x over previous
//
#include <hip/hip_runtime.h>
#include <float.h>

#define N_NODES 100000
#define N_EDGES 3200000
#define N_GRAPHS 1024
#define F_IN 78
#define H 128
#define BN_EPS 1e-5f

#define CHUNK 1024
#define NCHUNK ((N_NODES + CHUNK - 1) / CHUNK)  // 98

// ---------------- CSR build ----------------

__global__ void k_deg(const int* __restrict__ dst, int* __restrict__ deg) {
    int e = blockIdx.x * blockDim.x + threadIdx.x;
    if (e < N_EDGES) atomicAdd(&deg[dst[e]], 1);
}

__global__ void k_chunk_sum(const int* __restrict__ deg, int* __restrict__ csum) {
    __shared__ int sd[256];
    int b = blockIdx.x;
    int s = 0;
    for (int j = threadIdx.x; j < CHUNK; j += 256) {
        int i = b * CHUNK + j;
        s += (i < N_NODES) ? deg[i] : 0;
    }
    sd[threadIdx.x] = s;
    __syncthreads();
    for (int off = 128; off > 0; off >>= 1) {
        if (threadIdx.x < off) sd[threadIdx.x] += sd[threadIdx.x + off];
        __syncthreads();
    }
    if (threadIdx.x == 0) csum[b] = sd[0];
}

__global__ void k_scan_chunks(const int* __restrict__ csum, int* __restrict__ coff,
                              int* __restrict__ row_start) {
    if (threadIdx.x == 0) {
        int acc = 0;
        for (int b = 0; b < NCHUNK; ++b) { coff[b] = acc; acc += csum[b]; }
        row_start[N_NODES] = acc;  // == N_EDGES
    }
}

__global__ void k_scan_within(const int* __restrict__ deg, const int* __restrict__ coff,
                              int* __restrict__ row_start) {
    __shared__ int sd[256];
    int b = blockIdx.x, t = threadIdx.x;
    int base = b * CHUNK + t * 4;
    int loc[4];
    int s = 0;
#pragma unroll
    for (int j = 0; j < 4; ++j) {
        loc[j] = s;
        int i = base + j;
        s += (i < N_NODES) ? deg[i] : 0;
    }
    sd[t] = s;
    __syncthreads();
    if (t == 0) {
        int run = 0;
        for (int u = 0; u < 256; ++u) { int tmp = sd[u]; sd[u] = run; run += tmp; }
    }
    __syncthreads();
    int off = coff[b] + sd[t];
#pragma unroll
    for (int j = 0; j < 4; ++j) {
        int i = base + j;
        if (i < N_NODES) row_start[i] = off + loc[j];
    }
}

__global__ void k_scatter(const int* __restrict__ src, const int* __restrict__ dst,
                          int* __restrict__ cursor, int* __restrict__ esrc) {
    int e = blockIdx.x * blockDim.x + threadIdx.x;
    if (e < N_EDGES) {
        int d = dst[e];
        int p = atomicAdd(&cursor[d], 1);
        esrc[p] = src[e];
    }
}

// ---------------- gather (aggregate) kernels ----------------

// H=128 path: one wave per node; lane holds float2 (512 B row = one request).
// Edge loop unrolled x8 with 8 independent loads in flight, 4 accumulators.
__global__ void k_gather128(const float* __restrict__ x, const int* __restrict__ row_start,
                            const int* __restrict__ esrc, float* __restrict__ out) {
    int wave = threadIdx.x >> 6;
    int lane = threadIdx.x & 63;
    int node = blockIdx.x * 4 + wave;
    const float2* __restrict__ x2 = (const float2*)x;
    int s = row_start[node], e = row_start[node + 1];
    float2 self = x2[node * 64 + lane];
    float a0x = 0.f, a0y = 0.f, a1x = 0.f, a1y = 0.f;
    float a2x = 0.f, a2y = 0.f, a3x = 0.f, a3y = 0.f;
    int p = s;
    for (; p + 8 <= e; p += 8) {
        int i0 = esrc[p + 0], i1 = esrc[p + 1], i2 = esrc[p + 2], i3 = esrc[p + 3];
        int i4 = esrc[p + 4], i5 = esrc[p + 5], i6 = esrc[p + 6], i7 = esrc[p + 7];
        float2 v0 = x2[i0 * 64 + lane];
        float2 v1 = x2[i1 * 64 + lane];
        float2 v2 = x2[i2 * 64 + lane];
        float2 v3 = x2[i3 * 64 + lane];
        float2 v4 = x2[i4 * 64 + lane];
        float2 v5 = x2[i5 * 64 + lane];
        float2 v6 = x2[i6 * 64 + lane];
        float2 v7 = x2[i7 * 64 + lane];
        a0x += v0.x; a0y += v0.y; a1x += v1.x; a1y += v1.y;
        a2x += v2.x; a2y += v2.y; a3x += v3.x; a3y += v3.y;
        a0x += v4.x; a0y += v4.y; a1x += v5.x; a1y += v5.y;
        a2x += v6.x; a2y += v6.y; a3x += v7.x; a3y += v7.y;
    }
    for (; p + 2 <= e; p += 2) {
        int i0 = esrc[p], i1 = esrc[p + 1];
        float2 v0 = x2[i0 * 64 + lane];
        float2 v1 = x2[i1 * 64 + lane];
        a0x += v0.x; a0y += v0.y; a1x += v1.x; a1y += v1.y;
    }
    if (p < e) {
        float2 v = x2[esrc[p] * 64 + lane];
        a0x += v.x; a0y += v.y;
    }
    float2 r;
    r.x = self.x + (a0x + a1x) + (a2x + a3x);
    r.y = self.y + (a0y + a1y) + (a2y + a3y);
    ((float2*)out)[node * 64 + lane] = r;
}

// generic-width path (layer 0, NC=78): scalar lanes, unroll x4
template <int NC>
__global__ void k_gatherN(const float* __restrict__ x, const int* __restrict__ row_start,
                          const int* __restrict__ esrc, float* __restrict__ out) {
    int wave = threadIdx.x >> 6;
    int lane = threadIdx.x & 63;
    int node = blockIdx.x * 4 + wave;
    int s = row_start[node], e = row_start[node + 1];
    int c0 = lane, c1 = lane + 64;
    bool p0 = (c0 < NC), p1 = (c1 < NC);
    float s0 = p0 ? x[(size_t)node * NC + c0] : 0.f;
    float s1 = p1 ? x[(size_t)node * NC + c1] : 0.f;
    float a00 = 0.f, a01 = 0.f, a10 = 0.f, a11 = 0.f;
    float a20 = 0.f, a21 = 0.f, a30 = 0.f, a31 = 0.f;
    int p = s;
    for (; p + 4 <= e; p += 4) {
        int i0 = esrc[p], i1 = esrc[p + 1], i2 = esrc[p + 2], i3 = esrc[p + 3];
        float v00 = p0 ? x[i0 * NC + c0] : 0.f;
        float v01 = p1 ? x[i0 * NC + c1] : 0.f;
        float v10 = p0 ? x[i1 * NC + c0] : 0.f;
        float v11 = p1 ? x[i1 * NC + c1] : 0.f;
        float v20 = p0 ? x[i2 * NC + c0] : 0.f;
        float v21 = p1 ? x[i2 * NC + c1] : 0.f;
        float v30 = p0 ? x[i3 * NC + c0] : 0.f;
        float v31 = p1 ? x[i3 * NC + c1] : 0.f;
        a00 += v00; a01 += v01; a10 += v10; a11 += v11;
        a20 += v20; a21 += v21; a30 += v30; a31 += v31;
    }
    for (; p < e; ++p) {
        int i0 = esrc[p];
        a00 += p0 ? x[i0 * NC + c0] : 0.f;
        a01 += p1 ? x[i0 * NC + c1] : 0.f;
    }
    float r0 = s0 + (a00 + a10) + (a20 + a30);
    float r1 = s1 + (a01 + a11) + (a21 + a31);
    if (p0) out[(size_t)node * NC + c0] = r0;
    if (p1) out[(size_t)node * NC + c1] = r1;
}

// ---------------- GEMM kernels ----------------

// K=128 specialized: 32 rows/block, thread = 4 rows x 4 cols, k-step 4
__global__ __launch_bounds__(256) void k_gemm128(const float* __restrict__ in,
                                                 const float* __restrict__ W,
                                                 const float* __restrict__ bias,
                                                 float* __restrict__ out) {
    __shared__ float xs[32][128];
    int rp = threadIdx.x >> 5;         // 0..7 -> rows 4rp..4rp+3
    int c0 = (threadIdx.x & 31) * 4;   // col group
    int rowBase = blockIdx.x * 32;
    const float4* in4 = (const float4*)(in + (size_t)rowBase * 128);
    float4* xs4 = (float4*)xs;
#pragma unroll
    for (int i = 0; i < 4; ++i) xs4[threadIdx.x + i * 256] = in4[threadIdx.x + i * 256];
    __syncthreads();
    float4 b4 = *(const float4*)&bias[c0];
    float acc[4][4];
#pragma unroll
    for (int i = 0; i < 4; ++i) {
        acc[i][0] = b4.x; acc[i][1] = b4.y; acc[i][2] = b4.z; acc[i][3] = b4.w;
    }
    for (int k = 0; k < 128; k += 4) {
        float4 a[4], w[4];
#pragma unroll
        for (int i = 0; i < 4; ++i) a[i] = *(const float4*)&xs[4 * rp + i][k];
#pragma unroll
        for (int j = 0; j < 4; ++j) w[j] = *(const float4*)&W[(k + j) * H + c0];
#pragma unroll
        for (int i = 0; i < 4; ++i) {
            const float* ai = (const float*)&a[i];
#pragma unroll
            for (int j = 0; j < 4; ++j) {
                const float* wj = (const float*)&w[j];
                acc[i][0] += ai[j] * wj[0];
                acc[i][1] += ai[j] * wj[1];
                acc[i][2] += ai[j] * wj[2];
                acc[i][3] += ai[j] * wj[3];
            }
        }
    }
#pragma unroll
    for (int i = 0; i < 4; ++i) {
        int r = rowBase + 4 * rp + i;
        float4 o;
        o.x = fmaxf(acc[i][0], 0.f);
        o.y = fmaxf(acc[i][1], 0.f);
        o.z = fmaxf(acc[i][2], 0.f);
        o.w = fmaxf(acc[i][3], 0.f);
        *reinterpret_cast<float4*>(&out[(size_t)r * H + c0]) = o;
    }
}

// generic-K (layer 0 first GEMM, K=78): 16 rows/block, thread = 2 rows x 4 cols
template <int K>
__global__ __launch_bounds__(256) void k_gemm(const float* __restrict__ in,
                                              const float* __restrict__ W,
                                              const float* __restrict__ bias,
                                              float* __restrict__ out) {
    __shared__ float xs[16][K];
    int c0 = (threadIdx.x & 31) * 4;
    int rp = threadIdx.x >> 5;
    int rowBase = blockIdx.x * 16;
    for (int idx = threadIdx.x; idx < 16 * K; idx += 256) {
        int r = idx / K, k = idx - r * K;
        xs[r][k] = in[(size_t)(rowBase + r) * K + k];
    }
    __syncthreads();
    float4 b4 = *reinterpret_cast<const float4*>(&bias[c0]);
    float acc[2][4];
    acc[0][0] = b4.x; acc[0][1] = b4.y; acc[0][2] = b4.z; acc[0][3] = b4.w;
    acc[1][0] = b4.x; acc[1][1] = b4.y; acc[1][2] = b4.z; acc[1][3] = b4.w;
#pragma unroll 4
    for (int k = 0; k < K; ++k) {
        float4 w = *reinterpret_cast<const float4*>(&W[k * H + c0]);
        float a0 = xs[2 * rp][k];
        float a1 = xs[2 * rp + 1][k];
        acc[0][0] += a0 * w.x; acc[0][1] += a0 * w.y; acc[0][2] += a0 * w.z; acc[0][3] += a0 * w.w;
        acc[1][0] += a1 * w.x; acc[1][1] += a1 * w.y; acc[1][2] += a1 * w.z; acc[1][3] += a1 * w.w;
    }
#pragma unroll
    for (int i = 0; i < 2; ++i) {
        int r = rowBase + 2 * rp + i;
        float4 o;
        o.x = fmaxf(acc[i][0], 0.f);
        o.y = fmaxf(acc[i][1], 0.f);
        o.z = fmaxf(acc[i][2], 0.f);
        o.w = fmaxf(acc[i][3], 0.f);
        *reinterpret_cast<float4*>(&out[(size_t)r * H + c0]) = o;
    }
}

// ---------------- BN ----------------

__global__ void k_bnstats(const float* __restrict__ v, float* __restrict__ gsum,
                          float* __restrict__ gss) {
    __shared__ float sd[512];
    int c = threadIdx.x & 127;
    int half = threadIdx.x >> 7;
    float s = 0.f, ss = 0.f;
    for (int i = blockIdx.x * 2 + half; i < N_NODES; i += gridDim.x * 2) {
        float val = v[(size_t)i * H + c];
        s += val;
        ss += val * val;
    }
    sd[threadIdx.x] = s;
    sd[256 + threadIdx.x] = ss;
    __syncthreads();
    if (threadIdx.x < 128) {
        atomicAdd(&gsum[c], sd[c] + sd[128 + c]);
        atomicAdd(&gss[c], sd[256 + c] + sd[384 + c]);
    }
}

__global__ void k_bnfinal(const float* __restrict__ gsum, const float* __restrict__ gss,
                          const float* __restrict__ gamma, const float* __restrict__ beta,
                          float* __restrict__ scale, float* __restrict__ shift) {
    int c = threadIdx.x;
    const float inv_n = 1.f / (float)N_NODES;
    float mu = gsum[c] * inv_n;
    float var = fmaxf(gss[c] * inv_n - mu * mu, 0.f);
    float sc = gamma[c] * rsqrtf(var + BN_EPS);
    scale[c] = sc;
    shift[c] = beta[c] - mu * sc;
}

template <bool RES>
__global__ void k_bnapply(const float* __restrict__ v, const float* __restrict__ scale,
                          const float* __restrict__ shift, float* __restrict__ h) {
    int idx = blockIdx.x * blockDim.x + threadIdx.x;  // float4 index
    if (idx >= N_NODES * H / 4) return;
    int c4 = idx & 31;
    float4 val = reinterpret_cast<const float4*>(v)[idx];
    float4 sc = reinterpret_cast<const float4*>(scale)[c4];
    float4 sh = reinterpret_cast<const float4*>(shift)[c4];
    float4 r;
    r.x = val.x * sc.x + sh.x;
    r.y = val.y * sc.y + sh.y;
    r.z = val.z * sc.z + sh.z;
    r.w = val.w * sc.w + sh.w;
    if (RES) {
        float4 hv = reinterpret_cast<float4*>(h)[idx];
        r.x += hv.x; r.y += hv.y; r.z += hv.z; r.w += hv.w;
    }
    reinterpret_cast<float4*>(h)[idx] = r;
}

// ---------------- pooling + head ----------------

__global__ void k_bounds(const int* __restrict__ batch, int* __restrict__ row_begin) {
    int i = blockIdx.x * blockDim.x + threadIdx.x;
    if (i >= N_NODES) return;
    int bi = batch[i];
    int bp = (i == 0) ? -1 : batch[i - 1];
    for (int g = bp + 1; g <= bi; ++g) row_begin[g] = i;
    if (i == N_NODES - 1) {
        for (int g = bi + 1; g <= N_GRAPHS; ++g) row_begin[g] = N_NODES;
    }
}

__global__ void k_pool(const float* __restrict__ h, const int* __restrict__ row_begin,
                       float* __restrict__ pooled) {
    int g = blockIdx.x;
    int c = threadIdx.x;  // 128
    int s = row_begin[g], e = row_begin[g + 1];
    float sum = 0.f, mx = -FLT_MAX;
    for (int i = s; i < e; ++i) {
        float v = h[(size_t)i * H + c];
        sum += v;
        mx = fmaxf(mx, v);
    }
    int cnt = e - s;
    pooled[g * 256 + c]       = (cnt > 0) ? sum / (float)cnt : 0.f;
    pooled[g * 256 + 128 + c] = (cnt > 0) ? mx : 0.f;
}

__global__ void k_final(const float* __restrict__ pooled, const float* __restrict__ Wf,
                        const float* __restrict__ bf, float* __restrict__ out) {
    __shared__ float ps[256];
    int g = blockIdx.x, c = threadIdx.x;  // 128 threads
    ps[c] = pooled[g * 256 + c];
    ps[128 + c] = pooled[g * 256 + 128 + c];
    __syncthreads();
    float acc = bf[c];
#pragma unroll 8
    for (int k = 0; k < 256; ++k) acc += ps[k] * Wf[k * H + c];
    out[g * H + c] = acc;
}

// ---------------- launcher ----------------

extern "C" void kernel_launch(void* const* d_in, const int* in_sizes, int n_in,
                              void* d_out, int out_size, void* d_ws, size_t ws_size,
                              hipStream_t stream) {
    const float* x     = (const float*)d_in[0];
    const int*   ei    = (const int*)d_in[1];
    const int*   src   = ei;
    const int*   dst   = ei + N_EDGES;
    const int*   batch = (const int*)d_in[2];
    const float* W1_0  = (const float*)d_in[3];
    const float* b1_0  = (const float*)d_in[4];
    const float* W2_0  = (const float*)d_in[5];
    const float* b2_0  = (const float*)d_in[6];
    const float* W1    = (const float*)d_in[7];
    const float* b1    = (const float*)d_in[8];
    const float* W2    = (const float*)d_in[9];
    const float* b2    = (const float*)d_in[10];
    const float* gamma = (const float*)d_in[11];
    const float* beta  = (const float*)d_in[12];
    const float* Wf    = (const float*)d_in[13];
    const float* bf    = (const float*)d_in[14];
    float* out = (float*)d_out;

    char* ws = (char*)d_ws;
    size_t off = 0;
    auto alloc = [&](size_t bytes) -> void* {
        void* p = ws + off;
        off = (off + bytes + 255) & ~(size_t)255;
        return p;
    };

    float* h    = (float*)alloc((size_t)N_NODES * H * 4);
    float* bufA = (float*)alloc((size_t)N_NODES * H * 4);
    float* bufB = (float*)alloc((size_t)N_NODES * H * 4);
    int* deg       = (int*)alloc((size_t)N_NODES * 4);
    int* row_start = (int*)alloc((size_t)(N_NODES + 1) * 4);
    int* cursor    = (int*)alloc((size_t)N_NODES * 4);
    int* esrc      = (int*)alloc((size_t)N_EDGES * 4);
    int* csum      = (int*)alloc((size_t)NCHUNK * 4);
    int* coff      = (int*)alloc((size_t)NCHUNK * 4);
    float* gsum  = (float*)alloc(H * 4);
    float* gss   = (float*)alloc(H * 4);
    float* scale = (float*)alloc(H * 4);
    float* shift = (float*)alloc(H * 4);
    int* row_begin = (int*)alloc((size_t)(N_GRAPHS + 1) * 4);
    float* pooled  = (float*)alloc((size_t)N_GRAPHS * 256 * 4);

    // ---- CSR build (counting sort by dst) ----
    hipMemsetAsync(deg, 0, (size_t)N_NODES * 4, stream);
    k_deg<<<N_EDGES / 256, 256, 0, stream>>>(dst, deg);
    k_chunk_sum<<<NCHUNK, 256, 0, stream>>>(deg, csum);
    k_scan_chunks<<<1, 64, 0, stream>>>(csum, coff, row_start);
    k_scan_within<<<NCHUNK, 256, 0, stream>>>(deg, coff, row_start);
    hipMemcpyAsync(cursor, row_start, (size_t)N_NODES * 4, hipMemcpyDeviceToDevice, stream);
    k_scatter<<<N_EDGES / 256, 256, 0, stream>>>(src, dst, cursor, esrc);

    // ---- layer 0 (78 -> 128, no residual) ----
    k_gatherN<F_IN><<<N_NODES / 4, 256, 0, stream>>>(x, row_start, esrc, bufA);
    k_gemm<F_IN><<<N_NODES / 16, 256, 0, stream>>>(bufA, W1_0, b1_0, bufB);
    k_gemm128<<<N_NODES / 32, 256, 0, stream>>>(bufB, W2_0, b2_0, bufA);
    hipMemsetAsync(gsum, 0, H * 4, stream);
    hipMemsetAsync(gss, 0, H * 4, stream);
    k_bnstats<<<256, 256, 0, stream>>>(bufA, gsum, gss);
    k_bnfinal<<<1, 128, 0, stream>>>(gsum, gss, gamma, beta, scale, shift);
    k_bnapply<false><<<N_NODES * H / 4 / 256, 256, 0, stream>>>(bufA, scale, shift, h);

    // ---- layers 1..4 (residual) ----
    for (int l = 0; l < 4; ++l) {
        k_gather128<<<N_NODES / 4, 256, 0, stream>>>(h, row_start, esrc, bufA);
        k_gemm128<<<N_NODES / 32, 256, 0, stream>>>(bufA, W1 + l * H * H, b1 + l * H, bufB);
        k_gemm128<<<N_NODES / 32, 256, 0, stream>>>(bufB, W2 + l * H * H, b2 + l * H, bufA);
        hipMemsetAsync(gsum, 0, H * 4, stream);
        hipMemsetAsync(gss, 0, H * 4, stream);
        k_bnstats<<<256, 256, 0, stream>>>(bufA, gsum, gss);
        k_bnfinal<<<1, 128, 0, stream>>>(gsum, gss, gamma + (l + 1) * H, beta + (l + 1) * H,
                                         scale, shift);
        k_bnapply<true><<<N_NODES * H / 4 / 256, 256, 0, stream>>>(bufA, scale, shift, h);
    }

    // ---- pooling + head ----
    k_bounds<<<(N_NODES + 255) / 256, 256, 0, stream>>>(batch, row_begin);
    k_pool<<<N_GRAPHS, 128, 0, stream>>>(h, row_begin, pooled);
    k_final<<<N_GRAPHS, 128, 0, stream>>>(pooled, Wf, bf, out);
}

// Round 3
// 2072.328 us; speedup vs baseline: 1.6488x; 1.2305x over previous
//
#include <hip/hip_runtime.h>
#include <float.h>

#define N_NODES 100000
#define N_EDGES 3200000
#define N_GRAPHS 1024
#define F_IN 78
#define H 128
#define BN_EPS 1e-5f

#define CHUNK 1024
#define NCHUNK ((N_NODES + CHUNK - 1) / CHUNK)  // 98

#define BK_SHIFT 7
#define BK_NODES 128
#define NBUCKETS ((N_NODES + BK_NODES - 1) / BK_NODES)  // 782

__device__ __forceinline__ unsigned short f2bf(float f) {
    unsigned int u = __float_as_uint(f);
    unsigned int r = (u + 0x7fffu + ((u >> 16) & 1u)) >> 16;
    return (unsigned short)r;
}
__device__ __forceinline__ float bf_lo(unsigned int u) { return __uint_as_float(u << 16); }
__device__ __forceinline__ float bf_hi(unsigned int u) { return __uint_as_float(u & 0xffff0000u); }

// ---------------- CSR build ----------------

__global__ void k_deg(const int* __restrict__ dst, int* __restrict__ deg) {
    int e = blockIdx.x * blockDim.x + threadIdx.x;
    if (e < N_EDGES) atomicAdd(&deg[dst[e]], 1);
}

__global__ void k_chunk_sum(const int* __restrict__ deg, int* __restrict__ csum) {
    __shared__ int sd[256];
    int b = blockIdx.x;
    int s = 0;
    for (int j = threadIdx.x; j < CHUNK; j += 256) {
        int i = b * CHUNK + j;
        s += (i < N_NODES) ? deg[i] : 0;
    }
    sd[threadIdx.x] = s;
    __syncthreads();
    for (int off = 128; off > 0; off >>= 1) {
        if (threadIdx.x < off) sd[threadIdx.x] += sd[threadIdx.x + off];
        __syncthreads();
    }
    if (threadIdx.x == 0) csum[b] = sd[0];
}

__global__ void k_scan_chunks(const int* __restrict__ csum, int* __restrict__ coff,
                              int* __restrict__ row_start) {
    if (threadIdx.x == 0) {
        int acc = 0;
        for (int b = 0; b < NCHUNK; ++b) { coff[b] = acc; acc += csum[b]; }
        row_start[N_NODES] = acc;  // == N_EDGES
    }
}

__global__ void k_scan_within(const int* __restrict__ deg, const int* __restrict__ coff,
                              int* __restrict__ row_start) {
    __shared__ int sd[256];
    int b = blockIdx.x, t = threadIdx.x;
    int base = b * CHUNK + t * 4;
    int loc[4];
    int s = 0;
#pragma unroll
    for (int j = 0; j < 4; ++j) {
        loc[j] = s;
        int i = base + j;
        s += (i < N_NODES) ? deg[i] : 0;
    }
    sd[t] = s;
    __syncthreads();
    if (t == 0) {
        int run = 0;
        for (int u = 0; u < 256; ++u) { int tmp = sd[u]; sd[u] = run; run += tmp; }
    }
    __syncthreads();
    int off = coff[b] + sd[t];
#pragma unroll
    for (int j = 0; j < 4; ++j) {
        int i = base + j;
        if (i < N_NODES) row_start[i] = off + loc[j];
    }
}

// bucket cursors padded to one per 64B line
__global__ void k_binit(const int* __restrict__ row_start, int* __restrict__ bcur) {
    int b = blockIdx.x * blockDim.x + threadIdx.x;
    if (b < NBUCKETS) bcur[b * 16] = row_start[b << BK_SHIFT];
}

// stage 1: scatter (src,dst) into bucket-contiguous regions
__global__ void k_p3(const int* __restrict__ src, const int* __restrict__ dst,
                     int* __restrict__ bcur, int2* __restrict__ ebuf) {
    int e = blockIdx.x * blockDim.x + threadIdx.x;
    if (e < N_EDGES) {
        int d = dst[e];
        int b = d >> BK_SHIFT;
        int p = atomicAdd(&bcur[b * 16], 1);
        ebuf[p] = make_int2(src[e], d);
    }
}

// stage 2: within-bucket final scatter via LDS cursors
__global__ __launch_bounds__(256) void k_p4(const int* __restrict__ row_start,
                                            const int2* __restrict__ ebuf,
                                            int* __restrict__ esrc) {
    __shared__ int cur[BK_NODES];
    int b = blockIdx.x;
    int nodeBase = b << BK_SHIFT;
    int nLocal = min(BK_NODES, N_NODES - nodeBase);
    if (threadIdx.x < nLocal) cur[threadIdx.x] = row_start[nodeBase + threadIdx.x];
    __syncthreads();
    int s = row_start[nodeBase];
    int e = row_start[nodeBase + nLocal];
    for (int p = s + threadIdx.x; p < e; p += 256) {
        int2 ed = ebuf[p];
        int q = atomicAdd(&cur[ed.y - nodeBase], 1);
        esrc[q] = ed.x;
    }
}

// ---------------- bf16 mirrors ----------------

// x [N][78] f32 -> xb [N][80] bf16 (zero padded)
__global__ void k_cast_x(const float* __restrict__ x, unsigned short* __restrict__ xb) {
    int i = blockIdx.x * blockDim.x + threadIdx.x;
    if (i >= N_NODES * 80) return;
    int node = i / 80;
    int c = i - node * 80;
    float v = (c < F_IN) ? x[(size_t)node * F_IN + c] : 0.f;
    xb[i] = f2bf(v);
}

// ---------------- gather (aggregate) kernels ----------------

// layer 0: xb bf16 [N][80]; self term from f32 x; out f32 [N][78]
__global__ void k_gather0(const float* __restrict__ x, const unsigned int* __restrict__ xw,
                          const int* __restrict__ row_start, const int* __restrict__ esrc,
                          float* __restrict__ out) {
    int wave = threadIdx.x >> 6;
    int lane = threadIdx.x & 63;
    int node = blockIdx.x * 4 + wave;
    int s = row_start[node], e = row_start[node + 1];
    bool act = lane < 40;  // dwords per row = 40
    int c0 = 2 * lane, c1 = 2 * lane + 1;
    float s0 = (c0 < F_IN) ? x[(size_t)node * F_IN + c0] : 0.f;
    float s1 = (c1 < F_IN) ? x[(size_t)node * F_IN + c1] : 0.f;
    float a0 = 0.f, b0 = 0.f, a1 = 0.f, b1 = 0.f;
    float a2 = 0.f, b2 = 0.f, a3 = 0.f, b3 = 0.f;
    int p = s;
    for (; p + 8 <= e; p += 8) {
        int i0 = esrc[p + 0], i1 = esrc[p + 1], i2 = esrc[p + 2], i3 = esrc[p + 3];
        int i4 = esrc[p + 4], i5 = esrc[p + 5], i6 = esrc[p + 6], i7 = esrc[p + 7];
        unsigned int u0 = act ? xw[i0 * 40 + lane] : 0u;
        unsigned int u1 = act ? xw[i1 * 40 + lane] : 0u;
        unsigned int u2 = act ? xw[i2 * 40 + lane] : 0u;
        unsigned int u3 = act ? xw[i3 * 40 + lane] : 0u;
        unsigned int u4 = act ? xw[i4 * 40 + lane] : 0u;
        unsigned int u5 = act ? xw[i5 * 40 + lane] : 0u;
        unsigned int u6 = act ? xw[i6 * 40 + lane] : 0u;
        unsigned int u7 = act ? xw[i7 * 40 + lane] : 0u;
        a0 += bf_lo(u0); b0 += bf_hi(u0); a1 += bf_lo(u1); b1 += bf_hi(u1);
        a2 += bf_lo(u2); b2 += bf_hi(u2); a3 += bf_lo(u3); b3 += bf_hi(u3);
        a0 += bf_lo(u4); b0 += bf_hi(u4); a1 += bf_lo(u5); b1 += bf_hi(u5);
        a2 += bf_lo(u6); b2 += bf_hi(u6); a3 += bf_lo(u7); b3 += bf_hi(u7);
    }
    for (; p < e; ++p) {
        unsigned int u = act ? xw[esrc[p] * 40 + lane] : 0u;
        a0 += bf_lo(u); b0 += bf_hi(u);
    }
    float r0 = s0 + (a0 + a1) + (a2 + a3);
    float r1 = s1 + (b0 + b1) + (b2 + b3);
    if (lane < 39) {
        float2 r = make_float2(r0, r1);
        *reinterpret_cast<float2*>(&out[(size_t)node * F_IN + c0]) = r;
    }
}

// layers 1..4: hb bf16 [N][128]; self from f32 h; out f32 [N][128]
__global__ void k_gather128b(const float* __restrict__ h, const unsigned int* __restrict__ hw,
                             const int* __restrict__ row_start, const int* __restrict__ esrc,
                             float* __restrict__ out) {
    int wave = threadIdx.x >> 6;
    int lane = threadIdx.x & 63;
    int node = blockIdx.x * 4 + wave;
    int s = row_start[node], e = row_start[node + 1];
    float2 self = reinterpret_cast<const float2*>(h)[node * 64 + lane];
    float a0 = 0.f, b0 = 0.f, a1 = 0.f, b1 = 0.f;
    float a2 = 0.f, b2 = 0.f, a3 = 0.f, b3 = 0.f;
    int p = s;
    for (; p + 8 <= e; p += 8) {
        int i0 = esrc[p + 0], i1 = esrc[p + 1], i2 = esrc[p + 2], i3 = esrc[p + 3];
        int i4 = esrc[p + 4], i5 = esrc[p + 5], i6 = esrc[p + 6], i7 = esrc[p + 7];
        unsigned int u0 = hw[i0 * 64 + lane];
        unsigned int u1 = hw[i1 * 64 + lane];
        unsigned int u2 = hw[i2 * 64 + lane];
        unsigned int u3 = hw[i3 * 64 + lane];
        unsigned int u4 = hw[i4 * 64 + lane];
        unsigned int u5 = hw[i5 * 64 + lane];
        unsigned int u6 = hw[i6 * 64 + lane];
        unsigned int u7 = hw[i7 * 64 + lane];
        a0 += bf_lo(u0); b0 += bf_hi(u0); a1 += bf_lo(u1); b1 += bf_hi(u1);
        a2 += bf_lo(u2); b2 += bf_hi(u2); a3 += bf_lo(u3); b3 += bf_hi(u3);
        a0 += bf_lo(u4); b0 += bf_hi(u4); a1 += bf_lo(u5); b1 += bf_hi(u5);
        a2 += bf_lo(u6); b2 += bf_hi(u6); a3 += bf_lo(u7); b3 += bf_hi(u7);
    }
    for (; p < e; ++p) {
        unsigned int u = hw[esrc[p] * 64 + lane];
        a0 += bf_lo(u); b0 += bf_hi(u);
    }
    float2 r;
    r.x = self.x + (a0 + a1) + (a2 + a3);
    r.y = self.y + (b0 + b1) + (b2 + b3);
    reinterpret_cast<float2*>(out)[node * 64 + lane] = r;
}

// ---------------- GEMM kernels ----------------

// K=128: 32 rows/block, thread = 4 rows x 4 cols; optional fused BN-stats
template <bool STATS>
__global__ __launch_bounds__(256) void k_gemm128(const float* __restrict__ in,
                                                 const float* __restrict__ W,
                                                 const float* __restrict__ bias,
                                                 float* __restrict__ out,
                                                 float* __restrict__ gsum,
                                                 float* __restrict__ gss) {
    __shared__ float xs[32][128];
    int rp = threadIdx.x >> 5;
    int c0 = (threadIdx.x & 31) * 4;
    int rowBase = blockIdx.x * 32;
    const float4* in4 = (const float4*)(in + (size_t)rowBase * 128);
    float4* xs4 = (float4*)xs;
#pragma unroll
    for (int i = 0; i < 4; ++i) xs4[threadIdx.x + i * 256] = in4[threadIdx.x + i * 256];
    __syncthreads();
    float4 b4 = *(const float4*)&bias[c0];
    float acc[4][4];
#pragma unroll
    for (int i = 0; i < 4; ++i) {
        acc[i][0] = b4.x; acc[i][1] = b4.y; acc[i][2] = b4.z; acc[i][3] = b4.w;
    }
    for (int k = 0; k < 128; k += 4) {
        float4 a[4], w[4];
#pragma unroll
        for (int i = 0; i < 4; ++i) a[i] = *(const float4*)&xs[4 * rp + i][k];
#pragma unroll
        for (int j = 0; j < 4; ++j) w[j] = *(const float4*)&W[(k + j) * H + c0];
#pragma unroll
        for (int i = 0; i < 4; ++i) {
            const float* ai = (const float*)&a[i];
#pragma unroll
            for (int j = 0; j < 4; ++j) {
                const float* wj = (const float*)&w[j];
                acc[i][0] += ai[j] * wj[0];
                acc[i][1] += ai[j] * wj[1];
                acc[i][2] += ai[j] * wj[2];
                acc[i][3] += ai[j] * wj[3];
            }
        }
    }
    float s_[4] = {0.f, 0.f, 0.f, 0.f}, q_[4] = {0.f, 0.f, 0.f, 0.f};
#pragma unroll
    for (int i = 0; i < 4; ++i) {
        int r = rowBase + 4 * rp + i;
        float o0 = fmaxf(acc[i][0], 0.f);
        float o1 = fmaxf(acc[i][1], 0.f);
        float o2 = fmaxf(acc[i][2], 0.f);
        float o3 = fmaxf(acc[i][3], 0.f);
        float4 o = make_float4(o0, o1, o2, o3);
        *reinterpret_cast<float4*>(&out[(size_t)r * H + c0]) = o;
        if (STATS) {
            s_[0] += o0; s_[1] += o1; s_[2] += o2; s_[3] += o3;
            q_[0] += o0 * o0; q_[1] += o1 * o1; q_[2] += o2 * o2; q_[3] += o3 * o3;
        }
    }
    if (STATS) {
        __syncthreads();
        float* red = &xs[0][0];  // reuse LDS: [0..1023] sums, [1024..2047] sq
#pragma unroll
        for (int j = 0; j < 4; ++j) {
            red[rp * 128 + c0 + j] = s_[j];
            red[1024 + rp * 128 + c0 + j] = q_[j];
        }
        __syncthreads();
        if (threadIdx.x < 128) {
            int c = threadIdx.x;
            float s = 0.f, q = 0.f;
#pragma unroll
            for (int r = 0; r < 8; ++r) {
                s += red[r * 128 + c];
                q += red[1024 + r * 128 + c];
            }
            atomicAdd(&gsum[c], s);
            atomicAdd(&gss[c], q);
        }
    }
}

// generic-K (layer 0 first GEMM, K=78)
template <int K>
__global__ __launch_bounds__(256) void k_gemm(const float* __restrict__ in,
                                              const float* __restrict__ W,
                                              const float* __restrict__ bias,
                                              float* __restrict__ out) {
    __shared__ float xs[16][K];
    int c0 = (threadIdx.x & 31) * 4;
    int rp = threadIdx.x >> 5;
    int rowBase = blockIdx.x * 16;
    for (int idx = threadIdx.x; idx < 16 * K; idx += 256) {
        int r = idx / K, k = idx - r * K;
        xs[r][k] = in[(size_t)(rowBase + r) * K + k];
    }
    __syncthreads();
    float4 b4 = *reinterpret_cast<const float4*>(&bias[c0]);
    float acc[2][4];
    acc[0][0] = b4.x; acc[0][1] = b4.y; acc[0][2] = b4.z; acc[0][3] = b4.w;
    acc[1][0] = b4.x; acc[1][1] = b4.y; acc[1][2] = b4.z; acc[1][3] = b4.w;
#pragma unroll 4
    for (int k = 0; k < K; ++k) {
        float4 w = *reinterpret_cast<const float4*>(&W[k * H + c0]);
        float a0 = xs[2 * rp][k];
        float a1 = xs[2 * rp + 1][k];
        acc[0][0] += a0 * w.x; acc[0][1] += a0 * w.y; acc[0][2] += a0 * w.z; acc[0][3] += a0 * w.w;
        acc[1][0] += a1 * w.x; acc[1][1] += a1 * w.y; acc[1][2] += a1 * w.z; acc[1][3] += a1 * w.w;
    }
#pragma unroll
    for (int i = 0; i < 2; ++i) {
        int r = rowBase + 2 * rp + i;
        float4 o;
        o.x = fmaxf(acc[i][0], 0.f);
        o.y = fmaxf(acc[i][1], 0.f);
        o.z = fmaxf(acc[i][2], 0.f);
        o.w = fmaxf(acc[i][3], 0.f);
        *reinterpret_cast<float4*>(&out[(size_t)r * H + c0]) = o;
    }
}

// ---------------- BN ----------------

__global__ void k_bnfinal(const float* __restrict__ gsum, const float* __restrict__ gss,
                          const float* __restrict__ gamma, const float* __restrict__ beta,
                          float* __restrict__ scale, float* __restrict__ shift) {
    int c = threadIdx.x;
    const float inv_n = 1.f / (float)N_NODES;
    float mu = gsum[c] * inv_n;
    float var = fmaxf(gss[c] * inv_n - mu * mu, 0.f);
    float sc = gamma[c] * rsqrtf(var + BN_EPS);
    scale[c] = sc;
    shift[c] = beta[c] - mu * sc;
}

// h = (RES? h:0) + v*scale+shift ; optionally write bf16 mirror hb
template <bool RES, bool WB>
__global__ void k_bnapply(const float* __restrict__ v, const float* __restrict__ scale,
                          const float* __restrict__ shift, float* __restrict__ h,
                          uint2* __restrict__ hb) {
    int idx = blockIdx.x * blockDim.x + threadIdx.x;  // float4 index
    if (idx >= N_NODES * H / 4) return;
    int c4 = idx & 31;
    float4 val = reinterpret_cast<const float4*>(v)[idx];
    float4 sc = reinterpret_cast<const float4*>(scale)[c4];
    float4 sh = reinterpret_cast<const float4*>(shift)[c4];
    float4 r;
    r.x = val.x * sc.x + sh.x;
    r.y = val.y * sc.y + sh.y;
    r.z = val.z * sc.z + sh.z;
    r.w = val.w * sc.w + sh.w;
    if (RES) {
        float4 hv = reinterpret_cast<float4*>(h)[idx];
        r.x += hv.x; r.y += hv.y; r.z += hv.z; r.w += hv.w;
    }
    reinterpret_cast<float4*>(h)[idx] = r;
    if (WB) {
        uint2 pk;
        pk.x = (unsigned int)f2bf(r.x) | ((unsigned int)f2bf(r.y) << 16);
        pk.y = (unsigned int)f2bf(r.z) | ((unsigned int)f2bf(r.w) << 16);
        hb[idx] = pk;
    }
}

// ---------------- pooling + head ----------------

__global__ void k_bounds(const int* __restrict__ batch, int* __restrict__ row_begin) {
    int i = blockIdx.x * blockDim.x + threadIdx.x;
    if (i >= N_NODES) return;
    int bi = batch[i];
    int bp = (i == 0) ? -1 : batch[i - 1];
    for (int g = bp + 1; g <= bi; ++g) row_begin[g] = i;
    if (i == N_NODES - 1) {
        for (int g = bi + 1; g <= N_GRAPHS; ++g) row_begin[g] = N_NODES;
    }
}

__global__ void k_pool(const float* __restrict__ h, const int* __restrict__ row_begin,
                       float* __restrict__ pooled) {
    int g = blockIdx.x;
    int c = threadIdx.x;  // 128
    int s = row_begin[g], e = row_begin[g + 1];
    float sum = 0.f, mx = -FLT_MAX;
    for (int i = s; i < e; ++i) {
        float v = h[(size_t)i * H + c];
        sum += v;
        mx = fmaxf(mx, v);
    }
    int cnt = e - s;
    pooled[g * 256 + c]       = (cnt > 0) ? sum / (float)cnt : 0.f;
    pooled[g * 256 + 128 + c] = (cnt > 0) ? mx : 0.f;
}

__global__ void k_final(const float* __restrict__ pooled, const float* __restrict__ Wf,
                        const float* __restrict__ bf, float* __restrict__ out) {
    __shared__ float ps[256];
    int g = blockIdx.x, c = threadIdx.x;  // 128 threads
    ps[c] = pooled[g * 256 + c];
    ps[128 + c] = pooled[g * 256 + 128 + c];
    __syncthreads();
    float acc = bf[c];
#pragma unroll 8
    for (int k = 0; k < 256; ++k) acc += ps[k] * Wf[k * H + c];
    out[g * H + c] = acc;
}

// ---------------- launcher ----------------

extern "C" void kernel_launch(void* const* d_in, const int* in_sizes, int n_in,
                              void* d_out, int out_size, void* d_ws, size_t ws_size,
                              hipStream_t stream) {
    const float* x     = (const float*)d_in[0];
    const int*   ei    = (const int*)d_in[1];
    const int*   src   = ei;
    const int*   dst   = ei + N_EDGES;
    const int*   batch = (const int*)d_in[2];
    const float* W1_0  = (const float*)d_in[3];
    const float* b1_0  = (const float*)d_in[4];
    const float* W2_0  = (const float*)d_in[5];
    const float* b2_0  = (const float*)d_in[6];
    const float* W1    = (const float*)d_in[7];
    const float* b1    = (const float*)d_in[8];
    const float* W2    = (const float*)d_in[9];
    const float* b2    = (const float*)d_in[10];
    const float* gamma = (const float*)d_in[11];
    const float* beta  = (const float*)d_in[12];
    const float* Wf    = (const float*)d_in[13];
    const float* bf    = (const float*)d_in[14];
    float* out = (float*)d_out;

    char* ws = (char*)d_ws;
    size_t off = 0;
    auto alloc = [&](size_t bytes) -> void* {
        void* p = ws + off;
        off = (off + bytes + 255) & ~(size_t)255;
        return p;
    };

    float* h    = (float*)alloc((size_t)N_NODES * H * 4);
    float* bufA = (float*)alloc((size_t)N_NODES * H * 4);
    float* bufB = (float*)alloc((size_t)N_NODES * H * 4);
    uint2* hb   = (uint2*)alloc((size_t)N_NODES * H * 2);        // bf16 mirror of h
    unsigned short* xb = (unsigned short*)alloc((size_t)N_NODES * 80 * 2);  // bf16 x padded
    int* deg       = (int*)alloc((size_t)N_NODES * 4);
    int* row_start = (int*)alloc((size_t)(N_NODES + 1) * 4);
    int* esrc      = (int*)alloc((size_t)N_EDGES * 4);
    int2* ebuf     = (int2*)alloc((size_t)N_EDGES * 8);
    int* bcur      = (int*)alloc((size_t)NBUCKETS * 16 * 4);
    int* csum      = (int*)alloc((size_t)NCHUNK * 4);
    int* coff      = (int*)alloc((size_t)NCHUNK * 4);
    float* gsum  = (float*)alloc(H * 4);
    float* gss   = (float*)alloc(H * 4);
    float* scale = (float*)alloc(H * 4);
    float* shift = (float*)alloc(H * 4);
    int* row_begin = (int*)alloc((size_t)(N_GRAPHS + 1) * 4);
    float* pooled  = (float*)alloc((size_t)N_GRAPHS * 256 * 4);

    // ---- bf16 copy of x (overlaps CSR build) ----
    k_cast_x<<<(N_NODES * 80 + 255) / 256, 256, 0, stream>>>(x, xb);

    // ---- CSR build ----
    hipMemsetAsync(deg, 0, (size_t)N_NODES * 4, stream);
    k_deg<<<N_EDGES / 256, 256, 0, stream>>>(dst, deg);
    k_chunk_sum<<<NCHUNK, 256, 0, stream>>>(deg, csum);
    k_scan_chunks<<<1, 64, 0, stream>>>(csum, coff, row_start);
    k_scan_within<<<NCHUNK, 256, 0, stream>>>(deg, coff, row_start);
    k_binit<<<(NBUCKETS + 255) / 256, 256, 0, stream>>>(row_start, bcur);
    k_p3<<<N_EDGES / 256, 256, 0, stream>>>(src, dst, bcur, ebuf);
    k_p4<<<NBUCKETS, 256, 0, stream>>>(row_start, ebuf, esrc);

    // ---- layer 0 (78 -> 128, no residual) ----
    k_gather0<<<N_NODES / 4, 256, 0, stream>>>(x, (const unsigned int*)xb, row_start, esrc, bufA);
    k_gemm<F_IN><<<N_NODES / 16, 256, 0, stream>>>(bufA, W1_0, b1_0, bufB);
    hipMemsetAsync(gsum, 0, H * 4, stream);
    hipMemsetAsync(gss, 0, H * 4, stream);
    k_gemm128<true><<<N_NODES / 32, 256, 0, stream>>>(bufB, W2_0, b2_0, bufA, gsum, gss);
    k_bnfinal<<<1, 128, 0, stream>>>(gsum, gss, gamma, beta, scale, shift);
    k_bnapply<false, true><<<N_NODES * H / 4 / 256, 256, 0, stream>>>(bufA, scale, shift, h, hb);

    // ---- layers 1..4 (residual) ----
    for (int l = 0; l < 4; ++l) {
        k_gather128b<<<N_NODES / 4, 256, 0, stream>>>(h, (const unsigned int*)hb, row_start,
                                                      esrc, bufA);
        k_gemm128<false><<<N_NODES / 32, 256, 0, stream>>>(bufA, W1 + l * H * H, b1 + l * H,
                                                           bufB, nullptr, nullptr);
        hipMemsetAsync(gsum, 0, H * 4, stream);
        hipMemsetAsync(gss, 0, H * 4, stream);
        k_gemm128<true><<<N_NODES / 32, 256, 0, stream>>>(bufB, W2 + l * H * H, b2 + l * H,
                                                          bufA, gsum, gss);
        k_bnfinal<<<1, 128, 0, stream>>>(gsum, gss, gamma + (l + 1) * H, beta + (l + 1) * H,
                                         scale, shift);
        if (l < 3) {
            k_bnapply<true, true><<<N_NODES * H / 4 / 256, 256, 0, stream>>>(bufA, scale, shift,
                                                                             h, hb);
        } else {
            k_bnapply<true, false><<<N_NODES * H / 4 / 256, 256, 0, stream>>>(bufA, scale, shift,
                                                                              h, hb);
        }
    }

    // ---- pooling + head ----
    k_bounds<<<(N_NODES + 255) / 256, 256, 0, stream>>>(batch, row_begin);
    k_pool<<<N_GRAPHS, 128, 0, stream>>>(h, row_begin, pooled);
    k_final<<<N_GRAPHS, 128, 0, stream>>>(pooled, Wf, bf, out);
}

// Round 4
// 1841.628 us; speedup vs baseline: 1.8553x; 1.1253x over previous
//
#include <hip/hip_runtime.h>
#include <float.h>

#define N_NODES 100000
#define N_EDGES 3200000
#define N_GRAPHS 1024
#define F_IN 78
#define H 128
#define BN_EPS 1e-5f

#define CHUNK 1024
#define NCHUNK ((N_NODES + CHUNK - 1) / CHUNK)  // 98

#define BK_SHIFT 7
#define BK_NODES 128
#define NBUCKETS ((N_NODES + BK_NODES - 1) / BK_NODES)  // 782

using short8 = __attribute__((ext_vector_type(8))) short;
using f32x4v = __attribute__((ext_vector_type(4))) float;

__device__ __forceinline__ unsigned short f2bf(float f) {
    unsigned int u = __float_as_uint(f);
    unsigned int r = (u + 0x7fffu + ((u >> 16) & 1u)) >> 16;
    return (unsigned short)r;
}
__device__ __forceinline__ float bf_lo(unsigned int u) { return __uint_as_float(u << 16); }
__device__ __forceinline__ float bf_hi(unsigned int u) { return __uint_as_float(u & 0xffff0000u); }

// ---------------- CSR build ----------------

// fused: node degrees + per-(bucket,sub) counts, sub = blockIdx&7 (XCD proxy)
__global__ void k_deg_cnt(const int* __restrict__ dst, int* __restrict__ deg,
                          int* __restrict__ cnt) {
    int e = blockIdx.x * blockDim.x + threadIdx.x;
    if (e < N_EDGES) {
        int d = dst[e];
        atomicAdd(&deg[d], 1);
        atomicAdd(&cnt[(d >> BK_SHIFT) * 8 + (blockIdx.x & 7)], 1);
    }
}

__global__ void k_chunk_sum(const int* __restrict__ deg, int* __restrict__ csum) {
    __shared__ int sd[256];
    int b = blockIdx.x;
    int s = 0;
    for (int j = threadIdx.x; j < CHUNK; j += 256) {
        int i = b * CHUNK + j;
        s += (i < N_NODES) ? deg[i] : 0;
    }
    sd[threadIdx.x] = s;
    __syncthreads();
    for (int off = 128; off > 0; off >>= 1) {
        if (threadIdx.x < off) sd[threadIdx.x] += sd[threadIdx.x + off];
        __syncthreads();
    }
    if (threadIdx.x == 0) csum[b] = sd[0];
}

__global__ void k_scan_chunks(const int* __restrict__ csum, int* __restrict__ coff,
                              int* __restrict__ row_start) {
    if (threadIdx.x == 0) {
        int acc = 0;
        for (int b = 0; b < NCHUNK; ++b) { coff[b] = acc; acc += csum[b]; }
        row_start[N_NODES] = acc;  // == N_EDGES
    }
}

__global__ void k_scan_within(const int* __restrict__ deg, const int* __restrict__ coff,
                              int* __restrict__ row_start) {
    __shared__ int sd[256];
    int b = blockIdx.x, t = threadIdx.x;
    int base = b * CHUNK + t * 4;
    int loc[4];
    int s = 0;
#pragma unroll
    for (int j = 0; j < 4; ++j) {
        loc[j] = s;
        int i = base + j;
        s += (i < N_NODES) ? deg[i] : 0;
    }
    sd[t] = s;
    __syncthreads();
    if (t == 0) {
        int run = 0;
        for (int u = 0; u < 256; ++u) { int tmp = sd[u]; sd[u] = run; run += tmp; }
    }
    __syncthreads();
    int off = coff[b] + sd[t];
#pragma unroll
    for (int j = 0; j < 4; ++j) {
        int i = base + j;
        if (i < N_NODES) row_start[i] = off + loc[j];
    }
}

// per-(bucket,sub) region start cursors, padded one per 64B line
__global__ void k_boff(const int* __restrict__ row_start, const int* __restrict__ cnt,
                       int* __restrict__ bcur) {
    int b = blockIdx.x * blockDim.x + threadIdx.x;
    if (b < NBUCKETS) {
        int base = row_start[b << BK_SHIFT];
#pragma unroll
        for (int s = 0; s < 8; ++s) {
            bcur[(b * 8 + s) * 16] = base;
            base += cnt[b * 8 + s];
        }
    }
}

// stage 1: scatter (src,dst) into (bucket,sub)-contiguous regions
__global__ void k_p3(const int* __restrict__ src, const int* __restrict__ dst,
                     int* __restrict__ bcur, int2* __restrict__ ebuf) {
    int e = blockIdx.x * blockDim.x + threadIdx.x;
    int sub = blockIdx.x & 7;
    if (e < N_EDGES) {
        int d = dst[e];
        int p = atomicAdd(&bcur[((d >> BK_SHIFT) * 8 + sub) * 16], 1);
        ebuf[p] = make_int2(src[e], d);
    }
}

// stage 2: within-bucket final scatter via LDS cursors
__global__ __launch_bounds__(256) void k_p4(const int* __restrict__ row_start,
                                            const int2* __restrict__ ebuf,
                                            int* __restrict__ esrc) {
    __shared__ int cur[BK_NODES];
    int b = blockIdx.x;
    int nodeBase = b << BK_SHIFT;
    int nLocal = min(BK_NODES, N_NODES - nodeBase);
    if (threadIdx.x < nLocal) cur[threadIdx.x] = row_start[nodeBase + threadIdx.x];
    __syncthreads();
    int s = row_start[nodeBase];
    int e = row_start[nodeBase + nLocal];
    for (int p = s + threadIdx.x; p < e; p += 256) {
        int2 ed = ebuf[p];
        int q = atomicAdd(&cur[ed.y - nodeBase], 1);
        esrc[q] = ed.x;
    }
}

// ---------------- bf16 prep ----------------

// x [N][78] f32 -> xb [N][80] bf16 (zero padded)
__global__ void k_cast_x(const float* __restrict__ x, unsigned short* __restrict__ xb) {
    int i = blockIdx.x * blockDim.x + threadIdx.x;
    if (i >= N_NODES * 80) return;
    int node = i / 80;
    int c = i - node * 80;
    float v = (c < F_IN) ? x[(size_t)node * F_IN + c] : 0.f;
    xb[i] = f2bf(v);
}

// transpose+cast the 9 H x H weights: Wtall[w][n][k] = W_w[k][n]
__global__ void k_cast_w(const float* __restrict__ W2_0, const float* __restrict__ W1,
                         const float* __restrict__ W2, unsigned short* __restrict__ Wt) {
    int i = blockIdx.x * blockDim.x + threadIdx.x;
    if (i >= 9 * H * H) return;
    int w = i >> 14, r = i & 16383;
    int n = r >> 7, k = r & 127;
    const float* s = (w == 0) ? W2_0 : (w <= 4 ? W1 + (w - 1) * H * H : W2 + (w - 5) * H * H);
    Wt[i] = f2bf(s[k * H + n]);
}

// ---------------- gather (aggregate) kernels ----------------

// layer 0: xb bf16 [N][80]; self term from f32 x; out f32 [N][78]
__global__ void k_gather0(const float* __restrict__ x, const unsigned int* __restrict__ xw,
                          const int* __restrict__ row_start, const int* __restrict__ esrc,
                          float* __restrict__ out) {
    int wave = threadIdx.x >> 6;
    int lane = threadIdx.x & 63;
    int node = blockIdx.x * 4 + wave;
    int s = row_start[node], e = row_start[node + 1];
    bool act = lane < 40;  // dwords per row = 40
    int c0 = 2 * lane, c1 = 2 * lane + 1;
    float s0 = (c0 < F_IN) ? x[(size_t)node * F_IN + c0] : 0.f;
    float s1 = (c1 < F_IN) ? x[(size_t)node * F_IN + c1] : 0.f;
    float a0 = 0.f, b0 = 0.f, a1 = 0.f, b1 = 0.f;
    float a2 = 0.f, b2 = 0.f, a3 = 0.f, b3 = 0.f;
    int p = s;
    for (; p + 8 <= e; p += 8) {
        int i0 = esrc[p + 0], i1 = esrc[p + 1], i2 = esrc[p + 2], i3 = esrc[p + 3];
        int i4 = esrc[p + 4], i5 = esrc[p + 5], i6 = esrc[p + 6], i7 = esrc[p + 7];
        unsigned int u0 = act ? xw[i0 * 40 + lane] : 0u;
        unsigned int u1 = act ? xw[i1 * 40 + lane] : 0u;
        unsigned int u2 = act ? xw[i2 * 40 + lane] : 0u;
        unsigned int u3 = act ? xw[i3 * 40 + lane] : 0u;
        unsigned int u4 = act ? xw[i4 * 40 + lane] : 0u;
        unsigned int u5 = act ? xw[i5 * 40 + lane] : 0u;
        unsigned int u6 = act ? xw[i6 * 40 + lane] : 0u;
        unsigned int u7 = act ? xw[i7 * 40 + lane] : 0u;
        a0 += bf_lo(u0); b0 += bf_hi(u0); a1 += bf_lo(u1); b1 += bf_hi(u1);
        a2 += bf_lo(u2); b2 += bf_hi(u2); a3 += bf_lo(u3); b3 += bf_hi(u3);
        a0 += bf_lo(u4); b0 += bf_hi(u4); a1 += bf_lo(u5); b1 += bf_hi(u5);
        a2 += bf_lo(u6); b2 += bf_hi(u6); a3 += bf_lo(u7); b3 += bf_hi(u7);
    }
    for (; p < e; ++p) {
        unsigned int u = act ? xw[esrc[p] * 40 + lane] : 0u;
        a0 += bf_lo(u); b0 += bf_hi(u);
    }
    float r0 = s0 + (a0 + a1) + (a2 + a3);
    float r1 = s1 + (b0 + b1) + (b2 + b3);
    if (lane < 39) {
        float2 r = make_float2(r0, r1);
        *reinterpret_cast<float2*>(&out[(size_t)node * F_IN + c0]) = r;
    }
}

// layers 1..4: hb bf16 [N][128]; self from f32 h; out bf16 [N][128]
__global__ void k_gather128b(const float* __restrict__ h, const unsigned int* __restrict__ hw,
                             const int* __restrict__ row_start, const int* __restrict__ esrc,
                             unsigned int* __restrict__ aggb) {
    int wave = threadIdx.x >> 6;
    int lane = threadIdx.x & 63;
    int node = blockIdx.x * 4 + wave;
    int s = row_start[node], e = row_start[node + 1];
    float2 self = reinterpret_cast<const float2*>(h)[node * 64 + lane];
    float a0 = 0.f, b0 = 0.f, a1 = 0.f, b1 = 0.f;
    float a2 = 0.f, b2 = 0.f, a3 = 0.f, b3 = 0.f;
    int p = s;
    for (; p + 8 <= e; p += 8) {
        int i0 = esrc[p + 0], i1 = esrc[p + 1], i2 = esrc[p + 2], i3 = esrc[p + 3];
        int i4 = esrc[p + 4], i5 = esrc[p + 5], i6 = esrc[p + 6], i7 = esrc[p + 7];
        unsigned int u0 = hw[i0 * 64 + lane];
        unsigned int u1 = hw[i1 * 64 + lane];
        unsigned int u2 = hw[i2 * 64 + lane];
        unsigned int u3 = hw[i3 * 64 + lane];
        unsigned int u4 = hw[i4 * 64 + lane];
        unsigned int u5 = hw[i5 * 64 + lane];
        unsigned int u6 = hw[i6 * 64 + lane];
        unsigned int u7 = hw[i7 * 64 + lane];
        a0 += bf_lo(u0); b0 += bf_hi(u0); a1 += bf_lo(u1); b1 += bf_hi(u1);
        a2 += bf_lo(u2); b2 += bf_hi(u2); a3 += bf_lo(u3); b3 += bf_hi(u3);
        a0 += bf_lo(u4); b0 += bf_hi(u4); a1 += bf_lo(u5); b1 += bf_hi(u5);
        a2 += bf_lo(u6); b2 += bf_hi(u6); a3 += bf_lo(u7); b3 += bf_hi(u7);
    }
    for (; p < e; ++p) {
        unsigned int u = hw[esrc[p] * 64 + lane];
        a0 += bf_lo(u); b0 += bf_hi(u);
    }
    float rx = self.x + (a0 + a1) + (a2 + a3);
    float ry = self.y + (b0 + b1) + (b2 + b3);
    aggb[node * 64 + lane] = (unsigned int)f2bf(rx) | ((unsigned int)f2bf(ry) << 16);
}

// ---------------- MFMA GEMMs (bf16 in, f32 acc) ----------------
// A [N][128] bf16 row-major; Wt [128 n][128 k] bf16; tile: block=4 waves x 16 rows.
// A-frag: lane l -> row r0+(l&15), k = ks*32 + (l>>4)*8 + j  (one 16B chunk)
// B-frag: lane l -> col n*16+(l&15), same k slice from Wt row
// C/D:    col = l&15 (+n*16), row = r0 + (l>>4)*4 + reg

// GEMM1: out = relu(A @ W + b) as bf16
__global__ __launch_bounds__(256) void k_mfma1(const short* __restrict__ A,
                                               const short* __restrict__ Wt,
                                               const float* __restrict__ bias,
                                               unsigned short* __restrict__ out) {
    int wave = threadIdx.x >> 6, lane = threadIdx.x & 63;
    int r0 = blockIdx.x * 64 + wave * 16;
    int lm = lane & 15, lk = lane >> 4;
    int arow = r0 + lm;
    if (arow >= N_NODES) arow = N_NODES - 1;
    const short8* Arow = (const short8*)(A + (size_t)arow * H);
    f32x4v acc[8];
#pragma unroll
    for (int n = 0; n < 8; ++n) {
        float bv = bias[n * 16 + lm];
        acc[n] = (f32x4v){bv, bv, bv, bv};
    }
#pragma unroll
    for (int ks = 0; ks < 4; ++ks) {
        short8 af = Arow[ks * 4 + lk];
#pragma unroll
        for (int n = 0; n < 8; ++n) {
            const short8* Brow = (const short8*)(Wt + (size_t)(n * 16 + lm) * H);
            short8 bfr = Brow[ks * 4 + lk];
            acc[n] = __builtin_amdgcn_mfma_f32_16x16x32_bf16(af, bfr, acc[n], 0, 0, 0);
        }
    }
#pragma unroll
    for (int n = 0; n < 8; ++n) {
        int col = n * 16 + lm;
#pragma unroll
        for (int rg = 0; rg < 4; ++rg) {
            int r = r0 + lk * 4 + rg;
            if (r < N_NODES) {
                float v = fmaxf(acc[n][rg], 0.f);
                out[(size_t)r * H + col] = f2bf(v);
            }
        }
    }
}

// GEMM2: out = relu(A @ W + b) as f32, fused BN stats
__global__ __launch_bounds__(256) void k_mfma2(const short* __restrict__ A,
                                               const short* __restrict__ Wt,
                                               const float* __restrict__ bias,
                                               float* __restrict__ out,
                                               float* __restrict__ gsum,
                                               float* __restrict__ gss) {
    __shared__ float lsum[H], lss[H];
    if (threadIdx.x < H) { lsum[threadIdx.x] = 0.f; lss[threadIdx.x] = 0.f; }
    __syncthreads();
    int wave = threadIdx.x >> 6, lane = threadIdx.x & 63;
    int r0 = blockIdx.x * 64 + wave * 16;
    int lm = lane & 15, lk = lane >> 4;
    int arow = r0 + lm;
    if (arow >= N_NODES) arow = N_NODES - 1;
    const short8* Arow = (const short8*)(A + (size_t)arow * H);
    f32x4v acc[8];
#pragma unroll
    for (int n = 0; n < 8; ++n) {
        float bv = bias[n * 16 + lm];
        acc[n] = (f32x4v){bv, bv, bv, bv};
    }
#pragma unroll
    for (int ks = 0; ks < 4; ++ks) {
        short8 af = Arow[ks * 4 + lk];
#pragma unroll
        for (int n = 0; n < 8; ++n) {
            const short8* Brow = (const short8*)(Wt + (size_t)(n * 16 + lm) * H);
            short8 bfr = Brow[ks * 4 + lk];
            acc[n] = __builtin_amdgcn_mfma_f32_16x16x32_bf16(af, bfr, acc[n], 0, 0, 0);
        }
    }
#pragma unroll
    for (int n = 0; n < 8; ++n) {
        int col = n * 16 + lm;
        float s = 0.f, q = 0.f;
#pragma unroll
        for (int rg = 0; rg < 4; ++rg) {
            int r = r0 + lk * 4 + rg;
            if (r < N_NODES) {
                float v = fmaxf(acc[n][rg], 0.f);
                out[(size_t)r * H + col] = v;
                s += v;
                q += v * v;
            }
        }
        atomicAdd(&lsum[col], s);
        atomicAdd(&lss[col], q);
    }
    __syncthreads();
    if (threadIdx.x < H) {
        atomicAdd(&gsum[threadIdx.x], lsum[threadIdx.x]);
        atomicAdd(&gss[threadIdx.x], lss[threadIdx.x]);
    }
}

// generic-K f32 (layer 0 first GEMM, K=78) -> bf16 out
template <int K>
__global__ __launch_bounds__(256) void k_gemm78(const float* __restrict__ in,
                                                const float* __restrict__ W,
                                                const float* __restrict__ bias,
                                                unsigned short* __restrict__ out) {
    __shared__ float xs[16][K];
    int c0 = (threadIdx.x & 31) * 4;
    int rp = threadIdx.x >> 5;
    int rowBase = blockIdx.x * 16;
    for (int idx = threadIdx.x; idx < 16 * K; idx += 256) {
        int r = idx / K, k = idx - r * K;
        xs[r][k] = in[(size_t)(rowBase + r) * K + k];
    }
    __syncthreads();
    float4 b4 = *reinterpret_cast<const float4*>(&bias[c0]);
    float acc[2][4];
    acc[0][0] = b4.x; acc[0][1] = b4.y; acc[0][2] = b4.z; acc[0][3] = b4.w;
    acc[1][0] = b4.x; acc[1][1] = b4.y; acc[1][2] = b4.z; acc[1][3] = b4.w;
#pragma unroll 4
    for (int k = 0; k < K; ++k) {
        float4 w = *reinterpret_cast<const float4*>(&W[k * H + c0]);
        float a0 = xs[2 * rp][k];
        float a1 = xs[2 * rp + 1][k];
        acc[0][0] += a0 * w.x; acc[0][1] += a0 * w.y; acc[0][2] += a0 * w.z; acc[0][3] += a0 * w.w;
        acc[1][0] += a1 * w.x; acc[1][1] += a1 * w.y; acc[1][2] += a1 * w.z; acc[1][3] += a1 * w.w;
    }
#pragma unroll
    for (int i = 0; i < 2; ++i) {
        int r = rowBase + 2 * rp + i;
        uint2 pk;
        pk.x = (unsigned int)f2bf(fmaxf(acc[i][0], 0.f)) |
               ((unsigned int)f2bf(fmaxf(acc[i][1], 0.f)) << 16);
        pk.y = (unsigned int)f2bf(fmaxf(acc[i][2], 0.f)) |
               ((unsigned int)f2bf(fmaxf(acc[i][3], 0.f)) << 16);
        *reinterpret_cast<uint2*>(&out[(size_t)r * H + c0]) = pk;
    }
}

// ---------------- BN ----------------

__global__ void k_bnfinal(const float* __restrict__ gsum, const float* __restrict__ gss,
                          const float* __restrict__ gamma, const float* __restrict__ beta,
                          float* __restrict__ scale, float* __restrict__ shift) {
    int c = threadIdx.x;
    const float inv_n = 1.f / (float)N_NODES;
    float mu = gsum[c] * inv_n;
    float var = fmaxf(gss[c] * inv_n - mu * mu, 0.f);
    float sc = gamma[c] * rsqrtf(var + BN_EPS);
    scale[c] = sc;
    shift[c] = beta[c] - mu * sc;
}

// h = (RES? h:0) + v*scale+shift ; optionally write bf16 mirror hb
template <bool RES, bool WB>
__global__ void k_bnapply(const float* __restrict__ v, const float* __restrict__ scale,
                          const float* __restrict__ shift, float* __restrict__ h,
                          uint2* __restrict__ hb) {
    int idx = blockIdx.x * blockDim.x + threadIdx.x;  // float4 index
    if (idx >= N_NODES * H / 4) return;
    int c4 = idx & 31;
    float4 val = reinterpret_cast<const float4*>(v)[idx];
    float4 sc = reinterpret_cast<const float4*>(scale)[c4];
    float4 sh = reinterpret_cast<const float4*>(shift)[c4];
    float4 r;
    r.x = val.x * sc.x + sh.x;
    r.y = val.y * sc.y + sh.y;
    r.z = val.z * sc.z + sh.z;
    r.w = val.w * sc.w + sh.w;
    if (RES) {
        float4 hv = reinterpret_cast<float4*>(h)[idx];
        r.x += hv.x; r.y += hv.y; r.z += hv.z; r.w += hv.w;
    }
    reinterpret_cast<float4*>(h)[idx] = r;
    if (WB) {
        uint2 pk;
        pk.x = (unsigned int)f2bf(r.x) | ((unsigned int)f2bf(r.y) << 16);
        pk.y = (unsigned int)f2bf(r.z) | ((unsigned int)f2bf(r.w) << 16);
        hb[idx] = pk;
    }
}

// ---------------- pooling + head ----------------

__global__ void k_bounds(const int* __restrict__ batch, int* __restrict__ row_begin) {
    int i = blockIdx.x * blockDim.x + threadIdx.x;
    if (i >= N_NODES) return;
    int bi = batch[i];
    int bp = (i == 0) ? -1 : batch[i - 1];
    for (int g = bp + 1; g <= bi; ++g) row_begin[g] = i;
    if (i == N_NODES - 1) {
        for (int g = bi + 1; g <= N_GRAPHS; ++g) row_begin[g] = N_NODES;
    }
}

__global__ void k_pool(const float* __restrict__ h, const int* __restrict__ row_begin,
                       float* __restrict__ pooled) {
    int g = blockIdx.x;
    int c = threadIdx.x;  // 128
    int s = row_begin[g], e = row_begin[g + 1];
    float sum = 0.f, mx = -FLT_MAX;
    for (int i = s; i < e; ++i) {
        float v = h[(size_t)i * H + c];
        sum += v;
        mx = fmaxf(mx, v);
    }
    int cnt = e - s;
    pooled[g * 256 + c]       = (cnt > 0) ? sum / (float)cnt : 0.f;
    pooled[g * 256 + 128 + c] = (cnt > 0) ? mx : 0.f;
}

__global__ void k_final(const float* __restrict__ pooled, const float* __restrict__ Wf,
                        const float* __restrict__ bf, float* __restrict__ out) {
    __shared__ float ps[256];
    int g = blockIdx.x, c = threadIdx.x;  // 128 threads
    ps[c] = pooled[g * 256 + c];
    ps[128 + c] = pooled[g * 256 + 128 + c];
    __syncthreads();
    float acc = bf[c];
#pragma unroll 8
    for (int k = 0; k < 256; ++k) acc += ps[k] * Wf[k * H + c];
    out[g * H + c] = acc;
}

// ---------------- launcher ----------------

extern "C" void kernel_launch(void* const* d_in, const int* in_sizes, int n_in,
                              void* d_out, int out_size, void* d_ws, size_t ws_size,
                              hipStream_t stream) {
    const float* x     = (const float*)d_in[0];
    const int*   ei    = (const int*)d_in[1];
    const int*   src   = ei;
    const int*   dst   = ei + N_EDGES;
    const int*   batch = (const int*)d_in[2];
    const float* W1_0  = (const float*)d_in[3];
    const float* b1_0  = (const float*)d_in[4];
    const float* W2_0  = (const float*)d_in[5];
    const float* b2_0  = (const float*)d_in[6];
    const float* W1    = (const float*)d_in[7];
    const float* b1    = (const float*)d_in[8];
    const float* W2    = (const float*)d_in[9];
    const float* b2    = (const float*)d_in[10];
    const float* gamma = (const float*)d_in[11];
    const float* beta  = (const float*)d_in[12];
    const float* Wf    = (const float*)d_in[13];
    const float* bf    = (const float*)d_in[14];
    float* out = (float*)d_out;

    char* ws = (char*)d_ws;
    size_t off = 0;
    auto alloc = [&](size_t bytes) -> void* {
        void* p = ws + off;
        off = (off + bytes + 255) & ~(size_t)255;
        return p;
    };

    float* h    = (float*)alloc((size_t)N_NODES * H * 4);
    float* bufA = (float*)alloc((size_t)N_NODES * H * 4);
    uint2* hb   = (uint2*)alloc((size_t)N_NODES * H * 2);
    unsigned int*   aggb  = (unsigned int*)alloc((size_t)N_NODES * H * 2);
    unsigned short* act1b = (unsigned short*)alloc((size_t)N_NODES * H * 2);
    unsigned short* xb    = (unsigned short*)alloc((size_t)N_NODES * 80 * 2);
    unsigned short* Wtall = (unsigned short*)alloc((size_t)9 * H * H * 2);
    int* deg       = (int*)alloc((size_t)N_NODES * 4);
    int* row_start = (int*)alloc((size_t)(N_NODES + 1) * 4);
    int* esrc      = (int*)alloc((size_t)N_EDGES * 4);
    int2* ebuf     = (int2*)alloc((size_t)N_EDGES * 8);
    int* cnt       = (int*)alloc((size_t)NBUCKETS * 8 * 4);
    int* bcur      = (int*)alloc((size_t)NBUCKETS * 8 * 16 * 4);
    int* csum      = (int*)alloc((size_t)NCHUNK * 4);
    int* coff      = (int*)alloc((size_t)NCHUNK * 4);
    float* gsum  = (float*)alloc(H * 4);
    float* gss   = (float*)alloc(H * 4);
    float* scale = (float*)alloc(H * 4);
    float* shift = (float*)alloc(H * 4);
    int* row_begin = (int*)alloc((size_t)(N_GRAPHS + 1) * 4);
    float* pooled  = (float*)alloc((size_t)N_GRAPHS * 256 * 4);

    // ---- prep (overlaps CSR build) ----
    k_cast_x<<<(N_NODES * 80 + 255) / 256, 256, 0, stream>>>(x, xb);
    k_cast_w<<<(9 * H * H + 255) / 256, 256, 0, stream>>>(W2_0, W1, W2, Wtall);

    // ---- CSR build ----
    hipMemsetAsync(deg, 0, (size_t)N_NODES * 4, stream);
    hipMemsetAsync(cnt, 0, (size_t)NBUCKETS * 8 * 4, stream);
    k_deg_cnt<<<N_EDGES / 256, 256, 0, stream>>>(dst, deg, cnt);
    k_chunk_sum<<<NCHUNK, 256, 0, stream>>>(deg, csum);
    k_scan_chunks<<<1, 64, 0, stream>>>(csum, coff, row_start);
    k_scan_within<<<NCHUNK, 256, 0, stream>>>(deg, coff, row_start);
    k_boff<<<(NBUCKETS + 255) / 256, 256, 0, stream>>>(row_start, cnt, bcur);
    k_p3<<<N_EDGES / 256, 256, 0, stream>>>(src, dst, bcur, ebuf);
    k_p4<<<NBUCKETS, 256, 0, stream>>>(row_start, ebuf, esrc);

    const int mfma_grid = (N_NODES + 63) / 64;

    // ---- layer 0 (78 -> 128, no residual) ----
    k_gather0<<<N_NODES / 4, 256, 0, stream>>>(x, (const unsigned int*)xb, row_start, esrc, bufA);
    k_gemm78<F_IN><<<N_NODES / 16, 256, 0, stream>>>(bufA, W1_0, b1_0, act1b);
    hipMemsetAsync(gsum, 0, H * 4, stream);
    hipMemsetAsync(gss, 0, H * 4, stream);
    k_mfma2<<<mfma_grid, 256, 0, stream>>>((const short*)act1b, (const short*)Wtall, b2_0,
                                           bufA, gsum, gss);
    k_bnfinal<<<1, 128, 0, stream>>>(gsum, gss, gamma, beta, scale, shift);
    k_bnapply<false, true><<<N_NODES * H / 4 / 256, 256, 0, stream>>>(bufA, scale, shift, h, hb);

    // ---- layers 1..4 (residual) ----
    for (int l = 0; l < 4; ++l) {
        k_gather128b<<<N_NODES / 4, 256, 0, stream>>>(h, (const unsigned int*)hb, row_start,
                                                      esrc, aggb);
        k_mfma1<<<mfma_grid, 256, 0, stream>>>((const short*)aggb,
                                               (const short*)(Wtall + (1 + l) * H * H),
                                               b1 + l * H, act1b);
        hipMemsetAsync(gsum, 0, H * 4, stream);
        hipMemsetAsync(gss, 0, H * 4, stream);
        k_mfma2<<<mfma_grid, 256, 0, stream>>>((const short*)act1b,
                                               (const short*)(Wtall + (5 + l) * H * H),
                                               b2 + l * H, bufA, gsum, gss);
        k_bnfinal<<<1, 128, 0, stream>>>(gsum, gss, gamma + (l + 1) * H, beta + (l + 1) * H,
                                         scale, shift);
        if (l < 3) {
            k_bnapply<true, true><<<N_NODES * H / 4 / 256, 256, 0, stream>>>(bufA, scale, shift,
                                                                             h, hb);
        } else {
            k_bnapply<true, false><<<N_NODES * H / 4 / 256, 256, 0, stream>>>(bufA, scale, shift,
                                                                              h, hb);
        }
    }

    // ---- pooling + head ----
    k_bounds<<<(N_NODES + 255) / 256, 256, 0, stream>>>(batch, row_begin);
    k_pool<<<N_GRAPHS, 128, 0, stream>>>(h, row_begin, pooled);
    k_final<<<N_GRAPHS, 128, 0, stream>>>(pooled, Wf, bf, out);
}

// Round 5
// 1638.564 us; speedup vs baseline: 2.0852x; 1.1239x over previous
//
#include <hip/hip_runtime.h>
#include <float.h>

#define N_NODES 100000
#define N_EDGES 3200000
#define N_GRAPHS 1024
#define F_IN 78
#define H 128
#define BN_EPS 1e-5f

#define BK_SHIFT 7
#define BK_NODES 128
#define NBUCKETS ((N_NODES + BK_NODES - 1) / BK_NODES)  // 782
#define CIDX(b, s) ((s) * NBUCKETS + (b))
#define CNT_BLOCKS 64

using short8 = __attribute__((ext_vector_type(8))) short;
using f32x4v = __attribute__((ext_vector_type(4))) float;

__device__ __forceinline__ unsigned short f2bf(float f) {
    unsigned int u = __float_as_uint(f);
    unsigned int r = (u + 0x7fffu + ((u >> 16) & 1u)) >> 16;
    return (unsigned short)r;
}
__device__ __forceinline__ float bf_lo(unsigned int u) { return __uint_as_float(u << 16); }
__device__ __forceinline__ float bf_hi(unsigned int u) { return __uint_as_float(u & 0xffff0000u); }

// ---------------- CSR build ----------------

// LDS histogram of per-(bucket,sub) counts; sub = (e>>8)&7 matches k_p3's block sub
__global__ __launch_bounds__(256) void k_cnt(const int* __restrict__ dst,
                                             int* __restrict__ cnt) {
    __shared__ int lcnt[NBUCKETS * 8];  // 25 KB
    for (int i = threadIdx.x; i < NBUCKETS * 8; i += 256) lcnt[i] = 0;
    __syncthreads();
    for (int e = blockIdx.x * 256 + threadIdx.x; e < N_EDGES; e += CNT_BLOCKS * 256) {
        int d = dst[e];
        int sub = (e >> 8) & 7;
        atomicAdd(&lcnt[CIDX(d >> BK_SHIFT, sub)], 1);
    }
    __syncthreads();
    for (int i = threadIdx.x; i < NBUCKETS * 8; i += 256) {
        int v = lcnt[i];
        if (v) atomicAdd(&cnt[i], v);
    }
}

// one block: scan 782 bucket totals -> bbase[783]; fill per-(bucket,sub) cursors
__global__ __launch_bounds__(256) void k_scan_bkt(const int* __restrict__ cnt,
                                                  int* __restrict__ bbase,
                                                  int* __restrict__ bcur,
                                                  int* __restrict__ row_start) {
    __shared__ int part[256];
    int t = threadIdx.x;
    int b0 = t * 4;
    int s = 0;
#pragma unroll
    for (int j = 0; j < 4; ++j) {
        int b = b0 + j;
        if (b < NBUCKETS)
#pragma unroll
            for (int q = 0; q < 8; ++q) s += cnt[CIDX(b, q)];
    }
    part[t] = s;
    __syncthreads();
    if (t == 0) {
        int run = 0;
        for (int u = 0; u < 256; ++u) { int tmp = part[u]; part[u] = run; run += tmp; }
    }
    __syncthreads();
    int base = part[t];
#pragma unroll
    for (int j = 0; j < 4; ++j) {
        int b = b0 + j;
        if (b < NBUCKETS) {
            bbase[b] = base;
#pragma unroll
            for (int q = 0; q < 8; ++q) {
                bcur[CIDX(b, q) * 16] = base;
                base += cnt[CIDX(b, q)];
            }
        }
    }
    if (t == 0) {
        bbase[NBUCKETS] = N_EDGES;
        row_start[N_NODES] = N_EDGES;
    }
}

// stage 1: scatter (src,dst) into (bucket,sub)-contiguous regions
__global__ void k_p3(const int* __restrict__ src, const int* __restrict__ dst,
                     int* __restrict__ bcur, int2* __restrict__ ebuf) {
    int e = blockIdx.x * blockDim.x + threadIdx.x;
    int sub = blockIdx.x & 7;
    if (e < N_EDGES) {
        int d = dst[e];
        int p = atomicAdd(&bcur[CIDX(d >> BK_SHIFT, sub) * 16], 1);
        ebuf[p] = make_int2(src[e], d);
    }
}

// stage 2: per-bucket node-degree histogram + prefix -> row_start, then scatter esrc
__global__ __launch_bounds__(256) void k_p4(const int* __restrict__ bbase,
                                            const int2* __restrict__ ebuf,
                                            int* __restrict__ esrc,
                                            int* __restrict__ row_start) {
    __shared__ int cur[BK_NODES];
    __shared__ int start[BK_NODES];
    int b = blockIdx.x;
    int nodeBase = b << BK_SHIFT;
    int nLocal = min(BK_NODES, N_NODES - nodeBase);
    if (threadIdx.x < BK_NODES) cur[threadIdx.x] = 0;
    __syncthreads();
    int s = bbase[b], e = bbase[b + 1];
    for (int p = s + threadIdx.x; p < e; p += 256)
        atomicAdd(&cur[ebuf[p].y - nodeBase], 1);
    __syncthreads();
    if (threadIdx.x == 0) {
        int run = s;
        for (int i = 0; i < nLocal; ++i) { start[i] = run; run += cur[i]; }
    }
    __syncthreads();
    if (threadIdx.x < nLocal) {
        row_start[nodeBase + threadIdx.x] = start[threadIdx.x];
        cur[threadIdx.x] = start[threadIdx.x];
    }
    __syncthreads();
    for (int p = s + threadIdx.x; p < e; p += 256) {
        int2 ed = ebuf[p];
        int q = atomicAdd(&cur[ed.y - nodeBase], 1);
        esrc[q] = ed.x;
    }
}

// ---------------- bf16 prep ----------------

__global__ void k_cast_x(const float* __restrict__ x, unsigned short* __restrict__ xb) {
    int i = blockIdx.x * blockDim.x + threadIdx.x;
    if (i >= N_NODES * 80) return;
    int node = i / 80;
    int c = i - node * 80;
    float v = (c < F_IN) ? x[(size_t)node * F_IN + c] : 0.f;
    xb[i] = f2bf(v);
}

__global__ void k_cast_w(const float* __restrict__ W2_0, const float* __restrict__ W1,
                         const float* __restrict__ W2, unsigned short* __restrict__ Wt) {
    int i = blockIdx.x * blockDim.x + threadIdx.x;
    if (i >= 9 * H * H) return;
    int w = i >> 14, r = i & 16383;
    int n = r >> 7, k = r & 127;
    const float* s = (w == 0) ? W2_0 : (w <= 4 ? W1 + (w - 1) * H * H : W2 + (w - 5) * H * H);
    Wt[i] = f2bf(s[k * H + n]);
}

// ---------------- gather (aggregate) kernels ----------------

__global__ void k_gather0(const float* __restrict__ x, const unsigned int* __restrict__ xw,
                          const int* __restrict__ row_start, const int* __restrict__ esrc,
                          float* __restrict__ out) {
    int wave = threadIdx.x >> 6;
    int lane = threadIdx.x & 63;
    int node = blockIdx.x * 4 + wave;
    int s = row_start[node], e = row_start[node + 1];
    bool act = lane < 40;
    int c0 = 2 * lane, c1 = 2 * lane + 1;
    float s0 = (c0 < F_IN) ? x[(size_t)node * F_IN + c0] : 0.f;
    float s1 = (c1 < F_IN) ? x[(size_t)node * F_IN + c1] : 0.f;
    float a0 = 0.f, b0 = 0.f, a1 = 0.f, b1 = 0.f;
    float a2 = 0.f, b2 = 0.f, a3 = 0.f, b3 = 0.f;
    int p = s;
    for (; p + 8 <= e; p += 8) {
        int i0 = esrc[p + 0], i1 = esrc[p + 1], i2 = esrc[p + 2], i3 = esrc[p + 3];
        int i4 = esrc[p + 4], i5 = esrc[p + 5], i6 = esrc[p + 6], i7 = esrc[p + 7];
        unsigned int u0 = act ? xw[i0 * 40 + lane] : 0u;
        unsigned int u1 = act ? xw[i1 * 40 + lane] : 0u;
        unsigned int u2 = act ? xw[i2 * 40 + lane] : 0u;
        unsigned int u3 = act ? xw[i3 * 40 + lane] : 0u;
        unsigned int u4 = act ? xw[i4 * 40 + lane] : 0u;
        unsigned int u5 = act ? xw[i5 * 40 + lane] : 0u;
        unsigned int u6 = act ? xw[i6 * 40 + lane] : 0u;
        unsigned int u7 = act ? xw[i7 * 40 + lane] : 0u;
        a0 += bf_lo(u0); b0 += bf_hi(u0); a1 += bf_lo(u1); b1 += bf_hi(u1);
        a2 += bf_lo(u2); b2 += bf_hi(u2); a3 += bf_lo(u3); b3 += bf_hi(u3);
        a0 += bf_lo(u4); b0 += bf_hi(u4); a1 += bf_lo(u5); b1 += bf_hi(u5);
        a2 += bf_lo(u6); b2 += bf_hi(u6); a3 += bf_lo(u7); b3 += bf_hi(u7);
    }
    for (; p < e; ++p) {
        unsigned int u = act ? xw[esrc[p] * 40 + lane] : 0u;
        a0 += bf_lo(u); b0 += bf_hi(u);
    }
    float r0 = s0 + (a0 + a1) + (a2 + a3);
    float r1 = s1 + (b0 + b1) + (b2 + b3);
    if (lane < 39) {
        float2 r = make_float2(r0, r1);
        *reinterpret_cast<float2*>(&out[(size_t)node * F_IN + c0]) = r;
    }
}

__global__ void k_gather128b(const float* __restrict__ h, const unsigned int* __restrict__ hw,
                             const int* __restrict__ row_start, const int* __restrict__ esrc,
                             unsigned int* __restrict__ aggb) {
    int wave = threadIdx.x >> 6;
    int lane = threadIdx.x & 63;
    int node = blockIdx.x * 4 + wave;
    int s = row_start[node], e = row_start[node + 1];
    float2 self = reinterpret_cast<const float2*>(h)[node * 64 + lane];
    float a0 = 0.f, b0 = 0.f, a1 = 0.f, b1 = 0.f;
    float a2 = 0.f, b2 = 0.f, a3 = 0.f, b3 = 0.f;
    int p = s;
    for (; p + 8 <= e; p += 8) {
        int i0 = esrc[p + 0], i1 = esrc[p + 1], i2 = esrc[p + 2], i3 = esrc[p + 3];
        int i4 = esrc[p + 4], i5 = esrc[p + 5], i6 = esrc[p + 6], i7 = esrc[p + 7];
        unsigned int u0 = hw[i0 * 64 + lane];
        unsigned int u1 = hw[i1 * 64 + lane];
        unsigned int u2 = hw[i2 * 64 + lane];
        unsigned int u3 = hw[i3 * 64 + lane];
        unsigned int u4 = hw[i4 * 64 + lane];
        unsigned int u5 = hw[i5 * 64 + lane];
        unsigned int u6 = hw[i6 * 64 + lane];
        unsigned int u7 = hw[i7 * 64 + lane];
        a0 += bf_lo(u0); b0 += bf_hi(u0); a1 += bf_lo(u1); b1 += bf_hi(u1);
        a2 += bf_lo(u2); b2 += bf_hi(u2); a3 += bf_lo(u3); b3 += bf_hi(u3);
        a0 += bf_lo(u4); b0 += bf_hi(u4); a1 += bf_lo(u5); b1 += bf_hi(u5);
        a2 += bf_lo(u6); b2 += bf_hi(u6); a3 += bf_lo(u7); b3 += bf_hi(u7);
    }
    for (; p < e; ++p) {
        unsigned int u = hw[esrc[p] * 64 + lane];
        a0 += bf_lo(u); b0 += bf_hi(u);
    }
    float rx = self.x + (a0 + a1) + (a2 + a3);
    float ry = self.y + (b0 + b1) + (b2 + b3);
    aggb[node * 64 + lane] = (unsigned int)f2bf(rx) | ((unsigned int)f2bf(ry) << 16);
}

// ---------------- MFMA GEMMs ----------------

__global__ __launch_bounds__(256) void k_mfma1(const short* __restrict__ A,
                                               const short* __restrict__ Wt,
                                               const float* __restrict__ bias,
                                               unsigned short* __restrict__ out) {
    int wave = threadIdx.x >> 6, lane = threadIdx.x & 63;
    int r0 = blockIdx.x * 64 + wave * 16;
    int lm = lane & 15, lk = lane >> 4;
    int arow = r0 + lm;
    if (arow >= N_NODES) arow = N_NODES - 1;
    const short8* Arow = (const short8*)(A + (size_t)arow * H);
    f32x4v acc[8];
#pragma unroll
    for (int n = 0; n < 8; ++n) {
        float bv = bias[n * 16 + lm];
        acc[n] = (f32x4v){bv, bv, bv, bv};
    }
#pragma unroll
    for (int ks = 0; ks < 4; ++ks) {
        short8 af = Arow[ks * 4 + lk];
#pragma unroll
        for (int n = 0; n < 8; ++n) {
            const short8* Brow = (const short8*)(Wt + (size_t)(n * 16 + lm) * H);
            short8 bfr = Brow[ks * 4 + lk];
            acc[n] = __builtin_amdgcn_mfma_f32_16x16x32_bf16(af, bfr, acc[n], 0, 0, 0);
        }
    }
#pragma unroll
    for (int n = 0; n < 8; ++n) {
        int col = n * 16 + lm;
#pragma unroll
        for (int rg = 0; rg < 4; ++rg) {
            int r = r0 + lk * 4 + rg;
            if (r < N_NODES) {
                float v = fmaxf(acc[n][rg], 0.f);
                out[(size_t)r * H + col] = f2bf(v);
            }
        }
    }
}

__global__ __launch_bounds__(256) void k_mfma2(const short* __restrict__ A,
                                               const short* __restrict__ Wt,
                                               const float* __restrict__ bias,
                                               float* __restrict__ out,
                                               float* __restrict__ gsum,
                                               float* __restrict__ gss) {
    __shared__ float lsum[H], lss[H];
    if (threadIdx.x < H) { lsum[threadIdx.x] = 0.f; lss[threadIdx.x] = 0.f; }
    __syncthreads();
    int wave = threadIdx.x >> 6, lane = threadIdx.x & 63;
    int r0 = blockIdx.x * 64 + wave * 16;
    int lm = lane & 15, lk = lane >> 4;
    int arow = r0 + lm;
    if (arow >= N_NODES) arow = N_NODES - 1;
    const short8* Arow = (const short8*)(A + (size_t)arow * H);
    f32x4v acc[8];
#pragma unroll
    for (int n = 0; n < 8; ++n) {
        float bv = bias[n * 16 + lm];
        acc[n] = (f32x4v){bv, bv, bv, bv};
    }
#pragma unroll
    for (int ks = 0; ks < 4; ++ks) {
        short8 af = Arow[ks * 4 + lk];
#pragma unroll
        for (int n = 0; n < 8; ++n) {
            const short8* Brow = (const short8*)(Wt + (size_t)(n * 16 + lm) * H);
            short8 bfr = Brow[ks * 4 + lk];
            acc[n] = __builtin_amdgcn_mfma_f32_16x16x32_bf16(af, bfr, acc[n], 0, 0, 0);
        }
    }
#pragma unroll
    for (int n = 0; n < 8; ++n) {
        int col = n * 16 + lm;
        float s = 0.f, q = 0.f;
#pragma unroll
        for (int rg = 0; rg < 4; ++rg) {
            int r = r0 + lk * 4 + rg;
            if (r < N_NODES) {
                float v = fmaxf(acc[n][rg], 0.f);
                out[(size_t)r * H + col] = v;
                s += v;
                q += v * v;
            }
        }
        atomicAdd(&lsum[col], s);
        atomicAdd(&lss[col], q);
    }
    __syncthreads();
    if (threadIdx.x < H) {
        atomicAdd(&gsum[threadIdx.x], lsum[threadIdx.x]);
        atomicAdd(&gss[threadIdx.x], lss[threadIdx.x]);
    }
}

template <int K>
__global__ __launch_bounds__(256) void k_gemm78(const float* __restrict__ in,
                                                const float* __restrict__ W,
                                                const float* __restrict__ bias,
                                                unsigned short* __restrict__ out) {
    __shared__ float xs[16][K];
    int c0 = (threadIdx.x & 31) * 4;
    int rp = threadIdx.x >> 5;
    int rowBase = blockIdx.x * 16;
    for (int idx = threadIdx.x; idx < 16 * K; idx += 256) {
        int r = idx / K, k = idx - r * K;
        xs[r][k] = in[(size_t)(rowBase + r) * K + k];
    }
    __syncthreads();
    float4 b4 = *reinterpret_cast<const float4*>(&bias[c0]);
    float acc[2][4];
    acc[0][0] = b4.x; acc[0][1] = b4.y; acc[0][2] = b4.z; acc[0][3] = b4.w;
    acc[1][0] = b4.x; acc[1][1] = b4.y; acc[1][2] = b4.z; acc[1][3] = b4.w;
#pragma unroll 4
    for (int k = 0; k < K; ++k) {
        float4 w = *reinterpret_cast<const float4*>(&W[k * H + c0]);
        float a0 = xs[2 * rp][k];
        float a1 = xs[2 * rp + 1][k];
        acc[0][0] += a0 * w.x; acc[0][1] += a0 * w.y; acc[0][2] += a0 * w.z; acc[0][3] += a0 * w.w;
        acc[1][0] += a1 * w.x; acc[1][1] += a1 * w.y; acc[1][2] += a1 * w.z; acc[1][3] += a1 * w.w;
    }
#pragma unroll
    for (int i = 0; i < 2; ++i) {
        int r = rowBase + 2 * rp + i;
        uint2 pk;
        pk.x = (unsigned int)f2bf(fmaxf(acc[i][0], 0.f)) |
               ((unsigned int)f2bf(fmaxf(acc[i][1], 0.f)) << 16);
        pk.y = (unsigned int)f2bf(fmaxf(acc[i][2], 0.f)) |
               ((unsigned int)f2bf(fmaxf(acc[i][3], 0.f)) << 16);
        *reinterpret_cast<uint2*>(&out[(size_t)r * H + c0]) = pk;
    }
}

// ---------------- BN ----------------

__global__ void k_bnfinal(const float* __restrict__ gsum, const float* __restrict__ gss,
                          const float* __restrict__ gamma, const float* __restrict__ beta,
                          float* __restrict__ scale, float* __restrict__ shift) {
    int c = threadIdx.x;
    const float inv_n = 1.f / (float)N_NODES;
    float mu = gsum[c] * inv_n;
    float var = fmaxf(gss[c] * inv_n - mu * mu, 0.f);
    float sc = gamma[c] * rsqrtf(var + BN_EPS);
    scale[c] = sc;
    shift[c] = beta[c] - mu * sc;
}

template <bool RES, bool WB>
__global__ void k_bnapply(const float* __restrict__ v, const float* __restrict__ scale,
                          const float* __restrict__ shift, float* __restrict__ h,
                          uint2* __restrict__ hb) {
    int idx = blockIdx.x * blockDim.x + threadIdx.x;
    if (idx >= N_NODES * H / 4) return;
    int c4 = idx & 31;
    float4 val = reinterpret_cast<const float4*>(v)[idx];
    float4 sc = reinterpret_cast<const float4*>(scale)[c4];
    float4 sh = reinterpret_cast<const float4*>(shift)[c4];
    float4 r;
    r.x = val.x * sc.x + sh.x;
    r.y = val.y * sc.y + sh.y;
    r.z = val.z * sc.z + sh.z;
    r.w = val.w * sc.w + sh.w;
    if (RES) {
        float4 hv = reinterpret_cast<float4*>(h)[idx];
        r.x += hv.x; r.y += hv.y; r.z += hv.z; r.w += hv.w;
    }
    reinterpret_cast<float4*>(h)[idx] = r;
    if (WB) {
        uint2 pk;
        pk.x = (unsigned int)f2bf(r.x) | ((unsigned int)f2bf(r.y) << 16);
        pk.y = (unsigned int)f2bf(r.z) | ((unsigned int)f2bf(r.w) << 16);
        hb[idx] = pk;
    }
}

// ---------------- pooling + head ----------------

__global__ void k_bounds(const int* __restrict__ batch, int* __restrict__ row_begin) {
    int i = blockIdx.x * blockDim.x + threadIdx.x;
    if (i >= N_NODES) return;
    int bi = batch[i];
    int bp = (i == 0) ? -1 : batch[i - 1];
    for (int g = bp + 1; g <= bi; ++g) row_begin[g] = i;
    if (i == N_NODES - 1) {
        for (int g = bi + 1; g <= N_GRAPHS; ++g) row_begin[g] = N_NODES;
    }
}

__global__ void k_pool(const float* __restrict__ h, const int* __restrict__ row_begin,
                       float* __restrict__ pooled) {
    int g = blockIdx.x;
    int c = threadIdx.x;
    int s = row_begin[g], e = row_begin[g + 1];
    float sum = 0.f, mx = -FLT_MAX;
    for (int i = s; i < e; ++i) {
        float v = h[(size_t)i * H + c];
        sum += v;
        mx = fmaxf(mx, v);
    }
    int cnt = e - s;
    pooled[g * 256 + c]       = (cnt > 0) ? sum / (float)cnt : 0.f;
    pooled[g * 256 + 128 + c] = (cnt > 0) ? mx : 0.f;
}

__global__ void k_final(const float* __restrict__ pooled, const float* __restrict__ Wf,
                        const float* __restrict__ bf, float* __restrict__ out) {
    __shared__ float ps[256];
    int g = blockIdx.x, c = threadIdx.x;
    ps[c] = pooled[g * 256 + c];
    ps[128 + c] = pooled[g * 256 + 128 + c];
    __syncthreads();
    float acc = bf[c];
#pragma unroll 8
    for (int k = 0; k < 256; ++k) acc += ps[k] * Wf[k * H + c];
    out[g * H + c] = acc;
}

// ---------------- launcher ----------------

extern "C" void kernel_launch(void* const* d_in, const int* in_sizes, int n_in,
                              void* d_out, int out_size, void* d_ws, size_t ws_size,
                              hipStream_t stream) {
    const float* x     = (const float*)d_in[0];
    const int*   ei    = (const int*)d_in[1];
    const int*   src   = ei;
    const int*   dst   = ei + N_EDGES;
    const int*   batch = (const int*)d_in[2];
    const float* W1_0  = (const float*)d_in[3];
    const float* b1_0  = (const float*)d_in[4];
    const float* W2_0  = (const float*)d_in[5];
    const float* b2_0  = (const float*)d_in[6];
    const float* W1    = (const float*)d_in[7];
    const float* b1    = (const float*)d_in[8];
    const float* W2    = (const float*)d_in[9];
    const float* b2    = (const float*)d_in[10];
    const float* gamma = (const float*)d_in[11];
    const float* beta  = (const float*)d_in[12];
    const float* Wf    = (const float*)d_in[13];
    const float* bf    = (const float*)d_in[14];
    float* out = (float*)d_out;

    char* ws = (char*)d_ws;
    size_t off = 0;
    auto alloc = [&](size_t bytes) -> void* {
        void* p = ws + off;
        off = (off + bytes + 255) & ~(size_t)255;
        return p;
    };

    float* h    = (float*)alloc((size_t)N_NODES * H * 4);
    float* bufA = (float*)alloc((size_t)N_NODES * H * 4);
    uint2* hb   = (uint2*)alloc((size_t)N_NODES * H * 2);
    unsigned int*   aggb  = (unsigned int*)alloc((size_t)N_NODES * H * 2);
    unsigned short* act1b = (unsigned short*)alloc((size_t)N_NODES * H * 2);
    unsigned short* xb    = (unsigned short*)alloc((size_t)N_NODES * 80 * 2);
    unsigned short* Wtall = (unsigned short*)alloc((size_t)9 * H * H * 2);
    int* row_start = (int*)alloc((size_t)(N_NODES + 1) * 4);
    int* esrc      = (int*)alloc((size_t)N_EDGES * 4);
    int2* ebuf     = (int2*)alloc((size_t)N_EDGES * 8);
    int* cnt       = (int*)alloc((size_t)NBUCKETS * 8 * 4);
    int* bbase     = (int*)alloc((size_t)(NBUCKETS + 1) * 4);
    int* bcur      = (int*)alloc((size_t)NBUCKETS * 8 * 16 * 4);
    float* gsum  = (float*)alloc(H * 4);
    float* gss   = (float*)alloc(H * 4);
    float* scale = (float*)alloc(H * 4);
    float* shift = (float*)alloc(H * 4);
    int* row_begin = (int*)alloc((size_t)(N_GRAPHS + 1) * 4);
    float* pooled  = (float*)alloc((size_t)N_GRAPHS * 256 * 4);

    // ---- prep (overlaps CSR build) ----
    k_cast_x<<<(N_NODES * 80 + 255) / 256, 256, 0, stream>>>(x, xb);
    k_cast_w<<<(9 * H * H + 255) / 256, 256, 0, stream>>>(W2_0, W1, W2, Wtall);

    // ---- CSR build ----
    hipMemsetAsync(cnt, 0, (size_t)NBUCKETS * 8 * 4, stream);
    k_cnt<<<CNT_BLOCKS, 256, 0, stream>>>(dst, cnt);
    k_scan_bkt<<<1, 256, 0, stream>>>(cnt, bbase, bcur, row_start);
    k_p3<<<N_EDGES / 256, 256, 0, stream>>>(src, dst, bcur, ebuf);
    k_p4<<<NBUCKETS, 256, 0, stream>>>(bbase, ebuf, esrc, row_start);

    const int mfma_grid = (N_NODES + 63) / 64;

    // ---- layer 0 (78 -> 128, no residual) ----
    k_gather0<<<N_NODES / 4, 256, 0, stream>>>(x, (const unsigned int*)xb, row_start, esrc, bufA);
    k_gemm78<F_IN><<<N_NODES / 16, 256, 0, stream>>>(bufA, W1_0, b1_0, act1b);
    hipMemsetAsync(gsum, 0, H * 4, stream);
    hipMemsetAsync(gss, 0, H * 4, stream);
    k_mfma2<<<mfma_grid, 256, 0, stream>>>((const short*)act1b, (const short*)Wtall, b2_0,
                                           bufA, gsum, gss);
    k_bnfinal<<<1, 128, 0, stream>>>(gsum, gss, gamma, beta, scale, shift);
    k_bnapply<false, true><<<N_NODES * H / 4 / 256, 256, 0, stream>>>(bufA, scale, shift, h, hb);

    // ---- layers 1..4 (residual) ----
    for (int l = 0; l < 4; ++l) {
        k_gather128b<<<N_NODES / 4, 256, 0, stream>>>(h, (const unsigned int*)hb, row_start,
                                                      esrc, aggb);
        k_mfma1<<<mfma_grid, 256, 0, stream>>>((const short*)aggb,
                                               (const short*)(Wtall + (1 + l) * H * H),
                                               b1 + l * H, act1b);
        hipMemsetAsync(gsum, 0, H * 4, stream);
        hipMemsetAsync(gss, 0, H * 4, stream);
        k_mfma2<<<mfma_grid, 256, 0, stream>>>((const short*)act1b,
                                               (const short*)(Wtall + (5 + l) * H * H),
                                               b2 + l * H, bufA, gsum, gss);
        k_bnfinal<<<1, 128, 0, stream>>>(gsum, gss, gamma + (l + 1) * H, beta + (l + 1) * H,
                                         scale, shift);
        if (l < 3) {
            k_bnapply<true, true><<<N_NODES * H / 4 / 256, 256, 0, stream>>>(bufA, scale, shift,
                                                                             h, hb);
        } else {
            k_bnapply<true, false><<<N_NODES * H / 4 / 256, 256, 0, stream>>>(bufA, scale, shift,
                                                                              h, hb);
        }
    }

    // ---- pooling + head ----
    k_bounds<<<(N_NODES + 255) / 256, 256, 0, stream>>>(batch, row_begin);
    k_pool<<<N_GRAPHS, 128, 0, stream>>>(h, row_begin, pooled);
    k_final<<<N_GRAPHS, 128, 0, stream>>>(pooled, Wf, bf, out);
}

// Round 6
// 1529.652 us; speedup vs baseline: 2.2337x; 1.0712x over previous
//
#include <hip/hip_runtime.h>
#include <float.h>

#define N_NODES 100000
#define N_EDGES 3200000
#define N_GRAPHS 1024
#define F_IN 78
#define H 128
#define BN_EPS 1e-5f

#define BK_SHIFT 7
#define BK_NODES 128
#define NBUCKETS ((N_NODES + BK_NODES - 1) / BK_NODES)  // 782
#define CIDX(b, s) ((s) * NBUCKETS + (b))
#define CNT_BLOCKS 64

using short8 = __attribute__((ext_vector_type(8))) short;
using f32x4v = __attribute__((ext_vector_type(4))) float;

__device__ __forceinline__ unsigned short f2bf(float f) {
    unsigned int u = __float_as_uint(f);
    unsigned int r = (u + 0x7fffu + ((u >> 16) & 1u)) >> 16;
    return (unsigned short)r;
}
__device__ __forceinline__ float bf_lo(unsigned int u) { return __uint_as_float(u << 16); }
__device__ __forceinline__ float bf_hi(unsigned int u) { return __uint_as_float(u & 0xffff0000u); }

// ---------------- CSR build ----------------

__global__ __launch_bounds__(256) void k_cnt(const int* __restrict__ dst,
                                             int* __restrict__ cnt) {
    __shared__ int lcnt[NBUCKETS * 8];  // 25 KB
    for (int i = threadIdx.x; i < NBUCKETS * 8; i += 256) lcnt[i] = 0;
    __syncthreads();
    for (int e = blockIdx.x * 256 + threadIdx.x; e < N_EDGES; e += CNT_BLOCKS * 256) {
        int d = dst[e];
        int sub = (e >> 8) & 7;
        atomicAdd(&lcnt[CIDX(d >> BK_SHIFT, sub)], 1);
    }
    __syncthreads();
    for (int i = threadIdx.x; i < NBUCKETS * 8; i += 256) {
        int v = lcnt[i];
        if (v) atomicAdd(&cnt[i], v);
    }
}

__global__ __launch_bounds__(256) void k_scan_bkt(const int* __restrict__ cnt,
                                                  int* __restrict__ bbase,
                                                  int* __restrict__ bcur,
                                                  int* __restrict__ row_start) {
    __shared__ int part[256];
    int t = threadIdx.x;
    int b0 = t * 4;
    int s = 0;
#pragma unroll
    for (int j = 0; j < 4; ++j) {
        int b = b0 + j;
        if (b < NBUCKETS)
#pragma unroll
            for (int q = 0; q < 8; ++q) s += cnt[CIDX(b, q)];
    }
    part[t] = s;
    __syncthreads();
    if (t == 0) {
        int run = 0;
        for (int u = 0; u < 256; ++u) { int tmp = part[u]; part[u] = run; run += tmp; }
    }
    __syncthreads();
    int base = part[t];
#pragma unroll
    for (int j = 0; j < 4; ++j) {
        int b = b0 + j;
        if (b < NBUCKETS) {
            bbase[b] = base;
#pragma unroll
            for (int q = 0; q < 8; ++q) {
                bcur[CIDX(b, q) * 16] = base;
                base += cnt[CIDX(b, q)];
            }
        }
    }
    if (t == 0) {
        bbase[NBUCKETS] = N_EDGES;
        row_start[N_NODES] = N_EDGES;
    }
}

// stage 1: scatter packed (src<<7 | dst&127) into (bucket,sub)-contiguous regions
__global__ void k_p3(const int* __restrict__ src, const int* __restrict__ dst,
                     int* __restrict__ bcur, unsigned int* __restrict__ ebuf) {
    int e = blockIdx.x * blockDim.x + threadIdx.x;
    int sub = blockIdx.x & 7;
    if (e < N_EDGES) {
        int d = dst[e];
        int p = atomicAdd(&bcur[CIDX(d >> BK_SHIFT, sub) * 16], 1);
        ebuf[p] = ((unsigned int)src[e] << 7) | (unsigned int)(d & (BK_NODES - 1));
    }
}

// stage 2: per-bucket node-degree histogram + prefix -> row_start, then scatter esrc
__global__ __launch_bounds__(256) void k_p4(const int* __restrict__ bbase,
                                            const unsigned int* __restrict__ ebuf,
                                            int* __restrict__ esrc,
                                            int* __restrict__ row_start) {
    __shared__ int cur[BK_NODES];
    __shared__ int start[BK_NODES];
    int b = blockIdx.x;
    int nodeBase = b << BK_SHIFT;
    int nLocal = min(BK_NODES, N_NODES - nodeBase);
    if (threadIdx.x < BK_NODES) cur[threadIdx.x] = 0;
    __syncthreads();
    int s = bbase[b], e = bbase[b + 1];
    for (int p = s + threadIdx.x; p < e; p += 256)
        atomicAdd(&cur[ebuf[p] & (BK_NODES - 1)], 1);
    __syncthreads();
    if (threadIdx.x == 0) {
        int run = s;
        for (int i = 0; i < nLocal; ++i) { start[i] = run; run += cur[i]; }
    }
    __syncthreads();
    if (threadIdx.x < nLocal) {
        row_start[nodeBase + threadIdx.x] = start[threadIdx.x];
        cur[threadIdx.x] = start[threadIdx.x];
    }
    __syncthreads();
    for (int p = s + threadIdx.x; p < e; p += 256) {
        unsigned int ed = ebuf[p];
        int q = atomicAdd(&cur[ed & (BK_NODES - 1)], 1);
        esrc[q] = (int)(ed >> 7);
    }
}

// ---------------- bf16 prep ----------------

// x [N][78] f32 -> xb [N][96] bf16 (zero padded; rows = 192 B = 3 aligned lines)
__global__ void k_cast_x(const float* __restrict__ x, unsigned short* __restrict__ xb) {
    int i = blockIdx.x * blockDim.x + threadIdx.x;
    if (i >= N_NODES * 96) return;
    int node = i / 96;
    int c = i - node * 96;
    float v = (c < F_IN) ? x[(size_t)node * F_IN + c] : 0.f;
    xb[i] = f2bf(v);
}

// transpose+cast 9 H x H weights: Wtall[w][n][k] = W_w[k][n]
__global__ void k_cast_w(const float* __restrict__ W2_0, const float* __restrict__ W1,
                         const float* __restrict__ W2, unsigned short* __restrict__ Wt) {
    int i = blockIdx.x * blockDim.x + threadIdx.x;
    if (i >= 9 * H * H) return;
    int w = i >> 14, r = i & 16383;
    int n = r >> 7, k = r & 127;
    const float* s = (w == 0) ? W2_0 : (w <= 4 ? W1 + (w - 1) * H * H : W2 + (w - 5) * H * H);
    Wt[i] = f2bf(s[k * H + n]);
}

// W1_0 [78][128] -> Wt0 [128][96] bf16 (zero padded K)
__global__ void k_cast_w0(const float* __restrict__ W1_0, unsigned short* __restrict__ Wt0) {
    int i = blockIdx.x * blockDim.x + threadIdx.x;
    if (i >= H * 96) return;
    int n = i / 96, k = i - n * 96;
    Wt0[i] = f2bf((k < F_IN) ? W1_0[k * H + n] : 0.f);
}

// ---------------- gather (aggregate) kernels ----------------

// layer 0: xb bf16 [N][96] (48 dwords); out = self+agg as bf16 [N][96]
__global__ void k_gather96(const unsigned int* __restrict__ xw,
                           const int* __restrict__ row_start, const int* __restrict__ esrc,
                           unsigned int* __restrict__ out) {
    int wave = threadIdx.x >> 6;
    int lane = threadIdx.x & 63;
    int node = blockIdx.x * 4 + wave;
    int s = row_start[node], e = row_start[node + 1];
    bool act = lane < 48;
    unsigned int su = act ? xw[node * 48 + lane] : 0u;
    float a0 = bf_lo(su), b0 = bf_hi(su);
    float a1 = 0.f, b1 = 0.f, a2 = 0.f, b2 = 0.f, a3 = 0.f, b3 = 0.f;
    int p = s;
    for (; p + 8 <= e; p += 8) {
        int i0 = esrc[p + 0], i1 = esrc[p + 1], i2 = esrc[p + 2], i3 = esrc[p + 3];
        int i4 = esrc[p + 4], i5 = esrc[p + 5], i6 = esrc[p + 6], i7 = esrc[p + 7];
        unsigned int u0 = act ? xw[i0 * 48 + lane] : 0u;
        unsigned int u1 = act ? xw[i1 * 48 + lane] : 0u;
        unsigned int u2 = act ? xw[i2 * 48 + lane] : 0u;
        unsigned int u3 = act ? xw[i3 * 48 + lane] : 0u;
        unsigned int u4 = act ? xw[i4 * 48 + lane] : 0u;
        unsigned int u5 = act ? xw[i5 * 48 + lane] : 0u;
        unsigned int u6 = act ? xw[i6 * 48 + lane] : 0u;
        unsigned int u7 = act ? xw[i7 * 48 + lane] : 0u;
        a0 += bf_lo(u0); b0 += bf_hi(u0); a1 += bf_lo(u1); b1 += bf_hi(u1);
        a2 += bf_lo(u2); b2 += bf_hi(u2); a3 += bf_lo(u3); b3 += bf_hi(u3);
        a0 += bf_lo(u4); b0 += bf_hi(u4); a1 += bf_lo(u5); b1 += bf_hi(u5);
        a2 += bf_lo(u6); b2 += bf_hi(u6); a3 += bf_lo(u7); b3 += bf_hi(u7);
    }
    for (; p < e; ++p) {
        unsigned int u = act ? xw[esrc[p] * 48 + lane] : 0u;
        a0 += bf_lo(u); b0 += bf_hi(u);
    }
    if (act) {
        float rx = (a0 + a1) + (a2 + a3);
        float ry = (b0 + b1) + (b2 + b3);
        out[node * 48 + lane] = (unsigned int)f2bf(rx) | ((unsigned int)f2bf(ry) << 16);
    }
}

// layers 1..4: hb bf16 [N][128]; self also from hb; out bf16 [N][128]
__global__ void k_gather128b(const unsigned int* __restrict__ hw,
                             const int* __restrict__ row_start, const int* __restrict__ esrc,
                             unsigned int* __restrict__ aggb) {
    int wave = threadIdx.x >> 6;
    int lane = threadIdx.x & 63;
    int node = blockIdx.x * 4 + wave;
    int s = row_start[node], e = row_start[node + 1];
    unsigned int su = hw[node * 64 + lane];
    float a0 = bf_lo(su), b0 = bf_hi(su);
    float a1 = 0.f, b1 = 0.f, a2 = 0.f, b2 = 0.f, a3 = 0.f, b3 = 0.f;
    int p = s;
    for (; p + 8 <= e; p += 8) {
        int i0 = esrc[p + 0], i1 = esrc[p + 1], i2 = esrc[p + 2], i3 = esrc[p + 3];
        int i4 = esrc[p + 4], i5 = esrc[p + 5], i6 = esrc[p + 6], i7 = esrc[p + 7];
        unsigned int u0 = hw[i0 * 64 + lane];
        unsigned int u1 = hw[i1 * 64 + lane];
        unsigned int u2 = hw[i2 * 64 + lane];
        unsigned int u3 = hw[i3 * 64 + lane];
        unsigned int u4 = hw[i4 * 64 + lane];
        unsigned int u5 = hw[i5 * 64 + lane];
        unsigned int u6 = hw[i6 * 64 + lane];
        unsigned int u7 = hw[i7 * 64 + lane];
        a0 += bf_lo(u0); b0 += bf_hi(u0); a1 += bf_lo(u1); b1 += bf_hi(u1);
        a2 += bf_lo(u2); b2 += bf_hi(u2); a3 += bf_lo(u3); b3 += bf_hi(u3);
        a0 += bf_lo(u4); b0 += bf_hi(u4); a1 += bf_lo(u5); b1 += bf_hi(u5);
        a2 += bf_lo(u6); b2 += bf_hi(u6); a3 += bf_lo(u7); b3 += bf_hi(u7);
    }
    for (; p < e; ++p) {
        unsigned int u = hw[esrc[p] * 64 + lane];
        a0 += bf_lo(u); b0 += bf_hi(u);
    }
    float rx = (a0 + a1) + (a2 + a3);
    float ry = (b0 + b1) + (b2 + b3);
    aggb[node * 64 + lane] = (unsigned int)f2bf(rx) | ((unsigned int)f2bf(ry) << 16);
}

// ---------------- MFMA GEMMs ----------------
// A [N][NK*32] bf16 row-major; Wt [128 n][NK*32 k] bf16; block = 4 waves x 16 rows.

template <int NK>
__global__ __launch_bounds__(256) void k_mfma1t(const short* __restrict__ A,
                                                const short* __restrict__ Wt,
                                                const float* __restrict__ bias,
                                                unsigned short* __restrict__ out) {
    const int K = NK * 32;
    int wave = threadIdx.x >> 6, lane = threadIdx.x & 63;
    int r0 = blockIdx.x * 64 + wave * 16;
    int lm = lane & 15, lk = lane >> 4;
    int arow = r0 + lm;
    if (arow >= N_NODES) arow = N_NODES - 1;
    const short8* Arow = (const short8*)(A + (size_t)arow * K);
    f32x4v acc[8];
#pragma unroll
    for (int n = 0; n < 8; ++n) {
        float bv = bias[n * 16 + lm];
        acc[n] = (f32x4v){bv, bv, bv, bv};
    }
#pragma unroll
    for (int ks = 0; ks < NK; ++ks) {
        short8 af = Arow[ks * 4 + lk];
#pragma unroll
        for (int n = 0; n < 8; ++n) {
            const short8* Brow = (const short8*)(Wt + (size_t)(n * 16 + lm) * K);
            short8 bfr = Brow[ks * 4 + lk];
            acc[n] = __builtin_amdgcn_mfma_f32_16x16x32_bf16(af, bfr, acc[n], 0, 0, 0);
        }
    }
#pragma unroll
    for (int n = 0; n < 8; ++n) {
        int col = n * 16 + lm;
#pragma unroll
        for (int rg = 0; rg < 4; ++rg) {
            int r = r0 + lk * 4 + rg;
            if (r < N_NODES) {
                float v = fmaxf(acc[n][rg], 0.f);
                out[(size_t)r * H + col] = f2bf(v);
            }
        }
    }
}

// GEMM2: out = relu(A @ W + b) as bf16, fused BN stats (stats in f32)
__global__ __launch_bounds__(256) void k_mfma2(const short* __restrict__ A,
                                               const short* __restrict__ Wt,
                                               const float* __restrict__ bias,
                                               unsigned short* __restrict__ out,
                                               float* __restrict__ gsum,
                                               float* __restrict__ gss) {
    __shared__ float lsum[H], lss[H];
    if (threadIdx.x < H) { lsum[threadIdx.x] = 0.f; lss[threadIdx.x] = 0.f; }
    __syncthreads();
    int wave = threadIdx.x >> 6, lane = threadIdx.x & 63;
    int r0 = blockIdx.x * 64 + wave * 16;
    int lm = lane & 15, lk = lane >> 4;
    int arow = r0 + lm;
    if (arow >= N_NODES) arow = N_NODES - 1;
    const short8* Arow = (const short8*)(A + (size_t)arow * H);
    f32x4v acc[8];
#pragma unroll
    for (int n = 0; n < 8; ++n) {
        float bv = bias[n * 16 + lm];
        acc[n] = (f32x4v){bv, bv, bv, bv};
    }
#pragma unroll
    for (int ks = 0; ks < 4; ++ks) {
        short8 af = Arow[ks * 4 + lk];
#pragma unroll
        for (int n = 0; n < 8; ++n) {
            const short8* Brow = (const short8*)(Wt + (size_t)(n * 16 + lm) * H);
            short8 bfr = Brow[ks * 4 + lk];
            acc[n] = __builtin_amdgcn_mfma_f32_16x16x32_bf16(af, bfr, acc[n], 0, 0, 0);
        }
    }
#pragma unroll
    for (int n = 0; n < 8; ++n) {
        int col = n * 16 + lm;
        float s = 0.f, q = 0.f;
#pragma unroll
        for (int rg = 0; rg < 4; ++rg) {
            int r = r0 + lk * 4 + rg;
            if (r < N_NODES) {
                float v = fmaxf(acc[n][rg], 0.f);
                out[(size_t)r * H + col] = f2bf(v);
                s += v;
                q += v * v;
            }
        }
        atomicAdd(&lsum[col], s);
        atomicAdd(&lss[col], q);
    }
    __syncthreads();
    if (threadIdx.x < H) {
        atomicAdd(&gsum[threadIdx.x], lsum[threadIdx.x]);
        atomicAdd(&gss[threadIdx.x], lss[threadIdx.x]);
    }
}

// ---------------- BN ----------------

// reads + RESETS gsum/gss (so no per-layer memset is needed within a call)
__global__ void k_bnfinal(float* __restrict__ gsum, float* __restrict__ gss,
                          const float* __restrict__ gamma, const float* __restrict__ beta,
                          float* __restrict__ scale, float* __restrict__ shift) {
    int c = threadIdx.x;
    const float inv_n = 1.f / (float)N_NODES;
    float sv = gsum[c], qv = gss[c];
    gsum[c] = 0.f;
    gss[c] = 0.f;
    float mu = sv * inv_n;
    float var = fmaxf(qv * inv_n - mu * mu, 0.f);
    float sc = gamma[c] * rsqrtf(var + BN_EPS);
    scale[c] = sc;
    shift[c] = beta[c] - mu * sc;
}

// h = (RES? h:0) + v*scale+shift ; v is bf16; optionally write bf16 mirror hb
template <bool RES, bool WB>
__global__ void k_bnapply(const uint2* __restrict__ vb, const float* __restrict__ scale,
                          const float* __restrict__ shift, float* __restrict__ h,
                          uint2* __restrict__ hb) {
    int idx = blockIdx.x * blockDim.x + threadIdx.x;  // 4-elem index
    if (idx >= N_NODES * H / 4) return;
    int c4 = idx & 31;
    uint2 pv = vb[idx];
    float4 val = make_float4(bf_lo(pv.x), bf_hi(pv.x), bf_lo(pv.y), bf_hi(pv.y));
    float4 sc = reinterpret_cast<const float4*>(scale)[c4];
    float4 sh = reinterpret_cast<const float4*>(shift)[c4];
    float4 r;
    r.x = val.x * sc.x + sh.x;
    r.y = val.y * sc.y + sh.y;
    r.z = val.z * sc.z + sh.z;
    r.w = val.w * sc.w + sh.w;
    if (RES) {
        float4 hv = reinterpret_cast<float4*>(h)[idx];
        r.x += hv.x; r.y += hv.y; r.z += hv.z; r.w += hv.w;
    }
    reinterpret_cast<float4*>(h)[idx] = r;
    if (WB) {
        uint2 pk;
        pk.x = (unsigned int)f2bf(r.x) | ((unsigned int)f2bf(r.y) << 16);
        pk.y = (unsigned int)f2bf(r.z) | ((unsigned int)f2bf(r.w) << 16);
        hb[idx] = pk;
    }
}

// ---------------- pooling + head ----------------

__global__ void k_bounds(const int* __restrict__ batch, int* __restrict__ row_begin) {
    int i = blockIdx.x * blockDim.x + threadIdx.x;
    if (i >= N_NODES) return;
    int bi = batch[i];
    int bp = (i == 0) ? -1 : batch[i - 1];
    for (int g = bp + 1; g <= bi; ++g) row_begin[g] = i;
    if (i == N_NODES - 1) {
        for (int g = bi + 1; g <= N_GRAPHS; ++g) row_begin[g] = N_NODES;
    }
}

__global__ void k_pool(const float* __restrict__ h, const int* __restrict__ row_begin,
                       float* __restrict__ pooled) {
    int g = blockIdx.x;
    int c = threadIdx.x;
    int s = row_begin[g], e = row_begin[g + 1];
    float sum = 0.f, mx = -FLT_MAX;
    for (int i = s; i < e; ++i) {
        float v = h[(size_t)i * H + c];
        sum += v;
        mx = fmaxf(mx, v);
    }
    int cnt = e - s;
    pooled[g * 256 + c]       = (cnt > 0) ? sum / (float)cnt : 0.f;
    pooled[g * 256 + 128 + c] = (cnt > 0) ? mx : 0.f;
}

__global__ void k_final(const float* __restrict__ pooled, const float* __restrict__ Wf,
                        const float* __restrict__ bf, float* __restrict__ out) {
    __shared__ float ps[256];
    int g = blockIdx.x, c = threadIdx.x;
    ps[c] = pooled[g * 256 + c];
    ps[128 + c] = pooled[g * 256 + 128 + c];
    __syncthreads();
    float acc = bf[c];
#pragma unroll 8
    for (int k = 0; k < 256; ++k) acc += ps[k] * Wf[k * H + c];
    out[g * H + c] = acc;
}

// ---------------- launcher ----------------

extern "C" void kernel_launch(void* const* d_in, const int* in_sizes, int n_in,
                              void* d_out, int out_size, void* d_ws, size_t ws_size,
                              hipStream_t stream) {
    const float* x     = (const float*)d_in[0];
    const int*   ei    = (const int*)d_in[1];
    const int*   src   = ei;
    const int*   dst   = ei + N_EDGES;
    const int*   batch = (const int*)d_in[2];
    const float* W1_0  = (const float*)d_in[3];
    const float* b1_0  = (const float*)d_in[4];
    const float* W2_0  = (const float*)d_in[5];
    const float* b2_0  = (const float*)d_in[6];
    const float* W1    = (const float*)d_in[7];
    const float* b1    = (const float*)d_in[8];
    const float* W2    = (const float*)d_in[9];
    const float* b2    = (const float*)d_in[10];
    const float* gamma = (const float*)d_in[11];
    const float* beta  = (const float*)d_in[12];
    const float* Wf    = (const float*)d_in[13];
    const float* bf    = (const float*)d_in[14];
    float* out = (float*)d_out;

    char* ws = (char*)d_ws;
    size_t off = 0;
    auto alloc = [&](size_t bytes) -> void* {
        void* p = ws + off;
        off = (off + bytes + 255) & ~(size_t)255;
        return p;
    };

    float* h    = (float*)alloc((size_t)N_NODES * H * 4);
    uint2* hb   = (uint2*)alloc((size_t)N_NODES * H * 2);
    unsigned int*   aggb  = (unsigned int*)alloc((size_t)N_NODES * H * 2);
    unsigned short* act1b = (unsigned short*)alloc((size_t)N_NODES * H * 2);
    unsigned short* act2b = (unsigned short*)alloc((size_t)N_NODES * H * 2);
    unsigned short* xb    = (unsigned short*)alloc((size_t)N_NODES * 96 * 2);
    unsigned int*   agg0b = (unsigned int*)alloc((size_t)N_NODES * 48 * 4);
    unsigned short* Wtall = (unsigned short*)alloc((size_t)9 * H * H * 2);
    unsigned short* Wt0   = (unsigned short*)alloc((size_t)H * 96 * 2);
    int* row_start = (int*)alloc((size_t)(N_NODES + 1) * 4);
    int* esrc      = (int*)alloc((size_t)N_EDGES * 4);
    unsigned int* ebuf = (unsigned int*)alloc((size_t)N_EDGES * 4);
    int* cnt       = (int*)alloc((size_t)NBUCKETS * 8 * 4);
    int* bbase     = (int*)alloc((size_t)(NBUCKETS + 1) * 4);
    int* bcur      = (int*)alloc((size_t)NBUCKETS * 8 * 16 * 4);
    float* gsum  = (float*)alloc(H * 4);
    float* gss   = (float*)alloc(H * 4);
    float* scale = (float*)alloc(H * 4);
    float* shift = (float*)alloc(H * 4);
    int* row_begin = (int*)alloc((size_t)(N_GRAPHS + 1) * 4);
    float* pooled  = (float*)alloc((size_t)N_GRAPHS * 256 * 4);

    // ---- prep (overlaps CSR build) ----
    k_cast_x<<<(N_NODES * 96 + 255) / 256, 256, 0, stream>>>(x, xb);
    k_cast_w<<<(9 * H * H + 255) / 256, 256, 0, stream>>>(W2_0, W1, W2, Wtall);
    k_cast_w0<<<(H * 96 + 255) / 256, 256, 0, stream>>>(W1_0, Wt0);

    // ---- CSR build ----
    hipMemsetAsync(cnt, 0, (size_t)NBUCKETS * 8 * 4, stream);
    k_cnt<<<CNT_BLOCKS, 256, 0, stream>>>(dst, cnt);
    k_scan_bkt<<<1, 256, 0, stream>>>(cnt, bbase, bcur, row_start);
    k_p3<<<N_EDGES / 256, 256, 0, stream>>>(src, dst, bcur, ebuf);
    k_p4<<<NBUCKETS, 256, 0, stream>>>(bbase, ebuf, esrc, row_start);

    // zero BN accumulators once per call (bnfinal self-resets for later layers)
    hipMemsetAsync(gsum, 0, H * 4, stream);
    hipMemsetAsync(gss, 0, H * 4, stream);

    const int mfma_grid = (N_NODES + 63) / 64;

    // ---- layer 0 (78 -> 128, no residual) ----
    k_gather96<<<N_NODES / 4, 256, 0, stream>>>((const unsigned int*)xb, row_start, esrc, agg0b);
    k_mfma1t<3><<<mfma_grid, 256, 0, stream>>>((const short*)agg0b, (const short*)Wt0,
                                               b1_0, act1b);
    k_mfma2<<<mfma_grid, 256, 0, stream>>>((const short*)act1b, (const short*)Wtall, b2_0,
                                           act2b, gsum, gss);
    k_bnfinal<<<1, 128, 0, stream>>>(gsum, gss, gamma, beta, scale, shift);
    k_bnapply<false, true><<<N_NODES * H / 4 / 256, 256, 0, stream>>>((const uint2*)act2b,
                                                                      scale, shift, h, hb);

    // ---- layers 1..4 (residual) ----
    for (int l = 0; l < 4; ++l) {
        k_gather128b<<<N_NODES / 4, 256, 0, stream>>>((const unsigned int*)hb, row_start,
                                                      esrc, aggb);
        k_mfma1t<4><<<mfma_grid, 256, 0, stream>>>((const short*)aggb,
                                                   (const short*)(Wtall + (1 + l) * H * H),
                                                   b1 + l * H, act1b);
        k_mfma2<<<mfma_grid, 256, 0, stream>>>((const short*)act1b,
                                               (const short*)(Wtall + (5 + l) * H * H),
                                               b2 + l * H, act2b, gsum, gss);
        k_bnfinal<<<1, 128, 0, stream>>>(gsum, gss, gamma + (l + 1) * H, beta + (l + 1) * H,
                                         scale, shift);
        if (l < 3) {
            k_bnapply<true, true><<<N_NODES * H / 4 / 256, 256, 0, stream>>>((const uint2*)act2b,
                                                                             scale, shift, h, hb);
        } else {
            k_bnapply<true, false><<<N_NODES * H / 4 / 256, 256, 0, stream>>>((const uint2*)act2b,
                                                                              scale, shift, h, hb);
        }
    }

    // ---- pooling + head ----
    k_bounds<<<(N_NODES + 255) / 256, 256, 0, stream>>>(batch, row_begin);
    k_pool<<<N_GRAPHS, 128, 0, stream>>>(h, row_begin, pooled);
    k_final<<<N_GRAPHS, 128, 0, stream>>>(pooled, Wf, bf, out);
}

// Round 7
// 1419.645 us; speedup vs baseline: 2.4068x; 1.0775x over previous
//
#include <hip/hip_runtime.h>
#include <float.h>

#define N_NODES 100000
#define N_EDGES 3200000
#define N_GRAPHS 1024
#define F_IN 78
#define H 128
#define BN_EPS 1e-5f

#define BK_SHIFT 7
#define BK_NODES 128
#define NBUCKETS ((N_NODES + BK_NODES - 1) / BK_NODES)  // 782

#define P3_BLOCKS 800
#define P3_CHUNK 4000  // 800 * 4000 = 3.2M exactly

using short8 = __attribute__((ext_vector_type(8))) short;
using f32x4v = __attribute__((ext_vector_type(4))) float;

__device__ __forceinline__ unsigned short f2bf(float f) {
    unsigned int u = __float_as_uint(f);
    unsigned int r = (u + 0x7fffu + ((u >> 16) & 1u)) >> 16;
    return (unsigned short)r;
}
__device__ __forceinline__ float bf_lo(unsigned int u) { return __uint_as_float(u << 16); }
__device__ __forceinline__ float bf_hi(unsigned int u) { return __uint_as_float(u & 0xffff0000u); }

// ---------------- CSR build (atomic-free partition) ----------------

// per-block LDS histogram -> coalesced bofs[blk][NBUCKETS] (no global atomics)
__global__ __launch_bounds__(256) void k_hist(const int* __restrict__ dst,
                                              int* __restrict__ bofs) {
    __shared__ int lcnt[NBUCKETS];
    for (int i = threadIdx.x; i < NBUCKETS; i += 256) lcnt[i] = 0;
    __syncthreads();
    int base = blockIdx.x * P3_CHUNK;
    for (int j = threadIdx.x; j < P3_CHUNK; j += 256)
        atomicAdd(&lcnt[dst[base + j] >> BK_SHIFT], 1);
    __syncthreads();
    for (int i = threadIdx.x; i < NBUCKETS; i += 256)
        bofs[blockIdx.x * NBUCKETS + i] = lcnt[i];
}

// one block: exclusive column-scan of bofs per bucket + bucket prefix -> bbase
__global__ __launch_bounds__(1024) void k_scan2(int* __restrict__ bofs,
                                                int* __restrict__ bbase,
                                                int* __restrict__ row_start) {
    __shared__ int tot[1024];
    int b = threadIdx.x;
    int run = 0;
    if (b < NBUCKETS) {
#pragma unroll 8
        for (int blk = 0; blk < P3_BLOCKS; ++blk) {
            int v = bofs[blk * NBUCKETS + b];
            bofs[blk * NBUCKETS + b] = run;
            run += v;
        }
    }
    tot[threadIdx.x] = (b < NBUCKETS) ? run : 0;
    __syncthreads();
    if (threadIdx.x == 0) {
        int acc = 0;
        for (int i = 0; i < NBUCKETS; ++i) { int t = tot[i]; tot[i] = acc; acc += t; }
    }
    __syncthreads();
    if (b < NBUCKETS) bbase[b] = tot[b];
    if (threadIdx.x == 0) {
        bbase[NBUCKETS] = N_EDGES;
        row_start[N_NODES] = N_EDGES;
    }
}

// scatter packed (src<<7 | dst&127) via LDS cursors — zero global atomics
__global__ __launch_bounds__(256) void k_p3b(const int* __restrict__ src,
                                             const int* __restrict__ dst,
                                             const int* __restrict__ bofs,
                                             const int* __restrict__ bbase,
                                             unsigned int* __restrict__ ebuf) {
    __shared__ int cur[NBUCKETS];
    for (int i = threadIdx.x; i < NBUCKETS; i += 256)
        cur[i] = bbase[i] + bofs[blockIdx.x * NBUCKETS + i];
    __syncthreads();
    int base = blockIdx.x * P3_CHUNK;
    for (int j = threadIdx.x; j < P3_CHUNK; j += 256) {
        int d = dst[base + j];
        int p = atomicAdd(&cur[d >> BK_SHIFT], 1);
        ebuf[p] = ((unsigned int)src[base + j] << 7) | (unsigned int)(d & (BK_NODES - 1));
    }
}

// per-bucket node histogram + prefix -> row_start, then scatter esrc
__global__ __launch_bounds__(256) void k_p4(const int* __restrict__ bbase,
                                            const unsigned int* __restrict__ ebuf,
                                            int* __restrict__ esrc,
                                            int* __restrict__ row_start) {
    __shared__ int cur[BK_NODES];
    __shared__ int start[BK_NODES];
    int b = blockIdx.x;
    int nodeBase = b << BK_SHIFT;
    int nLocal = min(BK_NODES, N_NODES - nodeBase);
    if (threadIdx.x < BK_NODES) cur[threadIdx.x] = 0;
    __syncthreads();
    int s = bbase[b], e = bbase[b + 1];
    for (int p = s + threadIdx.x; p < e; p += 256)
        atomicAdd(&cur[ebuf[p] & (BK_NODES - 1)], 1);
    __syncthreads();
    if (threadIdx.x == 0) {
        int run = s;
        for (int i = 0; i < nLocal; ++i) { start[i] = run; run += cur[i]; }
    }
    __syncthreads();
    if (threadIdx.x < nLocal) {
        row_start[nodeBase + threadIdx.x] = start[threadIdx.x];
        cur[threadIdx.x] = start[threadIdx.x];
    }
    __syncthreads();
    for (int p = s + threadIdx.x; p < e; p += 256) {
        unsigned int ed = ebuf[p];
        int q = atomicAdd(&cur[ed & (BK_NODES - 1)], 1);
        esrc[q] = (int)(ed >> 7);
    }
}

// ---------------- bf16 prep ----------------

__global__ void k_cast_x(const float* __restrict__ x, unsigned short* __restrict__ xb) {
    int i = blockIdx.x * blockDim.x + threadIdx.x;
    if (i >= N_NODES * 96) return;
    int node = i / 96;
    int c = i - node * 96;
    float v = (c < F_IN) ? x[(size_t)node * F_IN + c] : 0.f;
    xb[i] = f2bf(v);
}

__global__ void k_cast_w(const float* __restrict__ W2_0, const float* __restrict__ W1,
                         const float* __restrict__ W2, unsigned short* __restrict__ Wt) {
    int i = blockIdx.x * blockDim.x + threadIdx.x;
    if (i >= 9 * H * H) return;
    int w = i >> 14, r = i & 16383;
    int n = r >> 7, k = r & 127;
    const float* s = (w == 0) ? W2_0 : (w <= 4 ? W1 + (w - 1) * H * H : W2 + (w - 5) * H * H);
    Wt[i] = f2bf(s[k * H + n]);
}

__global__ void k_cast_w0(const float* __restrict__ W1_0, unsigned short* __restrict__ Wt0) {
    int i = blockIdx.x * blockDim.x + threadIdx.x;
    if (i >= H * 96) return;
    int n = i / 96, k = i - n * 96;
    Wt0[i] = f2bf((k < F_IN) ? W1_0[k * H + n] : 0.f);
}

// ---------------- gather (aggregate) kernels ----------------

// layer 0: xb bf16 [N][96] (48 dwords); out = self+agg as bf16 [N][96]
__global__ void k_gather96(const unsigned int* __restrict__ xw,
                           const int* __restrict__ row_start, const int* __restrict__ esrc,
                           unsigned int* __restrict__ out) {
    int wave = threadIdx.x >> 6;
    int lane = threadIdx.x & 63;
    int node = blockIdx.x * 4 + wave;
    int s = row_start[node], e = row_start[node + 1];
    bool act = lane < 48;
    unsigned int su = act ? xw[node * 48 + lane] : 0u;
    float aA[8], aB[8];
#pragma unroll
    for (int j = 0; j < 8; ++j) { aA[j] = 0.f; aB[j] = 0.f; }
    aA[0] = bf_lo(su); aB[0] = bf_hi(su);
    int p = s;
    for (; p + 16 <= e; p += 16) {
        int idx[16];
#pragma unroll
        for (int j = 0; j < 16; ++j) idx[j] = esrc[p + j];
        unsigned int u[16];
#pragma unroll
        for (int j = 0; j < 16; ++j) u[j] = act ? xw[idx[j] * 48 + lane] : 0u;
#pragma unroll
        for (int j = 0; j < 16; ++j) { aA[j & 7] += bf_lo(u[j]); aB[j & 7] += bf_hi(u[j]); }
    }
    for (; p + 4 <= e; p += 4) {
        int i0 = esrc[p], i1 = esrc[p + 1], i2 = esrc[p + 2], i3 = esrc[p + 3];
        unsigned int u0 = act ? xw[i0 * 48 + lane] : 0u;
        unsigned int u1 = act ? xw[i1 * 48 + lane] : 0u;
        unsigned int u2 = act ? xw[i2 * 48 + lane] : 0u;
        unsigned int u3 = act ? xw[i3 * 48 + lane] : 0u;
        aA[0] += bf_lo(u0); aB[0] += bf_hi(u0); aA[1] += bf_lo(u1); aB[1] += bf_hi(u1);
        aA[2] += bf_lo(u2); aB[2] += bf_hi(u2); aA[3] += bf_lo(u3); aB[3] += bf_hi(u3);
    }
    for (; p < e; ++p) {
        unsigned int u = act ? xw[esrc[p] * 48 + lane] : 0u;
        aA[0] += bf_lo(u); aB[0] += bf_hi(u);
    }
    if (act) {
        float rx = ((aA[0] + aA[1]) + (aA[2] + aA[3])) + ((aA[4] + aA[5]) + (aA[6] + aA[7]));
        float ry = ((aB[0] + aB[1]) + (aB[2] + aB[3])) + ((aB[4] + aB[5]) + (aB[6] + aB[7]));
        out[node * 48 + lane] = (unsigned int)f2bf(rx) | ((unsigned int)f2bf(ry) << 16);
    }
}

// layers 1..4: hb bf16 [N][128]; 16 outstanding row loads
__global__ void k_gather128b(const unsigned int* __restrict__ hw,
                             const int* __restrict__ row_start, const int* __restrict__ esrc,
                             unsigned int* __restrict__ aggb) {
    int wave = threadIdx.x >> 6;
    int lane = threadIdx.x & 63;
    int node = blockIdx.x * 4 + wave;
    int s = row_start[node], e = row_start[node + 1];
    unsigned int su = hw[node * 64 + lane];
    float aA[8], aB[8];
#pragma unroll
    for (int j = 0; j < 8; ++j) { aA[j] = 0.f; aB[j] = 0.f; }
    aA[0] = bf_lo(su); aB[0] = bf_hi(su);
    int p = s;
    for (; p + 16 <= e; p += 16) {
        int idx[16];
#pragma unroll
        for (int j = 0; j < 16; ++j) idx[j] = esrc[p + j];
        unsigned int u[16];
#pragma unroll
        for (int j = 0; j < 16; ++j) u[j] = hw[idx[j] * 64 + lane];
#pragma unroll
        for (int j = 0; j < 16; ++j) { aA[j & 7] += bf_lo(u[j]); aB[j & 7] += bf_hi(u[j]); }
    }
    for (; p + 4 <= e; p += 4) {
        int i0 = esrc[p], i1 = esrc[p + 1], i2 = esrc[p + 2], i3 = esrc[p + 3];
        unsigned int u0 = hw[i0 * 64 + lane];
        unsigned int u1 = hw[i1 * 64 + lane];
        unsigned int u2 = hw[i2 * 64 + lane];
        unsigned int u3 = hw[i3 * 64 + lane];
        aA[0] += bf_lo(u0); aB[0] += bf_hi(u0); aA[1] += bf_lo(u1); aB[1] += bf_hi(u1);
        aA[2] += bf_lo(u2); aB[2] += bf_hi(u2); aA[3] += bf_lo(u3); aB[3] += bf_hi(u3);
    }
    for (; p < e; ++p) {
        unsigned int u = hw[esrc[p] * 64 + lane];
        aA[0] += bf_lo(u); aB[0] += bf_hi(u);
    }
    float rx = ((aA[0] + aA[1]) + (aA[2] + aA[3])) + ((aA[4] + aA[5]) + (aA[6] + aA[7]));
    float ry = ((aB[0] + aB[1]) + (aB[2] + aB[3])) + ((aB[4] + aB[5]) + (aB[6] + aB[7]));
    aggb[node * 64 + lane] = (unsigned int)f2bf(rx) | ((unsigned int)f2bf(ry) << 16);
}

// ---------------- MFMA GEMMs ----------------

template <int NK>
__global__ __launch_bounds__(256) void k_mfma1t(const short* __restrict__ A,
                                                const short* __restrict__ Wt,
                                                const float* __restrict__ bias,
                                                unsigned short* __restrict__ out) {
    const int K = NK * 32;
    int wave = threadIdx.x >> 6, lane = threadIdx.x & 63;
    int r0 = blockIdx.x * 64 + wave * 16;
    int lm = lane & 15, lk = lane >> 4;
    int arow = r0 + lm;
    if (arow >= N_NODES) arow = N_NODES - 1;
    const short8* Arow = (const short8*)(A + (size_t)arow * K);
    f32x4v acc[8];
#pragma unroll
    for (int n = 0; n < 8; ++n) {
        float bv = bias[n * 16 + lm];
        acc[n] = (f32x4v){bv, bv, bv, bv};
    }
#pragma unroll
    for (int ks = 0; ks < NK; ++ks) {
        short8 af = Arow[ks * 4 + lk];
#pragma unroll
        for (int n = 0; n < 8; ++n) {
            const short8* Brow = (const short8*)(Wt + (size_t)(n * 16 + lm) * K);
            short8 bfr = Brow[ks * 4 + lk];
            acc[n] = __builtin_amdgcn_mfma_f32_16x16x32_bf16(af, bfr, acc[n], 0, 0, 0);
        }
    }
#pragma unroll
    for (int n = 0; n < 8; ++n) {
        int col = n * 16 + lm;
#pragma unroll
        for (int rg = 0; rg < 4; ++rg) {
            int r = r0 + lk * 4 + rg;
            if (r < N_NODES) {
                float v = fmaxf(acc[n][rg], 0.f);
                out[(size_t)r * H + col] = f2bf(v);
            }
        }
    }
}

__global__ __launch_bounds__(256) void k_mfma2(const short* __restrict__ A,
                                               const short* __restrict__ Wt,
                                               const float* __restrict__ bias,
                                               unsigned short* __restrict__ out,
                                               float* __restrict__ gsum,
                                               float* __restrict__ gss) {
    __shared__ float lsum[H], lss[H];
    if (threadIdx.x < H) { lsum[threadIdx.x] = 0.f; lss[threadIdx.x] = 0.f; }
    __syncthreads();
    int wave = threadIdx.x >> 6, lane = threadIdx.x & 63;
    int r0 = blockIdx.x * 64 + wave * 16;
    int lm = lane & 15, lk = lane >> 4;
    int arow = r0 + lm;
    if (arow >= N_NODES) arow = N_NODES - 1;
    const short8* Arow = (const short8*)(A + (size_t)arow * H);
    f32x4v acc[8];
#pragma unroll
    for (int n = 0; n < 8; ++n) {
        float bv = bias[n * 16 + lm];
        acc[n] = (f32x4v){bv, bv, bv, bv};
    }
#pragma unroll
    for (int ks = 0; ks < 4; ++ks) {
        short8 af = Arow[ks * 4 + lk];
#pragma unroll
        for (int n = 0; n < 8; ++n) {
            const short8* Brow = (const short8*)(Wt + (size_t)(n * 16 + lm) * H);
            short8 bfr = Brow[ks * 4 + lk];
            acc[n] = __builtin_amdgcn_mfma_f32_16x16x32_bf16(af, bfr, acc[n], 0, 0, 0);
        }
    }
#pragma unroll
    for (int n = 0; n < 8; ++n) {
        int col = n * 16 + lm;
        float s = 0.f, q = 0.f;
#pragma unroll
        for (int rg = 0; rg < 4; ++rg) {
            int r = r0 + lk * 4 + rg;
            if (r < N_NODES) {
                float v = fmaxf(acc[n][rg], 0.f);
                out[(size_t)r * H + col] = f2bf(v);
                s += v;
                q += v * v;
            }
        }
        atomicAdd(&lsum[col], s);
        atomicAdd(&lss[col], q);
    }
    __syncthreads();
    if (threadIdx.x < H) {
        atomicAdd(&gsum[threadIdx.x], lsum[threadIdx.x]);
        atomicAdd(&gss[threadIdx.x], lss[threadIdx.x]);
    }
}

// ---------------- BN ----------------

__global__ void k_bnfinal(float* __restrict__ gsum, float* __restrict__ gss,
                          const float* __restrict__ gamma, const float* __restrict__ beta,
                          float* __restrict__ scale, float* __restrict__ shift) {
    int c = threadIdx.x;
    const float inv_n = 1.f / (float)N_NODES;
    float sv = gsum[c], qv = gss[c];
    gsum[c] = 0.f;
    gss[c] = 0.f;
    float mu = sv * inv_n;
    float var = fmaxf(qv * inv_n - mu * mu, 0.f);
    float sc = gamma[c] * rsqrtf(var + BN_EPS);
    scale[c] = sc;
    shift[c] = beta[c] - mu * sc;
}

template <bool RES, bool WB>
__global__ void k_bnapply(const uint2* __restrict__ vb, const float* __restrict__ scale,
                          const float* __restrict__ shift, float* __restrict__ h,
                          uint2* __restrict__ hb) {
    int idx = blockIdx.x * blockDim.x + threadIdx.x;
    if (idx >= N_NODES * H / 4) return;
    int c4 = idx & 31;
    uint2 pv = vb[idx];
    float4 val = make_float4(bf_lo(pv.x), bf_hi(pv.x), bf_lo(pv.y), bf_hi(pv.y));
    float4 sc = reinterpret_cast<const float4*>(scale)[c4];
    float4 sh = reinterpret_cast<const float4*>(shift)[c4];
    float4 r;
    r.x = val.x * sc.x + sh.x;
    r.y = val.y * sc.y + sh.y;
    r.z = val.z * sc.z + sh.z;
    r.w = val.w * sc.w + sh.w;
    if (RES) {
        float4 hv = reinterpret_cast<float4*>(h)[idx];
        r.x += hv.x; r.y += hv.y; r.z += hv.z; r.w += hv.w;
    }
    reinterpret_cast<float4*>(h)[idx] = r;
    if (WB) {
        uint2 pk;
        pk.x = (unsigned int)f2bf(r.x) | ((unsigned int)f2bf(r.y) << 16);
        pk.y = (unsigned int)f2bf(r.z) | ((unsigned int)f2bf(r.w) << 16);
        hb[idx] = pk;
    }
}

// ---------------- pooling + head ----------------

__global__ void k_bounds(const int* __restrict__ batch, int* __restrict__ row_begin) {
    int i = blockIdx.x * blockDim.x + threadIdx.x;
    if (i >= N_NODES) return;
    int bi = batch[i];
    int bp = (i == 0) ? -1 : batch[i - 1];
    for (int g = bp + 1; g <= bi; ++g) row_begin[g] = i;
    if (i == N_NODES - 1) {
        for (int g = bi + 1; g <= N_GRAPHS; ++g) row_begin[g] = N_NODES;
    }
}

__global__ void k_pool(const float* __restrict__ h, const int* __restrict__ row_begin,
                       float* __restrict__ pooled) {
    int g = blockIdx.x;
    int c = threadIdx.x;
    int s = row_begin[g], e = row_begin[g + 1];
    float sum = 0.f, mx = -FLT_MAX;
    for (int i = s; i < e; ++i) {
        float v = h[(size_t)i * H + c];
        sum += v;
        mx = fmaxf(mx, v);
    }
    int cnt = e - s;
    pooled[g * 256 + c]       = (cnt > 0) ? sum / (float)cnt : 0.f;
    pooled[g * 256 + 128 + c] = (cnt > 0) ? mx : 0.f;
}

__global__ void k_final(const float* __restrict__ pooled, const float* __restrict__ Wf,
                        const float* __restrict__ bf, float* __restrict__ out) {
    __shared__ float ps[256];
    int g = blockIdx.x, c = threadIdx.x;
    ps[c] = pooled[g * 256 + c];
    ps[128 + c] = pooled[g * 256 + 128 + c];
    __syncthreads();
    float acc = bf[c];
#pragma unroll 8
    for (int k = 0; k < 256; ++k) acc += ps[k] * Wf[k * H + c];
    out[g * H + c] = acc;
}

// ---------------- launcher ----------------

extern "C" void kernel_launch(void* const* d_in, const int* in_sizes, int n_in,
                              void* d_out, int out_size, void* d_ws, size_t ws_size,
                              hipStream_t stream) {
    const float* x     = (const float*)d_in[0];
    const int*   ei    = (const int*)d_in[1];
    const int*   src   = ei;
    const int*   dst   = ei + N_EDGES;
    const int*   batch = (const int*)d_in[2];
    const float* W1_0  = (const float*)d_in[3];
    const float* b1_0  = (const float*)d_in[4];
    const float* W2_0  = (const float*)d_in[5];
    const float* b2_0  = (const float*)d_in[6];
    const float* W1    = (const float*)d_in[7];
    const float* b1    = (const float*)d_in[8];
    const float* W2    = (const float*)d_in[9];
    const float* b2    = (const float*)d_in[10];
    const float* gamma = (const float*)d_in[11];
    const float* beta  = (const float*)d_in[12];
    const float* Wf    = (const float*)d_in[13];
    const float* bf    = (const float*)d_in[14];
    float* out = (float*)d_out;

    char* ws = (char*)d_ws;
    size_t off = 0;
    auto alloc = [&](size_t bytes) -> void* {
        void* p = ws + off;
        off = (off + bytes + 255) & ~(size_t)255;
        return p;
    };

    float* h    = (float*)alloc((size_t)N_NODES * H * 4);
    uint2* hb   = (uint2*)alloc((size_t)N_NODES * H * 2);
    unsigned int*   aggb  = (unsigned int*)alloc((size_t)N_NODES * H * 2);
    unsigned short* act1b = (unsigned short*)alloc((size_t)N_NODES * H * 2);
    unsigned short* act2b = (unsigned short*)alloc((size_t)N_NODES * H * 2);
    unsigned short* xb    = (unsigned short*)alloc((size_t)N_NODES * 96 * 2);
    unsigned int*   agg0b = (unsigned int*)alloc((size_t)N_NODES * 48 * 4);
    unsigned short* Wtall = (unsigned short*)alloc((size_t)9 * H * H * 2);
    unsigned short* Wt0   = (unsigned short*)alloc((size_t)H * 96 * 2);
    int* row_start = (int*)alloc((size_t)(N_NODES + 1) * 4);
    int* esrc      = (int*)alloc((size_t)N_EDGES * 4);
    unsigned int* ebuf = (unsigned int*)alloc((size_t)N_EDGES * 4);
    int* bofs      = (int*)alloc((size_t)P3_BLOCKS * NBUCKETS * 4);
    int* bbase     = (int*)alloc((size_t)(NBUCKETS + 1) * 4);
    float* gsum  = (float*)alloc(H * 4);
    float* gss   = (float*)alloc(H * 4);
    float* scale = (float*)alloc(H * 4);
    float* shift = (float*)alloc(H * 4);
    int* row_begin = (int*)alloc((size_t)(N_GRAPHS + 1) * 4);
    float* pooled  = (float*)alloc((size_t)N_GRAPHS * 256 * 4);

    // ---- prep (overlaps CSR build) ----
    k_cast_x<<<(N_NODES * 96 + 255) / 256, 256, 0, stream>>>(x, xb);
    k_cast_w<<<(9 * H * H + 255) / 256, 256, 0, stream>>>(W2_0, W1, W2, Wtall);
    k_cast_w0<<<(H * 96 + 255) / 256, 256, 0, stream>>>(W1_0, Wt0);

    // ---- CSR build (no global atomics) ----
    k_hist<<<P3_BLOCKS, 256, 0, stream>>>(dst, bofs);
    k_scan2<<<1, 1024, 0, stream>>>(bofs, bbase, row_start);
    k_p3b<<<P3_BLOCKS, 256, 0, stream>>>(src, dst, bofs, bbase, ebuf);
    k_p4<<<NBUCKETS, 256, 0, stream>>>(bbase, ebuf, esrc, row_start);

    // zero BN accumulators once per call (bnfinal self-resets for later layers)
    hipMemsetAsync(gsum, 0, H * 4, stream);
    hipMemsetAsync(gss, 0, H * 4, stream);

    const int mfma_grid = (N_NODES + 63) / 64;

    // ---- layer 0 (78 -> 128, no residual) ----
    k_gather96<<<N_NODES / 4, 256, 0, stream>>>((const unsigned int*)xb, row_start, esrc, agg0b);
    k_mfma1t<3><<<mfma_grid, 256, 0, stream>>>((const short*)agg0b, (const short*)Wt0,
                                               b1_0, act1b);
    k_mfma2<<<mfma_grid, 256, 0, stream>>>((const short*)act1b, (const short*)Wtall, b2_0,
                                           act2b, gsum, gss);
    k_bnfinal<<<1, 128, 0, stream>>>(gsum, gss, gamma, beta, scale, shift);
    k_bnapply<false, true><<<N_NODES * H / 4 / 256, 256, 0, stream>>>((const uint2*)act2b,
                                                                      scale, shift, h, hb);

    // ---- layers 1..4 (residual) ----
    for (int l = 0; l < 4; ++l) {
        k_gather128b<<<N_NODES / 4, 256, 0, stream>>>((const unsigned int*)hb, row_start,
                                                      esrc, aggb);
        k_mfma1t<4><<<mfma_grid, 256, 0, stream>>>((const short*)aggb,
                                                   (const short*)(Wtall + (1 + l) * H * H),
                                                   b1 + l * H, act1b);
        k_mfma2<<<mfma_grid, 256, 0, stream>>>((const short*)act1b,
                                               (const short*)(Wtall + (5 + l) * H * H),
                                               b2 + l * H, act2b, gsum, gss);
        k_bnfinal<<<1, 128, 0, stream>>>(gsum, gss, gamma + (l + 1) * H, beta + (l + 1) * H,
                                         scale, shift);
        if (l < 3) {
            k_bnapply<true, true><<<N_NODES * H / 4 / 256, 256, 0, stream>>>((const uint2*)act2b,
                                                                             scale, shift, h, hb);
        } else {
            k_bnapply<true, false><<<N_NODES * H / 4 / 256, 256, 0, stream>>>((const uint2*)act2b,
                                                                              scale, shift, h, hb);
        }
    }

    // ---- pooling + head ----
    k_bounds<<<(N_NODES + 255) / 256, 256, 0, stream>>>(batch, row_begin);
    k_pool<<<N_GRAPHS, 128, 0, stream>>>(h, row_begin, pooled);
    k_final<<<N_GRAPHS, 128, 0, stream>>>(pooled, Wf, bf, out);
}

// Round 8
// 1272.120 us; speedup vs baseline: 2.6859x; 1.1160x over previous
//
#include <hip/hip_runtime.h>
#include <float.h>

#define N_NODES 100000
#define N_EDGES 3200000
#define N_GRAPHS 1024
#define F_IN 78
#define H 128
#define BN_EPS 1e-5f

#define BK_SHIFT 7
#define BK_NODES 128
#define NBUCKETS ((N_NODES + BK_NODES - 1) / BK_NODES)  // 782

#define P3_BLOCKS 800
#define P3_CHUNK 4000  // 800 * 4000 = 3.2M exactly

using short8 = __attribute__((ext_vector_type(8))) short;
using f32x4v = __attribute__((ext_vector_type(4))) float;

__device__ __forceinline__ unsigned short f2bf(float f) {
    unsigned int u = __float_as_uint(f);
    unsigned int r = (u + 0x7fffu + ((u >> 16) & 1u)) >> 16;
    return (unsigned short)r;
}
__device__ __forceinline__ float bf_lo(unsigned int u) { return __uint_as_float(u << 16); }
__device__ __forceinline__ float bf_hi(unsigned int u) { return __uint_as_float(u & 0xffff0000u); }
__device__ __forceinline__ float bf1(unsigned short u) { return __uint_as_float((unsigned int)u << 16); }

// ---------------- CSR build (atomic-free partition) ----------------

__global__ __launch_bounds__(256) void k_hist(const int* __restrict__ dst,
                                              int* __restrict__ bofs) {
    __shared__ int lcnt[NBUCKETS];
    for (int i = threadIdx.x; i < NBUCKETS; i += 256) lcnt[i] = 0;
    __syncthreads();
    int base = blockIdx.x * P3_CHUNK;
    for (int j = threadIdx.x; j < P3_CHUNK; j += 256)
        atomicAdd(&lcnt[dst[base + j] >> BK_SHIFT], 1);
    __syncthreads();
    for (int i = threadIdx.x; i < NBUCKETS; i += 256)
        bofs[blockIdx.x * NBUCKETS + i] = lcnt[i];
}

// per-bucket exclusive scan across the 800 blocks (one block per bucket)
__global__ __launch_bounds__(256) void k_scan_a(int* __restrict__ bofs,
                                                int* __restrict__ btot) {
    __shared__ int part[256];
    int b = blockIdx.x, t = threadIdx.x;
    int val[4];
#pragma unroll
    for (int j = 0; j < 4; ++j) {
        int idx = t * 4 + j;
        val[j] = (idx < P3_BLOCKS) ? bofs[idx * NBUCKETS + b] : 0;
    }
    part[t] = val[0] + val[1] + val[2] + val[3];
    __syncthreads();
    if (t == 0) {
        int run = 0;
        for (int u = 0; u < 256; ++u) { int tmp = part[u]; part[u] = run; run += tmp; }
        btot[b] = run;
    }
    __syncthreads();
    int off = part[t];
#pragma unroll
    for (int j = 0; j < 4; ++j) {
        int idx = t * 4 + j;
        if (idx < P3_BLOCKS) {
            int tmp = val[j];
            bofs[idx * NBUCKETS + b] = off;
            off += tmp;
        }
    }
}

// scan 782 bucket totals -> bbase
__global__ __launch_bounds__(1024) void k_scan_b(const int* __restrict__ btot,
                                                 int* __restrict__ bbase,
                                                 int* __restrict__ row_start) {
    __shared__ int tot[1024];
    int t = threadIdx.x;
    tot[t] = (t < NBUCKETS) ? btot[t] : 0;
    __syncthreads();
    if (t == 0) {
        int acc = 0;
        for (int i = 0; i < NBUCKETS; ++i) { int v = tot[i]; tot[i] = acc; acc += v; }
    }
    __syncthreads();
    if (t < NBUCKETS) bbase[t] = tot[t];
    if (t == 0) {
        bbase[NBUCKETS] = N_EDGES;
        row_start[N_NODES] = N_EDGES;
    }
}

// scatter packed (src<<7 | dst&127) via LDS cursors — zero global atomics
__global__ __launch_bounds__(256) void k_p3b(const int* __restrict__ src,
                                             const int* __restrict__ dst,
                                             const int* __restrict__ bofs,
                                             const int* __restrict__ bbase,
                                             unsigned int* __restrict__ ebuf) {
    __shared__ int cur[NBUCKETS];
    for (int i = threadIdx.x; i < NBUCKETS; i += 256)
        cur[i] = bbase[i] + bofs[blockIdx.x * NBUCKETS + i];
    __syncthreads();
    int base = blockIdx.x * P3_CHUNK;
    for (int j = threadIdx.x; j < P3_CHUNK; j += 256) {
        int d = dst[base + j];
        int p = atomicAdd(&cur[d >> BK_SHIFT], 1);
        ebuf[p] = ((unsigned int)src[base + j] << 7) | (unsigned int)(d & (BK_NODES - 1));
    }
}

// per-bucket node histogram + prefix -> row_start, then scatter esrc
__global__ __launch_bounds__(256) void k_p4(const int* __restrict__ bbase,
                                            const unsigned int* __restrict__ ebuf,
                                            int* __restrict__ esrc,
                                            int* __restrict__ row_start) {
    __shared__ int cur[BK_NODES];
    __shared__ int start[BK_NODES];
    int b = blockIdx.x;
    int nodeBase = b << BK_SHIFT;
    int nLocal = min(BK_NODES, N_NODES - nodeBase);
    if (threadIdx.x < BK_NODES) cur[threadIdx.x] = 0;
    __syncthreads();
    int s = bbase[b], e = bbase[b + 1];
    for (int p = s + threadIdx.x; p < e; p += 256)
        atomicAdd(&cur[ebuf[p] & (BK_NODES - 1)], 1);
    __syncthreads();
    if (threadIdx.x == 0) {
        int run = s;
        for (int i = 0; i < nLocal; ++i) { start[i] = run; run += cur[i]; }
    }
    __syncthreads();
    if (threadIdx.x < nLocal) {
        row_start[nodeBase + threadIdx.x] = start[threadIdx.x];
        cur[threadIdx.x] = start[threadIdx.x];
    }
    __syncthreads();
    for (int p = s + threadIdx.x; p < e; p += 256) {
        unsigned int ed = ebuf[p];
        int q = atomicAdd(&cur[ed & (BK_NODES - 1)], 1);
        esrc[q] = (int)(ed >> 7);
    }
}

// ---------------- bf16 prep ----------------

__global__ void k_cast_x(const float* __restrict__ x, unsigned short* __restrict__ xb) {
    int i = blockIdx.x * blockDim.x + threadIdx.x;
    if (i >= N_NODES * 96) return;
    int node = i / 96;
    int c = i - node * 96;
    float v = (c < F_IN) ? x[(size_t)node * F_IN + c] : 0.f;
    xb[i] = f2bf(v);
}

__global__ void k_cast_w(const float* __restrict__ W2_0, const float* __restrict__ W1,
                         const float* __restrict__ W2, unsigned short* __restrict__ Wt) {
    int i = blockIdx.x * blockDim.x + threadIdx.x;
    if (i >= 9 * H * H) return;
    int w = i >> 14, r = i & 16383;
    int n = r >> 7, k = r & 127;
    const float* s = (w == 0) ? W2_0 : (w <= 4 ? W1 + (w - 1) * H * H : W2 + (w - 5) * H * H);
    Wt[i] = f2bf(s[k * H + n]);
}

__global__ void k_cast_w0(const float* __restrict__ W1_0, unsigned short* __restrict__ Wt0) {
    int i = blockIdx.x * blockDim.x + threadIdx.x;
    if (i >= H * 96) return;
    int n = i / 96, k = i - n * 96;
    Wt0[i] = f2bf((k < F_IN) ? W1_0[k * H + n] : 0.f);
}

// ---------------- gather (aggregate) kernels ----------------

__global__ void k_gather96(const unsigned int* __restrict__ xw,
                           const int* __restrict__ row_start, const int* __restrict__ esrc,
                           unsigned int* __restrict__ out) {
    int wave = threadIdx.x >> 6;
    int lane = threadIdx.x & 63;
    int node = blockIdx.x * 4 + wave;
    int s = row_start[node], e = row_start[node + 1];
    bool act = lane < 48;
    unsigned int su = act ? xw[node * 48 + lane] : 0u;
    float aA[8], aB[8];
#pragma unroll
    for (int j = 0; j < 8; ++j) { aA[j] = 0.f; aB[j] = 0.f; }
    aA[0] = bf_lo(su); aB[0] = bf_hi(su);
    int p = s;
    for (; p + 16 <= e; p += 16) {
        int idx[16];
#pragma unroll
        for (int j = 0; j < 16; ++j) idx[j] = esrc[p + j];
        unsigned int u[16];
#pragma unroll
        for (int j = 0; j < 16; ++j) u[j] = act ? xw[idx[j] * 48 + lane] : 0u;
#pragma unroll
        for (int j = 0; j < 16; ++j) { aA[j & 7] += bf_lo(u[j]); aB[j & 7] += bf_hi(u[j]); }
    }
    for (; p + 4 <= e; p += 4) {
        int i0 = esrc[p], i1 = esrc[p + 1], i2 = esrc[p + 2], i3 = esrc[p + 3];
        unsigned int u0 = act ? xw[i0 * 48 + lane] : 0u;
        unsigned int u1 = act ? xw[i1 * 48 + lane] : 0u;
        unsigned int u2 = act ? xw[i2 * 48 + lane] : 0u;
        unsigned int u3 = act ? xw[i3 * 48 + lane] : 0u;
        aA[0] += bf_lo(u0); aB[0] += bf_hi(u0); aA[1] += bf_lo(u1); aB[1] += bf_hi(u1);
        aA[2] += bf_lo(u2); aB[2] += bf_hi(u2); aA[3] += bf_lo(u3); aB[3] += bf_hi(u3);
    }
    for (; p < e; ++p) {
        unsigned int u = act ? xw[esrc[p] * 48 + lane] : 0u;
        aA[0] += bf_lo(u); aB[0] += bf_hi(u);
    }
    if (act) {
        float rx = ((aA[0] + aA[1]) + (aA[2] + aA[3])) + ((aA[4] + aA[5]) + (aA[6] + aA[7]));
        float ry = ((aB[0] + aB[1]) + (aB[2] + aB[3])) + ((aB[4] + aB[5]) + (aB[6] + aB[7]));
        out[node * 48 + lane] = (unsigned int)f2bf(rx) | ((unsigned int)f2bf(ry) << 16);
    }
}

__global__ void k_gather128b(const unsigned int* __restrict__ hw,
                             const int* __restrict__ row_start, const int* __restrict__ esrc,
                             unsigned int* __restrict__ aggb) {
    int wave = threadIdx.x >> 6;
    int lane = threadIdx.x & 63;
    int node = blockIdx.x * 4 + wave;
    int s = row_start[node], e = row_start[node + 1];
    unsigned int su = hw[node * 64 + lane];
    float aA[8], aB[8];
#pragma unroll
    for (int j = 0; j < 8; ++j) { aA[j] = 0.f; aB[j] = 0.f; }
    aA[0] = bf_lo(su); aB[0] = bf_hi(su);
    int p = s;
    for (; p + 16 <= e; p += 16) {
        int idx[16];
#pragma unroll
        for (int j = 0; j < 16; ++j) idx[j] = esrc[p + j];
        unsigned int u[16];
#pragma unroll
        for (int j = 0; j < 16; ++j) u[j] = hw[idx[j] * 64 + lane];
#pragma unroll
        for (int j = 0; j < 16; ++j) { aA[j & 7] += bf_lo(u[j]); aB[j & 7] += bf_hi(u[j]); }
    }
    for (; p + 4 <= e; p += 4) {
        int i0 = esrc[p], i1 = esrc[p + 1], i2 = esrc[p + 2], i3 = esrc[p + 3];
        unsigned int u0 = hw[i0 * 64 + lane];
        unsigned int u1 = hw[i1 * 64 + lane];
        unsigned int u2 = hw[i2 * 64 + lane];
        unsigned int u3 = hw[i3 * 64 + lane];
        aA[0] += bf_lo(u0); aB[0] += bf_hi(u0); aA[1] += bf_lo(u1); aB[1] += bf_hi(u1);
        aA[2] += bf_lo(u2); aB[2] += bf_hi(u2); aA[3] += bf_lo(u3); aB[3] += bf_hi(u3);
    }
    for (; p < e; ++p) {
        unsigned int u = hw[esrc[p] * 64 + lane];
        aA[0] += bf_lo(u); aB[0] += bf_hi(u);
    }
    float rx = ((aA[0] + aA[1]) + (aA[2] + aA[3])) + ((aA[4] + aA[5]) + (aA[6] + aA[7]));
    float ry = ((aB[0] + aB[1]) + (aB[2] + aB[3])) + ((aB[4] + aB[5]) + (aB[6] + aB[7]));
    aggb[node * 64 + lane] = (unsigned int)f2bf(rx) | ((unsigned int)f2bf(ry) << 16);
}

// ---------------- fused 2-GEMM MLP (MFMA, bf16) ----------------
// Phase 1: act1 = relu(A @ W1 + b1) -> LDS tile (64 x 128 bf16, XOR-swizzled).
// Phase 2: out = relu(act1 @ W2 + b2) -> bf16 global + fused BN stats.
// block = 4 waves x 16 rows; each wave reads/writes only its own 16 LDS rows.

template <int NK1>
__global__ __launch_bounds__(256) void k_mlp(const short* __restrict__ A,
                                             const short* __restrict__ Wt1,
                                             const float* __restrict__ b1v,
                                             const short* __restrict__ Wt2,
                                             const float* __restrict__ b2v,
                                             unsigned short* __restrict__ out,
                                             float* __restrict__ gsum,
                                             float* __restrict__ gss) {
    const int K1 = NK1 * 32;
    __shared__ unsigned short act1[64 * H];  // 16 KB
    __shared__ float lsum[H], lss[H];
    if (threadIdx.x < H) { lsum[threadIdx.x] = 0.f; lss[threadIdx.x] = 0.f; }
    int wave = threadIdx.x >> 6, lane = threadIdx.x & 63;
    int r0 = blockIdx.x * 64 + wave * 16;
    int lm = lane & 15, lk = lane >> 4;
    int arow = r0 + lm;
    if (arow >= N_NODES) arow = N_NODES - 1;
    const short8* Arow = (const short8*)(A + (size_t)arow * K1);
    f32x4v acc[8];
#pragma unroll
    for (int n = 0; n < 8; ++n) {
        float bv = b1v[n * 16 + lm];
        acc[n] = (f32x4v){bv, bv, bv, bv};
    }
#pragma unroll
    for (int ks = 0; ks < NK1; ++ks) {
        short8 af = Arow[ks * 4 + lk];
#pragma unroll
        for (int n = 0; n < 8; ++n) {
            const short8* Brow = (const short8*)(Wt1 + (size_t)(n * 16 + lm) * K1);
            short8 bfr = Brow[ks * 4 + lk];
            acc[n] = __builtin_amdgcn_mfma_f32_16x16x32_bf16(af, bfr, acc[n], 0, 0, 0);
        }
    }
    // phase-1 epilogue: relu -> LDS (swizzled rows)
#pragma unroll
    for (int n = 0; n < 8; ++n) {
        int colb = (n * 16 + lm) * 2;
#pragma unroll
        for (int rg = 0; rg < 4; ++rg) {
            int rl = wave * 16 + lk * 4 + rg;
            int byte = (rl * 256 + colb) ^ ((rl & 7) << 4);
            *(unsigned short*)((char*)act1 + byte) = f2bf(fmaxf(acc[n][rg], 0.f));
        }
    }
    __syncthreads();
    // phase 2: A from LDS
    f32x4v acc2[8];
#pragma unroll
    for (int n = 0; n < 8; ++n) {
        float bv = b2v[n * 16 + lm];
        acc2[n] = (f32x4v){bv, bv, bv, bv};
    }
    int rlr = wave * 16 + lm;
#pragma unroll
    for (int ks = 0; ks < 4; ++ks) {
        int byte = (rlr * 256 + ks * 64 + lk * 16) ^ ((rlr & 7) << 4);
        short8 af = *(const short8*)((char*)act1 + byte);
#pragma unroll
        for (int n = 0; n < 8; ++n) {
            const short8* Brow = (const short8*)(Wt2 + (size_t)(n * 16 + lm) * H);
            short8 bfr = Brow[ks * 4 + lk];
            acc2[n] = __builtin_amdgcn_mfma_f32_16x16x32_bf16(af, bfr, acc2[n], 0, 0, 0);
        }
    }
#pragma unroll
    for (int n = 0; n < 8; ++n) {
        int col = n * 16 + lm;
        float s = 0.f, q = 0.f;
#pragma unroll
        for (int rg = 0; rg < 4; ++rg) {
            int r = r0 + lk * 4 + rg;
            if (r < N_NODES) {
                float v = fmaxf(acc2[n][rg], 0.f);
                out[(size_t)r * H + col] = f2bf(v);
                s += v;
                q += v * v;
            }
        }
        atomicAdd(&lsum[col], s);
        atomicAdd(&lss[col], q);
    }
    __syncthreads();
    if (threadIdx.x < H) {
        atomicAdd(&gsum[threadIdx.x], lsum[threadIdx.x]);
        atomicAdd(&gss[threadIdx.x], lss[threadIdx.x]);
    }
}

// ---------------- BN ----------------

__global__ void k_bnfinal(float* __restrict__ gsum, float* __restrict__ gss,
                          const float* __restrict__ gamma, const float* __restrict__ beta,
                          float* __restrict__ scale, float* __restrict__ shift) {
    int c = threadIdx.x;
    const float inv_n = 1.f / (float)N_NODES;
    float sv = gsum[c], qv = gss[c];
    gsum[c] = 0.f;
    gss[c] = 0.f;
    float mu = sv * inv_n;
    float var = fmaxf(qv * inv_n - mu * mu, 0.f);
    float sc = gamma[c] * rsqrtf(var + BN_EPS);
    scale[c] = sc;
    shift[c] = beta[c] - mu * sc;
}

template <bool RES, bool WB>
__global__ void k_bnapply(const uint2* __restrict__ vb, const float* __restrict__ scale,
                          const float* __restrict__ shift, float* __restrict__ h,
                          uint2* __restrict__ hb) {
    int idx = blockIdx.x * blockDim.x + threadIdx.x;
    if (idx >= N_NODES * H / 4) return;
    int c4 = idx & 31;
    uint2 pv = vb[idx];
    float4 val = make_float4(bf_lo(pv.x), bf_hi(pv.x), bf_lo(pv.y), bf_hi(pv.y));
    float4 sc = reinterpret_cast<const float4*>(scale)[c4];
    float4 sh = reinterpret_cast<const float4*>(shift)[c4];
    float4 r;
    r.x = val.x * sc.x + sh.x;
    r.y = val.y * sc.y + sh.y;
    r.z = val.z * sc.z + sh.z;
    r.w = val.w * sc.w + sh.w;
    if (RES) {
        float4 hv = reinterpret_cast<float4*>(h)[idx];
        r.x += hv.x; r.y += hv.y; r.z += hv.z; r.w += hv.w;
    }
    reinterpret_cast<float4*>(h)[idx] = r;
    if (WB) {
        uint2 pk;
        pk.x = (unsigned int)f2bf(r.x) | ((unsigned int)f2bf(r.y) << 16);
        pk.y = (unsigned int)f2bf(r.z) | ((unsigned int)f2bf(r.w) << 16);
        hb[idx] = pk;
    }
}

// ---------------- pooling + head ----------------

__global__ void k_bounds(const int* __restrict__ batch, int* __restrict__ row_begin) {
    int i = blockIdx.x * blockDim.x + threadIdx.x;
    if (i >= N_NODES) return;
    int bi = batch[i];
    int bp = (i == 0) ? -1 : batch[i - 1];
    for (int g = bp + 1; g <= bi; ++g) row_begin[g] = i;
    if (i == N_NODES - 1) {
        for (int g = bi + 1; g <= N_GRAPHS; ++g) row_begin[g] = N_NODES;
    }
}

// fused: h4 = h3 + scale*act + shift computed on the fly, then mean/max pool
__global__ void k_pool_f(const unsigned short* __restrict__ act, const float* __restrict__ scale,
                         const float* __restrict__ shift, const float* __restrict__ h3,
                         const int* __restrict__ row_begin, float* __restrict__ pooled) {
    int g = blockIdx.x;
    int c = threadIdx.x;  // 128
    float sc = scale[c], sh = shift[c];
    int s = row_begin[g], e = row_begin[g + 1];
    float sum = 0.f, mx = -FLT_MAX;
    for (int i = s; i < e; ++i) {
        float v = h3[(size_t)i * H + c] + sc * bf1(act[(size_t)i * H + c]) + sh;
        sum += v;
        mx = fmaxf(mx, v);
    }
    int cnt = e - s;
    pooled[g * 256 + c]       = (cnt > 0) ? sum / (float)cnt : 0.f;
    pooled[g * 256 + 128 + c] = (cnt > 0) ? mx : 0.f;
}

__global__ void k_final(const float* __restrict__ pooled, const float* __restrict__ Wf,
                        const float* __restrict__ bf, float* __restrict__ out) {
    __shared__ float ps[256];
    int g = blockIdx.x, c = threadIdx.x;
    ps[c] = pooled[g * 256 + c];
    ps[128 + c] = pooled[g * 256 + 128 + c];
    __syncthreads();
    float acc = bf[c];
#pragma unroll 8
    for (int k = 0; k < 256; ++k) acc += ps[k] * Wf[k * H + c];
    out[g * H + c] = acc;
}

// ---------------- launcher ----------------

extern "C" void kernel_launch(void* const* d_in, const int* in_sizes, int n_in,
                              void* d_out, int out_size, void* d_ws, size_t ws_size,
                              hipStream_t stream) {
    const float* x     = (const float*)d_in[0];
    const int*   ei    = (const int*)d_in[1];
    const int*   src   = ei;
    const int*   dst   = ei + N_EDGES;
    const int*   batch = (const int*)d_in[2];
    const float* W1_0  = (const float*)d_in[3];
    const float* b1_0  = (const float*)d_in[4];
    const float* W2_0  = (const float*)d_in[5];
    const float* b2_0  = (const float*)d_in[6];
    const float* W1    = (const float*)d_in[7];
    const float* b1    = (const float*)d_in[8];
    const float* W2    = (const float*)d_in[9];
    const float* b2    = (const float*)d_in[10];
    const float* gamma = (const float*)d_in[11];
    const float* beta  = (const float*)d_in[12];
    const float* Wf    = (const float*)d_in[13];
    const float* bf    = (const float*)d_in[14];
    float* out = (float*)d_out;

    char* ws = (char*)d_ws;
    size_t off = 0;
    auto alloc = [&](size_t bytes) -> void* {
        void* p = ws + off;
        off = (off + bytes + 255) & ~(size_t)255;
        return p;
    };

    float* h    = (float*)alloc((size_t)N_NODES * H * 4);
    uint2* hb   = (uint2*)alloc((size_t)N_NODES * H * 2);
    unsigned int*   aggb  = (unsigned int*)alloc((size_t)N_NODES * H * 2);
    unsigned short* act2b = (unsigned short*)alloc((size_t)N_NODES * H * 2);
    unsigned short* xb    = (unsigned short*)alloc((size_t)N_NODES * 96 * 2);
    unsigned int*   agg0b = (unsigned int*)alloc((size_t)N_NODES * 48 * 4);
    unsigned short* Wtall = (unsigned short*)alloc((size_t)9 * H * H * 2);
    unsigned short* Wt0   = (unsigned short*)alloc((size_t)H * 96 * 2);
    int* row_start = (int*)alloc((size_t)(N_NODES + 1) * 4);
    int* esrc      = (int*)alloc((size_t)N_EDGES * 4);
    unsigned int* ebuf = (unsigned int*)alloc((size_t)N_EDGES * 4);
    int* bofs      = (int*)alloc((size_t)P3_BLOCKS * NBUCKETS * 4);
    int* btot      = (int*)alloc((size_t)NBUCKETS * 4);
    int* bbase     = (int*)alloc((size_t)(NBUCKETS + 1) * 4);
    float* gsum  = (float*)alloc(H * 4);
    float* gss   = (float*)alloc(H * 4);
    float* scale = (float*)alloc(H * 4);
    float* shift = (float*)alloc(H * 4);
    int* row_begin = (int*)alloc((size_t)(N_GRAPHS + 1) * 4);
    float* pooled  = (float*)alloc((size_t)N_GRAPHS * 256 * 4);

    // ---- prep ----
    k_cast_x<<<(N_NODES * 96 + 255) / 256, 256, 0, stream>>>(x, xb);
    k_cast_w<<<(9 * H * H + 255) / 256, 256, 0, stream>>>(W2_0, W1, W2, Wtall);
    k_cast_w0<<<(H * 96 + 255) / 256, 256, 0, stream>>>(W1_0, Wt0);

    // ---- CSR build (no global atomics) ----
    k_hist<<<P3_BLOCKS, 256, 0, stream>>>(dst, bofs);
    k_scan_a<<<NBUCKETS, 256, 0, stream>>>(bofs, btot);
    k_scan_b<<<1, 1024, 0, stream>>>(btot, bbase, row_start);
    k_p3b<<<P3_BLOCKS, 256, 0, stream>>>(src, dst, bofs, bbase, ebuf);
    k_p4<<<NBUCKETS, 256, 0, stream>>>(bbase, ebuf, esrc, row_start);

    // zero BN accumulators once per call (bnfinal self-resets for later layers)
    hipMemsetAsync(gsum, 0, H * 4, stream);
    hipMemsetAsync(gss, 0, H * 4, stream);

    const int mfma_grid = (N_NODES + 63) / 64;

    // ---- layer 0 (78 -> 128, no residual) ----
    k_gather96<<<N_NODES / 4, 256, 0, stream>>>((const unsigned int*)xb, row_start, esrc, agg0b);
    k_mlp<3><<<mfma_grid, 256, 0, stream>>>((const short*)agg0b, (const short*)Wt0, b1_0,
                                            (const short*)Wtall, b2_0, act2b, gsum, gss);
    k_bnfinal<<<1, 128, 0, stream>>>(gsum, gss, gamma, beta, scale, shift);
    k_bnapply<false, true><<<N_NODES * H / 4 / 256, 256, 0, stream>>>((const uint2*)act2b,
                                                                      scale, shift, h, hb);

    // ---- layers 1..4 (residual) ----
    for (int l = 0; l < 4; ++l) {
        k_gather128b<<<N_NODES / 4, 256, 0, stream>>>((const unsigned int*)hb, row_start,
                                                      esrc, aggb);
        k_mlp<4><<<mfma_grid, 256, 0, stream>>>((const short*)aggb,
                                                (const short*)(Wtall + (1 + l) * H * H),
                                                b1 + l * H,
                                                (const short*)(Wtall + (5 + l) * H * H),
                                                b2 + l * H, act2b, gsum, gss);
        k_bnfinal<<<1, 128, 0, stream>>>(gsum, gss, gamma + (l + 1) * H, beta + (l + 1) * H,
                                         scale, shift);
        if (l < 3) {
            k_bnapply<true, true><<<N_NODES * H / 4 / 256, 256, 0, stream>>>((const uint2*)act2b,
                                                                             scale, shift, h, hb);
        }
        // l == 3: bnapply fused into k_pool_f below
    }

    // ---- pooling + head ----
    k_bounds<<<(N_NODES + 255) / 256, 256, 0, stream>>>(batch, row_begin);
    k_pool_f<<<N_GRAPHS, 128, 0, stream>>>(act2b, scale, shift, h, row_begin, pooled);
    k_final<<<N_GRAPHS, 128, 0, stream>>>(pooled, Wf, bf, out);
}

// Round 9
// 1241.231 us; speedup vs baseline: 2.7527x; 1.0249x over previous
//
#include <hip/hip_runtime.h>
#include <float.h>

#define N_NODES 100000
#define N_EDGES 3200000
#define N_GRAPHS 1024
#define F_IN 78
#define H 128
#define BN_EPS 1e-5f

#define BK_SHIFT 7
#define BK_NODES 128
#define NBUCKETS ((N_NODES + BK_NODES - 1) / BK_NODES)  // 782

#define P3_BLOCKS 200
#define P3_CHUNK 16000  // 200 * 16000 = 3.2M exactly

using short8 = __attribute__((ext_vector_type(8))) short;
using f32x4v = __attribute__((ext_vector_type(4))) float;

__device__ __forceinline__ unsigned short f2bf(float f) {
    unsigned int u = __float_as_uint(f);
    unsigned int r = (u + 0x7fffu + ((u >> 16) & 1u)) >> 16;
    return (unsigned short)r;
}
__device__ __forceinline__ float bf_lo(unsigned int u) { return __uint_as_float(u << 16); }
__device__ __forceinline__ float bf_hi(unsigned int u) { return __uint_as_float(u & 0xffff0000u); }
__device__ __forceinline__ float bf1(unsigned short u) { return __uint_as_float((unsigned int)u << 16); }

// ---------------- CSR build (atomic-free partition) ----------------

__global__ __launch_bounds__(256) void k_hist(const int* __restrict__ dst,
                                              int* __restrict__ bofs) {
    __shared__ int lcnt[NBUCKETS];
    for (int i = threadIdx.x; i < NBUCKETS; i += 256) lcnt[i] = 0;
    __syncthreads();
    int base = blockIdx.x * P3_CHUNK;
    for (int j = threadIdx.x; j < P3_CHUNK; j += 256)
        atomicAdd(&lcnt[dst[base + j] >> BK_SHIFT], 1);
    __syncthreads();
    for (int i = threadIdx.x; i < NBUCKETS; i += 256)
        bofs[blockIdx.x * NBUCKETS + i] = lcnt[i];
}

// per-bucket exclusive scan across the P3_BLOCKS blocks (one block per bucket)
__global__ __launch_bounds__(256) void k_scan_a(int* __restrict__ bofs,
                                                int* __restrict__ btot) {
    __shared__ int part[256];
    int b = blockIdx.x, t = threadIdx.x;
    int val = (t < P3_BLOCKS) ? bofs[t * NBUCKETS + b] : 0;
    part[t] = val;
    __syncthreads();
    if (t == 0) {
        int run = 0;
        for (int u = 0; u < P3_BLOCKS; ++u) { int tmp = part[u]; part[u] = run; run += tmp; }
        btot[b] = run;
    }
    __syncthreads();
    if (t < P3_BLOCKS) bofs[t * NBUCKETS + b] = part[t];
}

// scan 782 bucket totals -> bbase
__global__ __launch_bounds__(1024) void k_scan_b(const int* __restrict__ btot,
                                                 int* __restrict__ bbase,
                                                 int* __restrict__ row_start) {
    __shared__ int tot[1024];
    int t = threadIdx.x;
    tot[t] = (t < NBUCKETS) ? btot[t] : 0;
    __syncthreads();
    if (t == 0) {
        int acc = 0;
        for (int i = 0; i < NBUCKETS; ++i) { int v = tot[i]; tot[i] = acc; acc += v; }
    }
    __syncthreads();
    if (t < NBUCKETS) bbase[t] = tot[t];
    if (t == 0) {
        bbase[NBUCKETS] = N_EDGES;
        row_start[N_NODES] = N_EDGES;
    }
}

// scatter packed (src<<7 | dst&127) via LDS cursors — zero global atomics
__global__ __launch_bounds__(256) void k_p3b(const int* __restrict__ src,
                                             const int* __restrict__ dst,
                                             const int* __restrict__ bofs,
                                             const int* __restrict__ bbase,
                                             unsigned int* __restrict__ ebuf) {
    __shared__ int cur[NBUCKETS];
    for (int i = threadIdx.x; i < NBUCKETS; i += 256)
        cur[i] = bbase[i] + bofs[blockIdx.x * NBUCKETS + i];
    __syncthreads();
    int base = blockIdx.x * P3_CHUNK;
    for (int j = threadIdx.x; j < P3_CHUNK; j += 256) {
        int d = dst[base + j];
        int p = atomicAdd(&cur[d >> BK_SHIFT], 1);
        ebuf[p] = ((unsigned int)src[base + j] << 7) | (unsigned int)(d & (BK_NODES - 1));
    }
}

// per-bucket node histogram + prefix -> row_start, then scatter esrc
__global__ __launch_bounds__(256) void k_p4(const int* __restrict__ bbase,
                                            const unsigned int* __restrict__ ebuf,
                                            int* __restrict__ esrc,
                                            int* __restrict__ row_start) {
    __shared__ int cur[BK_NODES];
    __shared__ int start[BK_NODES];
    int b = blockIdx.x;
    int nodeBase = b << BK_SHIFT;
    int nLocal = min(BK_NODES, N_NODES - nodeBase);
    if (threadIdx.x < BK_NODES) cur[threadIdx.x] = 0;
    __syncthreads();
    int s = bbase[b], e = bbase[b + 1];
    for (int p = s + threadIdx.x; p < e; p += 256)
        atomicAdd(&cur[ebuf[p] & (BK_NODES - 1)], 1);
    __syncthreads();
    if (threadIdx.x == 0) {
        int run = s;
        for (int i = 0; i < nLocal; ++i) { start[i] = run; run += cur[i]; }
    }
    __syncthreads();
    if (threadIdx.x < nLocal) {
        row_start[nodeBase + threadIdx.x] = start[threadIdx.x];
        cur[threadIdx.x] = start[threadIdx.x];
    }
    __syncthreads();
    for (int p = s + threadIdx.x; p < e; p += 256) {
        unsigned int ed = ebuf[p];
        int q = atomicAdd(&cur[ed & (BK_NODES - 1)], 1);
        esrc[q] = (int)(ed >> 7);
    }
}

// ---------------- bf16 prep ----------------

__global__ void k_cast_x(const float* __restrict__ x, unsigned short* __restrict__ xb) {
    int i = blockIdx.x * blockDim.x + threadIdx.x;
    if (i >= N_NODES * 96) return;
    int node = i / 96;
    int c = i - node * 96;
    float v = (c < F_IN) ? x[(size_t)node * F_IN + c] : 0.f;
    xb[i] = f2bf(v);
}

__global__ void k_cast_w(const float* __restrict__ W2_0, const float* __restrict__ W1,
                         const float* __restrict__ W2, unsigned short* __restrict__ Wt) {
    int i = blockIdx.x * blockDim.x + threadIdx.x;
    if (i >= 9 * H * H) return;
    int w = i >> 14, r = i & 16383;
    int n = r >> 7, k = r & 127;
    const float* s = (w == 0) ? W2_0 : (w <= 4 ? W1 + (w - 1) * H * H : W2 + (w - 5) * H * H);
    Wt[i] = f2bf(s[k * H + n]);
}

__global__ void k_cast_w0(const float* __restrict__ W1_0, unsigned short* __restrict__ Wt0) {
    int i = blockIdx.x * blockDim.x + threadIdx.x;
    if (i >= H * 96) return;
    int n = i / 96, k = i - n * 96;
    Wt0[i] = f2bf((k < F_IN) ? W1_0[k * H + n] : 0.f);
}

// ---------------- gather (aggregate) kernels ----------------

__global__ void k_gather96(const unsigned int* __restrict__ xw,
                           const int* __restrict__ row_start, const int* __restrict__ esrc,
                           unsigned int* __restrict__ out) {
    int wave = threadIdx.x >> 6;
    int lane = threadIdx.x & 63;
    int node = blockIdx.x * 4 + wave;
    int s = row_start[node], e = row_start[node + 1];
    bool act = lane < 48;
    unsigned int su = act ? xw[node * 48 + lane] : 0u;
    float aA[8], aB[8];
#pragma unroll
    for (int j = 0; j < 8; ++j) { aA[j] = 0.f; aB[j] = 0.f; }
    aA[0] = bf_lo(su); aB[0] = bf_hi(su);
    int p = s;
    for (; p + 16 <= e; p += 16) {
        int idx[16];
#pragma unroll
        for (int j = 0; j < 16; ++j) idx[j] = esrc[p + j];
        unsigned int u[16];
#pragma unroll
        for (int j = 0; j < 16; ++j) u[j] = act ? xw[idx[j] * 48 + lane] : 0u;
#pragma unroll
        for (int j = 0; j < 16; ++j) { aA[j & 7] += bf_lo(u[j]); aB[j & 7] += bf_hi(u[j]); }
    }
    for (; p + 4 <= e; p += 4) {
        int i0 = esrc[p], i1 = esrc[p + 1], i2 = esrc[p + 2], i3 = esrc[p + 3];
        unsigned int u0 = act ? xw[i0 * 48 + lane] : 0u;
        unsigned int u1 = act ? xw[i1 * 48 + lane] : 0u;
        unsigned int u2 = act ? xw[i2 * 48 + lane] : 0u;
        unsigned int u3 = act ? xw[i3 * 48 + lane] : 0u;
        aA[0] += bf_lo(u0); aB[0] += bf_hi(u0); aA[1] += bf_lo(u1); aB[1] += bf_hi(u1);
        aA[2] += bf_lo(u2); aB[2] += bf_hi(u2); aA[3] += bf_lo(u3); aB[3] += bf_hi(u3);
    }
    for (; p < e; ++p) {
        unsigned int u = act ? xw[esrc[p] * 48 + lane] : 0u;
        aA[0] += bf_lo(u); aB[0] += bf_hi(u);
    }
    if (act) {
        float rx = ((aA[0] + aA[1]) + (aA[2] + aA[3])) + ((aA[4] + aA[5]) + (aA[6] + aA[7]));
        float ry = ((aB[0] + aB[1]) + (aB[2] + aB[3])) + ((aB[4] + aB[5]) + (aB[6] + aB[7]));
        out[node * 48 + lane] = (unsigned int)f2bf(rx) | ((unsigned int)f2bf(ry) << 16);
    }
}

__global__ void k_gather128b(const unsigned int* __restrict__ hw,
                             const int* __restrict__ row_start, const int* __restrict__ esrc,
                             unsigned int* __restrict__ aggb) {
    int wave = threadIdx.x >> 6;
    int lane = threadIdx.x & 63;
    int node = blockIdx.x * 4 + wave;
    int s = row_start[node], e = row_start[node + 1];
    unsigned int su = hw[node * 64 + lane];
    float aA[8], aB[8];
#pragma unroll
    for (int j = 0; j < 8; ++j) { aA[j] = 0.f; aB[j] = 0.f; }
    aA[0] = bf_lo(su); aB[0] = bf_hi(su);
    int p = s;
    for (; p + 16 <= e; p += 16) {
        int idx[16];
#pragma unroll
        for (int j = 0; j < 16; ++j) idx[j] = esrc[p + j];
        unsigned int u[16];
#pragma unroll
        for (int j = 0; j < 16; ++j) u[j] = hw[idx[j] * 64 + lane];
#pragma unroll
        for (int j = 0; j < 16; ++j) { aA[j & 7] += bf_lo(u[j]); aB[j & 7] += bf_hi(u[j]); }
    }
    for (; p + 4 <= e; p += 4) {
        int i0 = esrc[p], i1 = esrc[p + 1], i2 = esrc[p + 2], i3 = esrc[p + 3];
        unsigned int u0 = hw[i0 * 64 + lane];
        unsigned int u1 = hw[i1 * 64 + lane];
        unsigned int u2 = hw[i2 * 64 + lane];
        unsigned int u3 = hw[i3 * 64 + lane];
        aA[0] += bf_lo(u0); aB[0] += bf_hi(u0); aA[1] += bf_lo(u1); aB[1] += bf_hi(u1);
        aA[2] += bf_lo(u2); aB[2] += bf_hi(u2); aA[3] += bf_lo(u3); aB[3] += bf_hi(u3);
    }
    for (; p < e; ++p) {
        unsigned int u = hw[esrc[p] * 64 + lane];
        aA[0] += bf_lo(u); aB[0] += bf_hi(u);
    }
    float rx = ((aA[0] + aA[1]) + (aA[2] + aA[3])) + ((aA[4] + aA[5]) + (aA[6] + aA[7]));
    float ry = ((aB[0] + aB[1]) + (aB[2] + aB[3])) + ((aB[4] + aB[5]) + (aB[6] + aB[7]));
    aggb[node * 64 + lane] = (unsigned int)f2bf(rx) | ((unsigned int)f2bf(ry) << 16);
}

// ---------------- fused 2-GEMM MLP (MFMA, bf16) ----------------

template <int NK1>
__global__ __launch_bounds__(256) void k_mlp(const short* __restrict__ A,
                                             const short* __restrict__ Wt1,
                                             const float* __restrict__ b1v,
                                             const short* __restrict__ Wt2,
                                             const float* __restrict__ b2v,
                                             unsigned short* __restrict__ out,
                                             float* __restrict__ gsum,
                                             float* __restrict__ gss) {
    const int K1 = NK1 * 32;
    __shared__ unsigned short act1[64 * H];  // 16 KB
    __shared__ float lsum[H], lss[H];
    if (threadIdx.x < H) { lsum[threadIdx.x] = 0.f; lss[threadIdx.x] = 0.f; }
    int wave = threadIdx.x >> 6, lane = threadIdx.x & 63;
    int r0 = blockIdx.x * 64 + wave * 16;
    int lm = lane & 15, lk = lane >> 4;
    int arow = r0 + lm;
    if (arow >= N_NODES) arow = N_NODES - 1;
    const short8* Arow = (const short8*)(A + (size_t)arow * K1);
    f32x4v acc[8];
#pragma unroll
    for (int n = 0; n < 8; ++n) {
        float bv = b1v[n * 16 + lm];
        acc[n] = (f32x4v){bv, bv, bv, bv};
    }
#pragma unroll
    for (int ks = 0; ks < NK1; ++ks) {
        short8 af = Arow[ks * 4 + lk];
#pragma unroll
        for (int n = 0; n < 8; ++n) {
            const short8* Brow = (const short8*)(Wt1 + (size_t)(n * 16 + lm) * K1);
            short8 bfr = Brow[ks * 4 + lk];
            acc[n] = __builtin_amdgcn_mfma_f32_16x16x32_bf16(af, bfr, acc[n], 0, 0, 0);
        }
    }
#pragma unroll
    for (int n = 0; n < 8; ++n) {
        int colb = (n * 16 + lm) * 2;
#pragma unroll
        for (int rg = 0; rg < 4; ++rg) {
            int rl = wave * 16 + lk * 4 + rg;
            int byte = (rl * 256 + colb) ^ ((rl & 7) << 4);
            *(unsigned short*)((char*)act1 + byte) = f2bf(fmaxf(acc[n][rg], 0.f));
        }
    }
    __syncthreads();
    f32x4v acc2[8];
#pragma unroll
    for (int n = 0; n < 8; ++n) {
        float bv = b2v[n * 16 + lm];
        acc2[n] = (f32x4v){bv, bv, bv, bv};
    }
    int rlr = wave * 16 + lm;
#pragma unroll
    for (int ks = 0; ks < 4; ++ks) {
        int byte = (rlr * 256 + ks * 64 + lk * 16) ^ ((rlr & 7) << 4);
        short8 af = *(const short8*)((char*)act1 + byte);
#pragma unroll
        for (int n = 0; n < 8; ++n) {
            const short8* Brow = (const short8*)(Wt2 + (size_t)(n * 16 + lm) * H);
            short8 bfr = Brow[ks * 4 + lk];
            acc2[n] = __builtin_amdgcn_mfma_f32_16x16x32_bf16(af, bfr, acc2[n], 0, 0, 0);
        }
    }
#pragma unroll
    for (int n = 0; n < 8; ++n) {
        int col = n * 16 + lm;
        float s = 0.f, q = 0.f;
#pragma unroll
        for (int rg = 0; rg < 4; ++rg) {
            int r = r0 + lk * 4 + rg;
            if (r < N_NODES) {
                float v = fmaxf(acc2[n][rg], 0.f);
                out[(size_t)r * H + col] = f2bf(v);
                s += v;
                q += v * v;
            }
        }
        atomicAdd(&lsum[col], s);
        atomicAdd(&lss[col], q);
    }
    __syncthreads();
    if (threadIdx.x < H) {
        atomicAdd(&gsum[threadIdx.x], lsum[threadIdx.x]);
        atomicAdd(&gss[threadIdx.x], lss[threadIdx.x]);
    }
}

// ---------------- BN ----------------

__global__ void k_bnfinal(float* __restrict__ gsum, float* __restrict__ gss,
                          const float* __restrict__ gamma, const float* __restrict__ beta,
                          float* __restrict__ scale, float* __restrict__ shift) {
    int c = threadIdx.x;
    const float inv_n = 1.f / (float)N_NODES;
    float sv = gsum[c], qv = gss[c];
    gsum[c] = 0.f;
    gss[c] = 0.f;
    float mu = sv * inv_n;
    float var = fmaxf(qv * inv_n - mu * mu, 0.f);
    float sc = gamma[c] * rsqrtf(var + BN_EPS);
    scale[c] = sc;
    shift[c] = beta[c] - mu * sc;
}

// hb = bf16( (RES? bf(hb):0) + bf(act)*scale + shift )   — bf16-only residual state
template <bool RES>
__global__ void k_bnapply(const uint2* __restrict__ vb, const float* __restrict__ scale,
                          const float* __restrict__ shift, uint2* __restrict__ hb) {
    int idx = blockIdx.x * blockDim.x + threadIdx.x;  // 4-elem index
    if (idx >= N_NODES * H / 4) return;
    int c4 = idx & 31;
    uint2 pv = vb[idx];
    float4 val = make_float4(bf_lo(pv.x), bf_hi(pv.x), bf_lo(pv.y), bf_hi(pv.y));
    float4 sc = reinterpret_cast<const float4*>(scale)[c4];
    float4 sh = reinterpret_cast<const float4*>(shift)[c4];
    float4 r;
    r.x = val.x * sc.x + sh.x;
    r.y = val.y * sc.y + sh.y;
    r.z = val.z * sc.z + sh.z;
    r.w = val.w * sc.w + sh.w;
    if (RES) {
        uint2 hv = hb[idx];
        r.x += bf_lo(hv.x); r.y += bf_hi(hv.x); r.z += bf_lo(hv.y); r.w += bf_hi(hv.y);
    }
    uint2 pk;
    pk.x = (unsigned int)f2bf(r.x) | ((unsigned int)f2bf(r.y) << 16);
    pk.y = (unsigned int)f2bf(r.z) | ((unsigned int)f2bf(r.w) << 16);
    hb[idx] = pk;
}

// ---------------- pooling + head ----------------

__global__ void k_bounds(const int* __restrict__ batch, int* __restrict__ row_begin) {
    int i = blockIdx.x * blockDim.x + threadIdx.x;
    if (i >= N_NODES) return;
    int bi = batch[i];
    int bp = (i == 0) ? -1 : batch[i - 1];
    for (int g = bp + 1; g <= bi; ++g) row_begin[g] = i;
    if (i == N_NODES - 1) {
        for (int g = bi + 1; g <= N_GRAPHS; ++g) row_begin[g] = N_NODES;
    }
}

// fused: h4 = bf(hb3) + scale*bf(act) + shift on the fly, then mean/max pool
__global__ void k_pool_f(const unsigned short* __restrict__ act, const float* __restrict__ scale,
                         const float* __restrict__ shift, const unsigned short* __restrict__ hb3,
                         const int* __restrict__ row_begin, float* __restrict__ pooled) {
    int g = blockIdx.x;
    int c = threadIdx.x;  // 128
    float sc = scale[c], sh = shift[c];
    int s = row_begin[g], e = row_begin[g + 1];
    float sum = 0.f, mx = -FLT_MAX;
    for (int i = s; i < e; ++i) {
        float v = bf1(hb3[(size_t)i * H + c]) + sc * bf1(act[(size_t)i * H + c]) + sh;
        sum += v;
        mx = fmaxf(mx, v);
    }
    int cnt = e - s;
    pooled[g * 256 + c]       = (cnt > 0) ? sum / (float)cnt : 0.f;
    pooled[g * 256 + 128 + c] = (cnt > 0) ? mx : 0.f;
}

__global__ void k_final(const float* __restrict__ pooled, const float* __restrict__ Wf,
                        const float* __restrict__ bf, float* __restrict__ out) {
    __shared__ float ps[256];
    int g = blockIdx.x, c = threadIdx.x;
    ps[c] = pooled[g * 256 + c];
    ps[128 + c] = pooled[g * 256 + 128 + c];
    __syncthreads();
    float acc = bf[c];
#pragma unroll 8
    for (int k = 0; k < 256; ++k) acc += ps[k] * Wf[k * H + c];
    out[g * H + c] = acc;
}

// ---------------- launcher ----------------

extern "C" void kernel_launch(void* const* d_in, const int* in_sizes, int n_in,
                              void* d_out, int out_size, void* d_ws, size_t ws_size,
                              hipStream_t stream) {
    const float* x     = (const float*)d_in[0];
    const int*   ei    = (const int*)d_in[1];
    const int*   src   = ei;
    const int*   dst   = ei + N_EDGES;
    const int*   batch = (const int*)d_in[2];
    const float* W1_0  = (const float*)d_in[3];
    const float* b1_0  = (const float*)d_in[4];
    const float* W2_0  = (const float*)d_in[5];
    const float* b2_0  = (const float*)d_in[6];
    const float* W1    = (const float*)d_in[7];
    const float* b1    = (const float*)d_in[8];
    const float* W2    = (const float*)d_in[9];
    const float* b2    = (const float*)d_in[10];
    const float* gamma = (const float*)d_in[11];
    const float* beta  = (const float*)d_in[12];
    const float* Wf    = (const float*)d_in[13];
    const float* bf    = (const float*)d_in[14];
    float* out = (float*)d_out;

    char* ws = (char*)d_ws;
    size_t off = 0;
    auto alloc = [&](size_t bytes) -> void* {
        void* p = ws + off;
        off = (off + bytes + 255) & ~(size_t)255;
        return p;
    };

    uint2* hb   = (uint2*)alloc((size_t)N_NODES * H * 2);
    unsigned int*   aggb  = (unsigned int*)alloc((size_t)N_NODES * H * 2);
    unsigned short* act2b = (unsigned short*)alloc((size_t)N_NODES * H * 2);
    unsigned short* xb    = (unsigned short*)alloc((size_t)N_NODES * 96 * 2);
    unsigned int*   agg0b = (unsigned int*)alloc((size_t)N_NODES * 48 * 4);
    unsigned short* Wtall = (unsigned short*)alloc((size_t)9 * H * H * 2);
    unsigned short* Wt0   = (unsigned short*)alloc((size_t)H * 96 * 2);
    int* row_start = (int*)alloc((size_t)(N_NODES + 1) * 4);
    int* esrc      = (int*)alloc((size_t)N_EDGES * 4);
    unsigned int* ebuf = (unsigned int*)alloc((size_t)N_EDGES * 4);
    int* bofs      = (int*)alloc((size_t)P3_BLOCKS * NBUCKETS * 4);
    int* btot      = (int*)alloc((size_t)NBUCKETS * 4);
    int* bbase     = (int*)alloc((size_t)(NBUCKETS + 1) * 4);
    float* gsum  = (float*)alloc(H * 4);
    float* gss   = (float*)alloc(H * 4);
    float* scale = (float*)alloc(H * 4);
    float* shift = (float*)alloc(H * 4);
    int* row_begin = (int*)alloc((size_t)(N_GRAPHS + 1) * 4);
    float* pooled  = (float*)alloc((size_t)N_GRAPHS * 256 * 4);

    // ---- prep ----
    k_cast_x<<<(N_NODES * 96 + 255) / 256, 256, 0, stream>>>(x, xb);
    k_cast_w<<<(9 * H * H + 255) / 256, 256, 0, stream>>>(W2_0, W1, W2, Wtall);
    k_cast_w0<<<(H * 96 + 255) / 256, 256, 0, stream>>>(W1_0, Wt0);

    // ---- CSR build (no global atomics) ----
    k_hist<<<P3_BLOCKS, 256, 0, stream>>>(dst, bofs);
    k_scan_a<<<NBUCKETS, 256, 0, stream>>>(bofs, btot);
    k_scan_b<<<1, 1024, 0, stream>>>(btot, bbase, row_start);
    k_p3b<<<P3_BLOCKS, 256, 0, stream>>>(src, dst, bofs, bbase, ebuf);
    k_p4<<<NBUCKETS, 256, 0, stream>>>(bbase, ebuf, esrc, row_start);

    // zero BN accumulators once per call (bnfinal self-resets for later layers)
    hipMemsetAsync(gsum, 0, H * 4, stream);
    hipMemsetAsync(gss, 0, H * 4, stream);

    const int mfma_grid = (N_NODES + 63) / 64;

    // ---- layer 0 (78 -> 128, no residual) ----
    k_gather96<<<N_NODES / 4, 256, 0, stream>>>((const unsigned int*)xb, row_start, esrc, agg0b);
    k_mlp<3><<<mfma_grid, 256, 0, stream>>>((const short*)agg0b, (const short*)Wt0, b1_0,
                                            (const short*)Wtall, b2_0, act2b, gsum, gss);
    k_bnfinal<<<1, 128, 0, stream>>>(gsum, gss, gamma, beta, scale, shift);
    k_bnapply<false><<<N_NODES * H / 4 / 256, 256, 0, stream>>>((const uint2*)act2b,
                                                                scale, shift, hb);

    // ---- layers 1..4 (residual) ----
    for (int l = 0; l < 4; ++l) {
        k_gather128b<<<N_NODES / 4, 256, 0, stream>>>((const unsigned int*)hb, row_start,
                                                      esrc, aggb);
        k_mlp<4><<<mfma_grid, 256, 0, stream>>>((const short*)aggb,
                                                (const short*)(Wtall + (1 + l) * H * H),
                                                b1 + l * H,
                                                (const short*)(Wtall + (5 + l) * H * H),
                                                b2 + l * H, act2b, gsum, gss);
        k_bnfinal<<<1, 128, 0, stream>>>(gsum, gss, gamma + (l + 1) * H, beta + (l + 1) * H,
                                         scale, shift);
        if (l < 3) {
            k_bnapply<true><<<N_NODES * H / 4 / 256, 256, 0, stream>>>((const uint2*)act2b,
                                                                       scale, shift, hb);
        }
        // l == 3: bnapply fused into k_pool_f below
    }

    // ---- pooling + head ----
    k_bounds<<<(N_NODES + 255) / 256, 256, 0, stream>>>(batch, row_begin);
    k_pool_f<<<N_GRAPHS, 128, 0, stream>>>(act2b, scale, shift,
                                           (const unsigned short*)hb, row_begin, pooled);
    k_final<<<N_GRAPHS, 128, 0, stream>>>(pooled, Wf, bf, out);
}